// Round 4
// baseline (2241.981 us; speedup 1.0000x reference)
//
#include <hip/hip_runtime.h>
#include <hip/hip_bf16.h>
#include <hip/hip_cooperative_groups.h>

namespace cg = cooperative_groups;

#define B_ 4
#define N_ 8192
#define D_ 512
#define H_ 8
#define DH_ 64
#define M_ 256
#define LCH 32
#define KER_ 33
#define NSPLIT 16
#define CS (N_/NSPLIT)   // 512 cols per split chunk

typedef __hip_bfloat16 bf16;
typedef __attribute__((ext_vector_type(8))) short short8;
typedef __attribute__((ext_vector_type(4))) float f32x4;

__device__ __forceinline__ float bf2f(bf16 h){ return __bfloat162float(h); }
__device__ __forceinline__ bf16 f2bf(float f){ return __float2bfloat16(f); }
__device__ __forceinline__ f32x4 mfma16(short8 a, short8 b, f32x4 c){
  return __builtin_amdgcn_mfma_f32_16x16x32_bf16(a, b, c, 0, 0, 0);
}

// ---------------- LayerNorm: x (b,n,512) fp32 -> xn bf16 ----------------
__global__ __launch_bounds__(256) void k_layernorm(const float* __restrict__ x,
    const float* __restrict__ gamma, const float* __restrict__ beta,
    bf16* __restrict__ xn){
  int row = blockIdx.x;
  const float* xr = x + (size_t)row * D_;
  bf16* o = xn + (size_t)row * D_;
  int t = threadIdx.x;
  float v0 = xr[t], v1 = xr[t+256];
  float s = v0+v1, ss = v0*v0 + v1*v1;
  __shared__ float sh[8];
  for (int off=32; off; off>>=1){ s += __shfl_xor(s,off); ss += __shfl_xor(ss,off); }
  int lane = t&63, wid = t>>6;
  if (lane==0){ sh[wid] = s; sh[wid+4] = ss; }
  __syncthreads();
  float S  = sh[0]+sh[1]+sh[2]+sh[3];
  float SS = sh[4]+sh[5]+sh[6]+sh[7];
  float mu = S*(1.f/D_);
  float var = SS*(1.f/D_) - mu*mu;
  float rs = rsqrtf(var + 1e-5f);
  o[t]     = f2bf((v0-mu)*rs*gamma[t]     + beta[t]);
  o[t+256] = f2bf((v1-mu)*rs*gamma[t+256] + beta[t+256]);
}

// ---------------- W transpose+convert: W (RxC fp32) -> WT (CxR bf16) ----------------
__global__ __launch_bounds__(256) void k_wt(const float* __restrict__ W, bf16* __restrict__ WT,
    int R, int C){
  int c0 = blockIdx.x*64, r0 = blockIdx.y*64;
  __shared__ float tile[64][65];
  int t = threadIdx.x;
  for (int i=t;i<4096;i+=256){ int r=i>>6, c=i&63; tile[r][c] = W[(size_t)(r0+r)*C + c0+c]; }
  __syncthreads();
  for (int i=t;i<512;i+=256){
    int c=i>>3, rg=i&7;
    short8 o;
    #pragma unroll
    for (int j=0;j<8;j++) ((bf16*)&o)[j] = f2bf(tile[rg*8+j][c]);
    *(short8*)&WT[(size_t)(c0+c)*R + r0 + rg*8] = o;
  }
}

// ---------------- QKV GEMM (MFMA, reg-staged, padded LDS): xn @ WT^T -> q,k,v ----------------
__global__ __launch_bounds__(256) void k_mm_qkv2(const bf16* __restrict__ A, const bf16* __restrict__ WT,
    bf16* __restrict__ qbuf, bf16* __restrict__ kbuf, bf16* __restrict__ vbuf){
  __shared__ __align__(16) bf16 As[128][72];
  __shared__ __align__(16) bf16 Bs[128][72];
  int t = threadIdx.x;
  int w = t>>6, lane = t&63, qd = lane>>4, n = lane&15;
  int wm = w>>1, wn = w&1;
  int r0 = blockIdx.x*128, c0 = blockIdx.y*128;
  f32x4 acc[4][4];
  #pragma unroll
  for (int i=0;i<4;i++)
    #pragma unroll
    for (int j=0;j<4;j++) acc[i][j] = (f32x4){0.f,0.f,0.f,0.f};
  int srow = t>>3, skc = t&7;
  for (int k0=0; k0<512; k0+=64){
    #pragma unroll
    for (int ch=0; ch<4; ch++){
      int m = ch*32 + srow;
      *(short8*)&As[m][skc*8] = *(const short8*)&A[(size_t)(r0+m)*512 + k0 + skc*8];
      *(short8*)&Bs[m][skc*8] = *(const short8*)&WT[(size_t)(c0+m)*512 + k0 + skc*8];
    }
    __syncthreads();
    #pragma unroll
    for (int ksub=0; ksub<2; ksub++){
      short8 af[4], bfr[4];
      #pragma unroll
      for (int i=0;i<4;i++) af[i]  = *(const short8*)&As[wm*64+i*16+n][ksub*32+qd*8];
      #pragma unroll
      for (int j=0;j<4;j++) bfr[j] = *(const short8*)&Bs[wn*64+j*16+n][ksub*32+qd*8];
      #pragma unroll
      for (int i=0;i<4;i++)
        #pragma unroll
        for (int j=0;j<4;j++) acc[i][j] = mfma16(af[i], bfr[j], acc[i][j]);
    }
    __syncthreads();
  }
  int part = c0 >> 9;
  bf16* dst = (part==0)? qbuf : (part==1)? kbuf : vbuf;
  float scale = (part==0)? 0.125f : 1.f;
  #pragma unroll
  for (int i=0;i<4;i++){
    #pragma unroll
    for (int j=0;j<4;j++){
      int c = c0 + wn*64 + j*16 + n;
      int cc = c & 511, h = cc>>6, dh = cc&63;
      #pragma unroll
      for (int rg=0; rg<4; rg++){
        int r = r0 + wm*64 + i*16 + qd*4 + rg;
        int b = r >> 13, nn = r & 8191;
        dst[(((size_t)(b*H_+h))*N_ + nn)*DH_ + dh] = f2bf(acc[i][j][rg]*scale);
      }
    }
  }
}

// ---------------- v -> vT tiled transpose (64x64) ----------------
__global__ __launch_bounds__(256) void k_transp_v(const bf16* __restrict__ v, bf16* __restrict__ vT){
  int bh = blockIdx.y, n0 = blockIdx.x*64;
  __shared__ bf16 tile[64][72];
  const bf16* vb = v + (size_t)bh*N_*DH_;
  int t = threadIdx.x;
  for (int i=t; i<512; i+=256){
    int r = i>>3, cg = i&7;
    *(short8*)&tile[r][cg*8] = *(const short8*)&vb[(size_t)(n0+r)*DH_ + cg*8];
  }
  __syncthreads();
  bf16* ob = vT + (size_t)bh*DH_*N_;
  for (int i=t; i<512; i+=256){
    int dh = i>>3, ng = i&7;
    short8 o;
    #pragma unroll
    for (int j=0;j<8;j++) ((bf16*)&o)[j] = tile[ng*8+j][dh];
    *(short8*)&ob[(size_t)dh*N_ + n0 + ng*8] = o;
  }
}

// ---------------- landmark means over contiguous 32-row chunks ----------------
__global__ __launch_bounds__(64) void k_landmark(const bf16* __restrict__ q, const bf16* __restrict__ k,
    bf16* __restrict__ ql, bf16* __restrict__ kl){
  int bhm = blockIdx.x;
  int bh = bhm >> 8, m = bhm & 255;
  int dh = threadIdx.x;
  const bf16* qp = q + ((size_t)bh*N_ + (size_t)m*LCH)*DH_ + dh;
  const bf16* kp = k + ((size_t)bh*N_ + (size_t)m*LCH)*DH_ + dh;
  float sq=0.f, sk=0.f;
  #pragma unroll
  for (int j=0;j<LCH;j++){ sq += bf2f(qp[(size_t)j*DH_]); sk += bf2f(kp[(size_t)j*DH_]); }
  ql[((size_t)bh*M_ + m)*DH_ + dh] = f2bf(sq*(1.f/LCH));
  kl[((size_t)bh*M_ + m)*DH_ + dh] = f2bf(sk*(1.f/LCH));
}

// ---------------- attn2 = softmax(q_l @ k_l^T) rows (fp32 out) ----------------
__global__ __launch_bounds__(256) void k_attn2(const bf16* __restrict__ ql, const bf16* __restrict__ kl,
    float* __restrict__ A2){
  int bhm = blockIdx.x;
  int bh = bhm >> 8, m = bhm & 255;
  int t = threadIdx.x;
  __shared__ float qrow[64];
  __shared__ float sh[4];
  if (t < 64) qrow[t] = bf2f(ql[((size_t)bh*M_ + m)*DH_ + t]);
  __syncthreads();
  const bf16* krow = kl + ((size_t)bh*M_ + t)*DH_;
  float s = 0.f;
  #pragma unroll
  for (int i=0;i<64;i++) s += qrow[i]*bf2f(krow[i]);
  float mx = s;
  for (int off=32; off; off>>=1) mx = fmaxf(mx, __shfl_xor(mx, off));
  if ((t&63)==0) sh[t>>6] = mx;
  __syncthreads();
  mx = fmaxf(fmaxf(sh[0],sh[1]), fmaxf(sh[2],sh[3]));
  float e = expf(s - mx);
  float sum = e;
  for (int off=32; off; off>>=1) sum += __shfl_xor(sum, off);
  __syncthreads();
  if ((t&63)==0) sh[t>>6] = sum;
  __syncthreads();
  sum = sh[0]+sh[1]+sh[2]+sh[3];
  A2[((size_t)bh*M_ + m)*M_ + t] = e/sum;
}

// ---------------- pinv init: Z = A^T / (max_rowsum * max_colsum) ----------------
__global__ __launch_bounds__(256) void k_pinv_init(const float* __restrict__ A2, float* __restrict__ Z){
  int bh = blockIdx.x;
  int t = threadIdx.x;
  const float* Ab = A2 + (size_t)bh*M_*M_;
  float* Zb = Z + (size_t)bh*M_*M_;
  float cs=0.f, rsm=0.f;
  for (int r=0;r<M_;r++) cs += fabsf(Ab[(size_t)r*M_ + t]);
  for (int c=0;c<M_;c++) rsm += fabsf(Ab[(size_t)t*M_ + c]);
  __shared__ float sh[4];
  float v = cs;
  for (int off=32; off; off>>=1) v = fmaxf(v, __shfl_xor(v, off));
  if ((t&63)==0) sh[t>>6] = v;
  __syncthreads();
  float maxc = fmaxf(fmaxf(sh[0],sh[1]), fmaxf(sh[2],sh[3]));
  __syncthreads();
  v = rsm;
  for (int off=32; off; off>>=1) v = fmaxf(v, __shfl_xor(v, off));
  if ((t&63)==0) sh[t>>6] = v;
  __syncthreads();
  float maxr = fmaxf(fmaxf(sh[0],sh[1]), fmaxf(sh[2],sh[3]));
  float inv = 1.f/(maxr*maxc);
  for (int r=0;r<M_;r++) Zb[(size_t)r*M_ + t] = Ab[(size_t)t*M_ + r]*inv;
}

// ---------------- pinv GEMM core (device): C = cScale*(cNeg? cDiag*I - A@B' : A@B') ----------------
// B' = bNeg? bDiag*I-B : B. split=1: hi/lo bf16, 3 MFMAs/product; split=0: plain bf16.
__device__ __forceinline__ void gemm_pm_dev(float* __restrict__ Cb, const float* __restrict__ Ab,
    const float* __restrict__ Bb, float bDiag, int bNeg, float cDiag, int cNeg, float cScale,
    int split, int tm, int tn,
    bf16 (&Ah)[64][72], bf16 (&Al)[64][72], bf16 (&Bh)[64][72], bf16 (&Bl)[64][72]){
  int t = threadIdx.x;
  int w = t>>6, lane = t&63, qd = lane>>4, n = lane&15;
  int wm = w>>1, wn = w&1;
  int r0 = tm*64, c0 = tn*64;
  f32x4 acc[2][2];
  #pragma unroll
  for (int i=0;i<2;i++)
    #pragma unroll
    for (int j=0;j<2;j++) acc[i][j] = (f32x4){0.f,0.f,0.f,0.f};
  int srow = t>>3, skc = t&7;
  for (int k0=0; k0<256; k0+=64){
    #pragma unroll
    for (int ch=0; ch<2; ch++){
      int m = ch*32 + srow;
      short8 vh, vl;
      const float* ap = &Ab[(size_t)(r0+m)*256 + k0 + skc*8];
      #pragma unroll
      for (int j=0;j<8;j++){
        float x = ap[j];
        bf16 h = f2bf(x);
        ((bf16*)&vh)[j] = h;
        if (split) ((bf16*)&vl)[j] = f2bf(x - bf2f(h));
      }
      *(short8*)&Ah[m][skc*8] = vh;
      if (split) *(short8*)&Al[m][skc*8] = vl;
      const float* bp = &Bb[(size_t)(k0+m)*256 + c0 + skc*8];
      int kr = k0 + m;
      #pragma unroll
      for (int j=0;j<8;j++){
        float x = bp[j];
        if (bNeg) x = (kr == (c0 + skc*8 + j) ? bDiag : 0.f) - x;
        bf16 h = f2bf(x);
        ((bf16*)&vh)[j] = h;
        if (split) ((bf16*)&vl)[j] = f2bf(x - bf2f(h));
      }
      #pragma unroll
      for (int j=0;j<8;j++){
        Bh[skc*8+j][m] = ((bf16*)&vh)[j];
        if (split) Bl[skc*8+j][m] = ((bf16*)&vl)[j];
      }
    }
    __syncthreads();
    #pragma unroll
    for (int ksub=0; ksub<2; ksub++){
      short8 afh[2], afl[2], bfh[2], bfl[2];
      #pragma unroll
      for (int i=0;i<2;i++){
        afh[i] = *(const short8*)&Ah[wm*32+i*16+n][ksub*32+qd*8];
        if (split) afl[i] = *(const short8*)&Al[wm*32+i*16+n][ksub*32+qd*8];
      }
      #pragma unroll
      for (int j=0;j<2;j++){
        bfh[j] = *(const short8*)&Bh[wn*32+j*16+n][ksub*32+qd*8];
        if (split) bfl[j] = *(const short8*)&Bl[wn*32+j*16+n][ksub*32+qd*8];
      }
      #pragma unroll
      for (int i=0;i<2;i++)
        #pragma unroll
        for (int j=0;j<2;j++){
          if (split){
            acc[i][j] = mfma16(afl[i], bfh[j], acc[i][j]);
            acc[i][j] = mfma16(afh[i], bfl[j], acc[i][j]);
          }
          acc[i][j] = mfma16(afh[i], bfh[j], acc[i][j]);
        }
    }
    __syncthreads();
  }
  #pragma unroll
  for (int i=0;i<2;i++){
    #pragma unroll
    for (int j=0;j<2;j++){
      int cidx = c0 + wn*32 + j*16 + n;
      #pragma unroll
      for (int rg=0; rg<4; rg++){
        int r = r0 + wm*32 + i*16 + qd*4 + rg;
        float r_ = acc[i][j][rg];
        if (cNeg) r_ = ((r==cidx)? cDiag : 0.f) - r_;
        Cb[(size_t)r*256 + cidx] = r_*cScale;
      }
    }
  }
}

// ---------------- fused pinv: all 6 Newton-Schulz iterations in ONE cooperative kernel ----------------
// 512 blocks (32 bh x 16 tiles), 2 blocks/CU guaranteed co-resident. grid.sync() between steps
// replaces 24 kernel launches (~150us of launch/ramp overhead on L2-resident 1-GFLOP dispatches).
__global__ __launch_bounds__(256, 2) void k_pinv_fused(const float* __restrict__ A2,
    float* __restrict__ P1, float* __restrict__ P2, float* __restrict__ P3, float* __restrict__ P4){
  cg::grid_group grid = cg::this_grid();
  __shared__ __align__(16) bf16 Ah[64][72];
  __shared__ __align__(16) bf16 Al[64][72];
  __shared__ __align__(16) bf16 Bh[64][72];
  __shared__ __align__(16) bf16 Bl[64][72];
  int bh = blockIdx.x >> 4;
  int tile = blockIdx.x & 15;
  int tm = tile >> 2, tn = tile & 3;
  size_t off = (size_t)bh*65536;
  const float* A2b = A2 + off;
  float* Zi = P1 + off; float* Zo = P3 + off;
  float* Pb = P2 + off; float* Ub = P4 + off;
  for (int it=0; it<6; ++it){
    int split = (it >= 4);
    gemm_pm_dev(Pb, A2b, Zi, 0.f,0, 0.f,0, 1.f,  split, tm, tn, Ah, Al, Bh, Bl);  // P = A2@Z
    grid.sync();
    gemm_pm_dev(Zo, Pb, Pb, 7.f,1, 15.f,1, 1.f,  split, tm, tn, Ah, Al, Bh, Bl);  // S = 15I - P@(7I-P)
    grid.sync();
    gemm_pm_dev(Ub, Pb, Zo, 0.f,0, 13.f,1, 1.f,  split, tm, tn, Ah, Al, Bh, Bl);  // U = 13I - P@S
    grid.sync();
    gemm_pm_dev(Zo, Zi, Ub, 0.f,0, 0.f,0, 0.25f, split, tm, tn, Ah, Al, Bh, Bl);  // Zn = 0.25*Z@U
    grid.sync();
    float* tt = Zi; Zi = Zo; Zo = tt;
  }
}

// ---------------- pinv GEMM (standalone launch fallback) ----------------
__global__ __launch_bounds__(256) void k_gemm_pm(float* __restrict__ C, const float* __restrict__ A,
    const float* __restrict__ Bm, float bDiag, int bNeg, float cDiag, int cNeg, float cScale,
    int split){
  __shared__ __align__(16) bf16 Ah[64][72];
  __shared__ __align__(16) bf16 Al[64][72];
  __shared__ __align__(16) bf16 Bh[64][72];
  __shared__ __align__(16) bf16 Bl[64][72];
  int bh = blockIdx.y;
  int tm = blockIdx.x >> 2, tn = blockIdx.x & 3;
  gemm_pm_dev(C + (size_t)bh*65536, A + (size_t)bh*65536, Bm + (size_t)bh*65536,
              bDiag, bNeg, cDiag, cNeg, cScale, split, tm, tn, Ah, Al, Bh, Bl);
}

// ---------------- batched GEMM 256x64x256: z2T = (Z @ kv3)^T ----------------
__global__ __launch_bounds__(256) void k_gemm_z2(bf16* __restrict__ z2t, const float* __restrict__ A,
    const bf16* __restrict__ Bm){
  int bh = blockIdx.y;
  int tm = blockIdx.x;
  const float* Ab = A  + (size_t)bh*65536;
  const bf16* Bb = Bm + (size_t)bh*M_*DH_;
  __shared__ float As[16][68];
  __shared__ float Bs[16][64];
  int t = threadIdx.x, tx = t&15, ty = t>>4;
  int r0 = tm*64;
  float acc[4][4] = {};
  for (int k0=0;k0<256;k0+=16){
    for (int i=t;i<1024;i+=256){
      int m=i>>4, kq=i&15;
      As[kq][m] = Ab[(size_t)(r0+m)*256 + k0+kq];
      int nn=i&63, k2=i>>6;
      Bs[k2][nn] = bf2f(Bb[(size_t)(k0+k2)*64 + nn]);
    }
    __syncthreads();
    #pragma unroll
    for (int kq=0;kq<16;kq++){
      float a0[4], b0[4];
      #pragma unroll
      for (int i=0;i<4;i++) a0[i] = As[kq][ty*4+i];
      #pragma unroll
      for (int j=0;j<4;j++) b0[j] = Bs[kq][tx*4+j];
      #pragma unroll
      for (int i=0;i<4;i++)
        #pragma unroll
        for (int j=0;j<4;j++) acc[i][j] += a0[i]*b0[j];
    }
    __syncthreads();
  }
  #pragma unroll
  for (int i=0;i<4;i++){
    int r = r0+ty*4+i;
    #pragma unroll
    for (int j=0;j<4;j++)
      z2t[(size_t)bh*16384 + (size_t)(tx*4+j)*256 + r] = f2bf(acc[i][j]);
  }
}

// ---------------- attn3 flash, flash-decoding split over columns ----------------
__global__ __launch_bounds__(256, 2) void k_flash_split(const bf16* __restrict__ Q,
    const bf16* __restrict__ K, const bf16* __restrict__ VT,
    float* __restrict__ OP, float* __restrict__ MP, float* __restrict__ LP){
  int bh = blockIdx.y;
  int sp = blockIdx.x;
  int t = threadIdx.x, w = t>>6, lane = t&63, qd = lane>>4, n = lane&15;
  int r0 = w*64;
  const size_t Qoff = ((size_t)bh*M_ + r0)*DH_;
  const size_t Koff = ((size_t)bh*N_ + (size_t)sp*CS)*DH_;
  const size_t Voff = (size_t)bh*DH_*N_ + (size_t)sp*CS;
  __shared__ __align__(16) bf16 pbuf[4][4][16][72];
  short8 aq[4][2];
  #pragma unroll
  for (int rt=0; rt<4; rt++){
    aq[rt][0] = *(const short8*)&Q[Qoff + (size_t)(rt*16+n)*DH_ + qd*8];
    aq[rt][1] = *(const short8*)&Q[Qoff + (size_t)(rt*16+n)*DH_ + 32 + qd*8];
  }
  f32x4 o[4][4];
  float mrun[4][4], lrun[4][4];
  #pragma unroll
  for (int rt=0; rt<4; rt++){
    #pragma unroll
    for (int j=0;j<4;j++){ o[rt][j] = (f32x4){0.f,0.f,0.f,0.f}; mrun[rt][j] = -1e30f; lrun[rt][j] = 0.f; }
  }
  for (int tl=0; tl<CS/64; ++tl){
    const bf16* kp = K + Koff + (size_t)(tl*64)*DH_;
    short8 kb[4][2];
    #pragma unroll
    for (int cg=0; cg<4; cg++){
      kb[cg][0] = *(const short8*)&kp[(size_t)(cg*16+n)*DH_ + qd*8];
      kb[cg][1] = *(const short8*)&kp[(size_t)(cg*16+n)*DH_ + 32 + qd*8];
    }
    #pragma unroll
    for (int rt=0; rt<4; rt++){
      f32x4 s[4];
      #pragma unroll
      for (int cg=0; cg<4; cg++){
        f32x4 z = (f32x4){0.f,0.f,0.f,0.f};
        z = mfma16(aq[rt][0], kb[cg][0], z);
        z = mfma16(aq[rt][1], kb[cg][1], z);
        s[cg] = z;
      }
      float alpha[4];
      #pragma unroll
      for (int rg=0; rg<4; rg++){
        float smax = fmaxf(fmaxf(s[0][rg],s[1][rg]), fmaxf(s[2][rg],s[3][rg]));
        smax = fmaxf(smax, __shfl_xor(smax, 1));
        smax = fmaxf(smax, __shfl_xor(smax, 2));
        smax = fmaxf(smax, __shfl_xor(smax, 4));
        smax = fmaxf(smax, __shfl_xor(smax, 8));
        float mn = fmaxf(mrun[rt][rg], smax);
        float p0 = __expf(s[0][rg]-mn), p1 = __expf(s[1][rg]-mn);
        float p2 = __expf(s[2][rg]-mn), p3 = __expf(s[3][rg]-mn);
        float ts = p0+p1+p2+p3;
        ts += __shfl_xor(ts,1); ts += __shfl_xor(ts,2);
        ts += __shfl_xor(ts,4); ts += __shfl_xor(ts,8);
        float al = __expf(mrun[rt][rg]-mn);
        lrun[rt][rg] = lrun[rt][rg]*al + ts;
        mrun[rt][rg] = mn;
        alpha[rg] = al;
        pbuf[w][rt][qd*4+rg][n]    = f2bf(p0);
        pbuf[w][rt][qd*4+rg][16+n] = f2bf(p1);
        pbuf[w][rt][qd*4+rg][32+n] = f2bf(p2);
        pbuf[w][rt][qd*4+rg][48+n] = f2bf(p3);
      }
      #pragma unroll
      for (int dg=0; dg<4; dg++)
        #pragma unroll
        for (int rg=0; rg<4; rg++) o[rt][dg][rg] *= alpha[rg];
    }
    const bf16* vp = VT + Voff + tl*64 + qd*8;
    short8 vb[4][2];
    #pragma unroll
    for (int dg=0; dg<4; dg++){
      vb[dg][0] = *(const short8*)&vp[(size_t)(dg*16+n)*N_];
      vb[dg][1] = *(const short8*)&vp[(size_t)(dg*16+n)*N_ + 32];
    }
    #pragma unroll
    for (int rt=0; rt<4; rt++){
      short8 ap0 = *(const short8*)&pbuf[w][rt][n][qd*8];
      short8 ap1 = *(const short8*)&pbuf[w][rt][n][32+qd*8];
      #pragma unroll
      for (int dg=0; dg<4; dg++){
        o[rt][dg] = mfma16(ap0, vb[dg][0], o[rt][dg]);
        o[rt][dg] = mfma16(ap1, vb[dg][1], o[rt][dg]);
      }
    }
  }
  size_t base = ((size_t)sp*(B_*H_) + bh)*M_;
  #pragma unroll
  for (int rt=0; rt<4; rt++){
    #pragma unroll
    for (int rg=0; rg<4; rg++){
      int row = r0 + rt*16 + qd*4 + rg;
      if (n==0){ MP[base+row] = mrun[rt][rg]; LP[base+row] = lrun[rt][rg]; }
      #pragma unroll
      for (int dg=0; dg<4; dg++)
        OP[(base+row)*DH_ + dg*16 + n] = o[rt][dg][rg];
    }
  }
}

// ---------------- merge NSPLIT flash partials -> kv3 ----------------
__global__ __launch_bounds__(256) void k_flash_merge(const float* __restrict__ OP,
    const float* __restrict__ MP, const float* __restrict__ LP, bf16* __restrict__ O){
  int bh = blockIdx.y;
  int r = blockIdx.x*4 + (threadIdx.x>>6);
  int dh = threadIdx.x & 63;
  float M = -1e30f, acc = 0.f, den = 0.f;
  for (int s=0; s<NSPLIT; s++){
    size_t base = ((size_t)s*(B_*H_) + bh)*M_ + r;
    float m = MP[base];
    float l = LP[base];
    float ov = OP[base*DH_ + dh];
    float Mn = fmaxf(M, m);
    float wo = __expf(M - Mn), wn = __expf(m - Mn);
    acc = acc*wo + ov*wn;
    den = den*wo + l*wn;
    M = Mn;
  }
  O[((size_t)bh*M_ + r)*DH_ + dh] = f2bf(acc/den);
}

// ---------------- attn1 flash, split-structured: 4 waves x 4 rowtiles, 64-col tiles ----------------
__global__ __launch_bounds__(256, 2) void k_flash_w3(const bf16* __restrict__ Q,
    const bf16* __restrict__ K, const bf16* __restrict__ VT, bf16* __restrict__ O){
  int bh = blockIdx.y;
  int t = threadIdx.x, w = t>>6, lane = t&63, qd = lane>>4, n = lane&15;
  int r0 = blockIdx.x*256 + w*64;
  const size_t Qoff = ((size_t)bh*N_ + r0)*DH_;
  const size_t Koff = (size_t)bh*M_*DH_;
  const size_t Voff = (size_t)bh*DH_*M_;
  __shared__ __align__(16) bf16 pbuf[4][4][16][72];
  short8 aq[4][2];
  #pragma unroll
  for (int rt=0; rt<4; rt++){
    aq[rt][0] = *(const short8*)&Q[Qoff + (size_t)(rt*16+n)*DH_ + qd*8];
    aq[rt][1] = *(const short8*)&Q[Qoff + (size_t)(rt*16+n)*DH_ + 32 + qd*8];
  }
  f32x4 o[4][4];
  float mrun[4][4], lrun[4][4];
  #pragma unroll
  for (int rt=0; rt<4; rt++){
    #pragma unroll
    for (int j=0;j<4;j++){ o[rt][j] = (f32x4){0.f,0.f,0.f,0.f}; mrun[rt][j] = -1e30f; lrun[rt][j] = 0.f; }
  }
  #pragma unroll
  for (int tl=0; tl<4; ++tl){
    const bf16* kp = K + Koff + (size_t)(tl*64)*DH_;
    short8 kb[4][2];
    #pragma unroll
    for (int cg=0; cg<4; cg++){
      kb[cg][0] = *(const short8*)&kp[(size_t)(cg*16+n)*DH_ + qd*8];
      kb[cg][1] = *(const short8*)&kp[(size_t)(cg*16+n)*DH_ + 32 + qd*8];
    }
    #pragma unroll
    for (int rt=0; rt<4; rt++){
      f32x4 s[4];
      #pragma unroll
      for (int cg=0; cg<4; cg++){
        f32x4 z = (f32x4){0.f,0.f,0.f,0.f};
        z = mfma16(aq[rt][0], kb[cg][0], z);
        z = mfma16(aq[rt][1], kb[cg][1], z);
        s[cg] = z;
      }
      float alpha[4];
      #pragma unroll
      for (int rg=0; rg<4; rg++){
        float smax = fmaxf(fmaxf(s[0][rg],s[1][rg]), fmaxf(s[2][rg],s[3][rg]));
        smax = fmaxf(smax, __shfl_xor(smax, 1));
        smax = fmaxf(smax, __shfl_xor(smax, 2));
        smax = fmaxf(smax, __shfl_xor(smax, 4));
        smax = fmaxf(smax, __shfl_xor(smax, 8));
        float mn = fmaxf(mrun[rt][rg], smax);
        float p0 = __expf(s[0][rg]-mn), p1 = __expf(s[1][rg]-mn);
        float p2 = __expf(s[2][rg]-mn), p3 = __expf(s[3][rg]-mn);
        float ts = p0+p1+p2+p3;
        ts += __shfl_xor(ts,1); ts += __shfl_xor(ts,2);
        ts += __shfl_xor(ts,4); ts += __shfl_xor(ts,8);
        float al = __expf(mrun[rt][rg]-mn);
        lrun[rt][rg] = lrun[rt][rg]*al + ts;
        mrun[rt][rg] = mn;
        alpha[rg] = al;
        pbuf[w][rt][qd*4+rg][n]    = f2bf(p0);
        pbuf[w][rt][qd*4+rg][16+n] = f2bf(p1);
        pbuf[w][rt][qd*4+rg][32+n] = f2bf(p2);
        pbuf[w][rt][qd*4+rg][48+n] = f2bf(p3);
      }
      #pragma unroll
      for (int dg=0; dg<4; dg++)
        #pragma unroll
        for (int rg=0; rg<4; rg++) o[rt][dg][rg] *= alpha[rg];
    }
    const bf16* vp = VT + Voff + tl*64 + qd*8;
    short8 vb[4][2];
    #pragma unroll
    for (int dg=0; dg<4; dg++){
      vb[dg][0] = *(const short8*)&vp[(size_t)(dg*16+n)*M_];
      vb[dg][1] = *(const short8*)&vp[(size_t)(dg*16+n)*M_ + 32];
    }
    #pragma unroll
    for (int rt=0; rt<4; rt++){
      short8 ap0 = *(const short8*)&pbuf[w][rt][n][qd*8];
      short8 ap1 = *(const short8*)&pbuf[w][rt][n][32+qd*8];
      #pragma unroll
      for (int dg=0; dg<4; dg++){
        o[rt][dg] = mfma16(ap0, vb[dg][0], o[rt][dg]);
        o[rt][dg] = mfma16(ap1, vb[dg][1], o[rt][dg]);
      }
    }
  }
  #pragma unroll
  for (int rt=0; rt<4; rt++){
    #pragma unroll
    for (int rg=0; rg<4; rg++){
      float inv = 1.f/lrun[rt][rg];
      size_t rowoff = ((size_t)bh*N_ + r0 + rt*16 + qd*4 + rg)*DH_;
      #pragma unroll
      for (int dg=0; dg<4; dg++)
        O[rowoff + dg*16 + n] = f2bf(o[rt][dg][rg]*inv);
    }
  }
}

// ---------------- depthwise conv(KER=33), LDS-tiled, vectorized RMW into outh ----------------
#define CCH 256
__global__ __launch_bounds__(256) void k_conv_add(const bf16* __restrict__ v, const float* __restrict__ w,
    bf16* __restrict__ outh){
  int bh = blockIdx.y;
  int n0 = blockIdx.x * CCH;
  int h = bh & 7;
  __shared__ bf16 vs[CCH+32][72];
  __shared__ float wk[KER_];
  int t = threadIdx.x;
  if (t < KER_) wk[t] = w[h*KER_ + t];
  const bf16* vb = v + (size_t)bh*N_*DH_;
  for (int i=t; i<(CCH+32)*8; i+=256){
    int r = i>>3, cg = i&7;
    int nn = n0 - 16 + r;
    short8 val = {0,0,0,0,0,0,0,0};
    if (nn >= 0 && nn < N_) val = *(const short8*)&vb[(size_t)nn*DH_ + cg*8];
    *(short8*)&vs[r][cg*8] = val;
  }
  __syncthreads();
  int dhg = t & 7, rowg = t >> 3;
  bf16* ob = outh + ((size_t)bh*N_ + n0)*DH_;
  #pragma unroll
  for (int rr=0; rr<8; rr++){
    int lr = rowg*8 + rr;
    float acc[8] = {0.f,0.f,0.f,0.f,0.f,0.f,0.f,0.f};
    for (int tt=0; tt<KER_; tt++){
      short8 vv = *(const short8*)&vs[lr+tt][dhg*8];
      float wt = wk[tt];
      #pragma unroll
      for (int j=0;j<8;j++) acc[j] += wt * bf2f(((bf16*)&vv)[j]);
    }
    short8 o = *(short8*)&ob[(size_t)lr*DH_ + dhg*8];
    #pragma unroll
    for (int j=0;j<8;j++) ((bf16*)&o)[j] = f2bf(bf2f(((bf16*)&o)[j]) + acc[j]);
    *(short8*)&ob[(size_t)lr*DH_ + dhg*8] = o;
  }
}

// ---------------- final GEMM (MFMA, reg-staged, padded LDS): out = x + gather(outh) @ WT2^T + b_out ----------------
__global__ __launch_bounds__(256) void k_mm_out2(const bf16* __restrict__ Ahd, const bf16* __restrict__ WT2,
    const float* __restrict__ bias, const float* __restrict__ xin, float* __restrict__ out){
  __shared__ __align__(16) bf16 As[128][72];
  __shared__ __align__(16) bf16 Bs[128][72];
  int t = threadIdx.x;
  int w = t>>6, lane = t&63, qd = lane>>4, n = lane&15;
  int wm = w>>1, wn = w&1;
  int r0 = blockIdx.x*128, c0 = blockIdx.y*128;
  f32x4 acc[4][4];
  #pragma unroll
  for (int i=0;i<4;i++)
    #pragma unroll
    for (int j=0;j<4;j++) acc[i][j] = (f32x4){0.f,0.f,0.f,0.f};
  int srow = t>>3, skc = t&7;
  for (int k0=0; k0<512; k0+=64){
    int h = k0 >> 6;
    #pragma unroll
    for (int ch=0; ch<4; ch++){
      int m = ch*32 + srow;
      int r = r0 + m, b = r>>13, nn = r&8191;
      *(short8*)&As[m][skc*8] = *(const short8*)&Ahd[((size_t)(b*H_+h)*N_ + nn)*DH_ + skc*8];
      *(short8*)&Bs[m][skc*8] = *(const short8*)&WT2[(size_t)(c0+m)*512 + k0 + skc*8];
    }
    __syncthreads();
    #pragma unroll
    for (int ksub=0; ksub<2; ksub++){
      short8 af[4], bfr[4];
      #pragma unroll
      for (int i=0;i<4;i++) af[i]  = *(const short8*)&As[wm*64+i*16+n][ksub*32+qd*8];
      #pragma unroll
      for (int j=0;j<4;j++) bfr[j] = *(const short8*)&Bs[wn*64+j*16+n][ksub*32+qd*8];
      #pragma unroll
      for (int i=0;i<4;i++)
        #pragma unroll
        for (int j=0;j<4;j++) acc[i][j] = mfma16(af[i], bfr[j], acc[i][j]);
    }
    __syncthreads();
  }
  #pragma unroll
  for (int i=0;i<4;i++){
    #pragma unroll
    for (int j=0;j<4;j++){
      int c = c0 + wn*64 + j*16 + n;
      #pragma unroll
      for (int rg=0; rg<4; rg++){
        int r = r0 + wm*64 + i*16 + qd*4 + rg;
        out[(size_t)r*512 + c] = acc[i][j][rg] + bias[c] + xin[(size_t)r*512 + c];
      }
    }
  }
}

extern "C" void kernel_launch(void* const* d_in, const int* in_sizes, int n_in,
                              void* d_out, int out_size, void* d_ws, size_t ws_size,
                              hipStream_t stream) {
  const float* x     = (const float*)d_in[0];
  const float* gamma = (const float*)d_in[1];
  const float* beta  = (const float*)d_in[2];
  const float* wqkv  = (const float*)d_in[3];
  const float* resk  = (const float*)d_in[4];
  const float* wout  = (const float*)d_in[5];
  const float* bout  = (const float*)d_in[6];
  float* out = (float*)d_out;

  const size_t SL = (size_t)B_*H_*N_*DH_;
  const size_t SM = (size_t)B_*H_*M_*DH_;
  const size_t SP = (size_t)B_*H_*M_*M_;

  bf16* xn  = (bf16*)d_ws;     // reused as: flash partial OP, then pinv P1..P4, then outh
  bf16* q   = xn + SL;
  bf16* k   = q + SL;
  bf16* v   = k + SL;
  bf16* vT  = v + SL;
  bf16* ql  = vT + SL;
  bf16* kl  = ql + SM;
  bf16* kv3 = kl + SM;
  bf16* z2T = kv3 + SM;
  float* A2 = (float*)(z2T + SM);
  bf16* WT  = (bf16*)(A2 + SP);       // 1536 x 512 bf16
  bf16* WT2 = WT + (size_t)1536*512;  // 512 x 512 bf16
  float* P1 = (float*)xn;             // pinv scratch aliases xn (4*SP*4B == SL*2B)
  float* P2 = P1 + SP;
  float* P3 = P2 + SP;
  float* P4 = P3 + SP;
  float* OPp = (float*)xn;
  float* MPp = (float*)z2T;
  float* LPp = MPp + (size_t)NSPLIT*B_*H_*M_;

  k_wt<<<dim3(24, 8), 256, 0, stream>>>(wqkv, WT, 512, 1536);
  k_wt<<<dim3(8, 8), 256, 0, stream>>>(wout, WT2, 512, 512);
  k_layernorm<<<B_*N_, 256, 0, stream>>>(x, gamma, beta, xn);
  k_mm_qkv2<<<dim3(256, 12), 256, 0, stream>>>(xn, WT, q, k, v);
  k_transp_v<<<dim3(128, 32), 256, 0, stream>>>(v, vT);
  k_landmark<<<B_*H_*M_, 64, 0, stream>>>(q, k, ql, kl);

  // attn3 flash (split + merge) runs BEFORE pinv so partials can use the dead xn/z2T regions
  k_flash_split<<<dim3(NSPLIT, B_*H_), 256, 0, stream>>>(ql, k, vT, OPp, MPp, LPp);
  k_flash_merge<<<dim3(M_/4, B_*H_), 256, 0, stream>>>(OPp, MPp, LPp, kv3);

  k_attn2<<<B_*H_*M_, 256, 0, stream>>>(ql, kl, A2);
  k_pinv_init<<<B_*H_, 256, 0, stream>>>(A2, P1);

  // fused 6-iteration Newton-Schulz in one cooperative launch (fallback: 24 launches)
  {
    const float* A2c = A2;
    void* cargs[] = { (void*)&A2c, (void*)&P1, (void*)&P2, (void*)&P3, (void*)&P4 };
    hipError_t cerr = hipLaunchCooperativeKernel((const void*)k_pinv_fused,
                        dim3(512), dim3(256), cargs, 0, stream);
    if (cerr != hipSuccess){
      float* Zi = P1; float* Zo = P3;
      for (int it=0; it<6; ++it){
        int sp = (it < 4) ? 0 : 1;
        k_gemm_pm<<<dim3(16,32), 256, 0, stream>>>(P2, A2, Zi, 0.f,0, 0.f,0, 1.f, sp);
        k_gemm_pm<<<dim3(16,32), 256, 0, stream>>>(Zo, P2, P2, 7.f,1, 15.f,1, 1.f, sp);
        k_gemm_pm<<<dim3(16,32), 256, 0, stream>>>(P4, P2, Zo, 0.f,0, 13.f,1, 1.f, sp);
        k_gemm_pm<<<dim3(16,32), 256, 0, stream>>>(Zo, Zi, P4, 0.f,0, 0.f,0, 0.25f, sp);
        float* tt = Zi; Zi = Zo; Zo = tt;
      }
    }
  }

  k_gemm_z2<<<dim3(4, B_*H_), 256, 0, stream>>>(z2T, P1, kv3);
  k_flash_w3<<<dim3(N_/256, B_*H_), 256, 0, stream>>>(q, kl, z2T, xn);
  k_conv_add<<<dim3(N_/CCH, B_*H_), 256, 0, stream>>>(v, resk, xn);
  k_mm_out2<<<dim3(256, 4), 256, 0, stream>>>(xn, WT2, bout, x, out);
}

// Round 5
// 889.914 us; speedup vs baseline: 2.5193x; 2.5193x over previous
//
#include <hip/hip_runtime.h>
#include <hip/hip_bf16.h>

#define B_ 4
#define N_ 8192
#define D_ 512
#define H_ 8
#define DH_ 64
#define M_ 256
#define LCH 32
#define KER_ 33
#define NSPLIT 16
#define CS (N_/NSPLIT)   // 512 cols per split chunk

typedef __hip_bfloat16 bf16;
typedef __attribute__((ext_vector_type(8))) short short8;
typedef __attribute__((ext_vector_type(4))) float f32x4;

__device__ __forceinline__ float bf2f(bf16 h){ return __bfloat162float(h); }
__device__ __forceinline__ bf16 f2bf(float f){ return __float2bfloat16(f); }
__device__ __forceinline__ f32x4 mfma16(short8 a, short8 b, f32x4 c){
  return __builtin_amdgcn_mfma_f32_16x16x32_bf16(a, b, c, 0, 0, 0);
}

// ---------------- LayerNorm: x (b,n,512) fp32 -> xn bf16 ----------------
__global__ __launch_bounds__(256) void k_layernorm(const float* __restrict__ x,
    const float* __restrict__ gamma, const float* __restrict__ beta,
    bf16* __restrict__ xn){
  int row = blockIdx.x;
  const float* xr = x + (size_t)row * D_;
  bf16* o = xn + (size_t)row * D_;
  int t = threadIdx.x;
  float v0 = xr[t], v1 = xr[t+256];
  float s = v0+v1, ss = v0*v0 + v1*v1;
  __shared__ float sh[8];
  for (int off=32; off; off>>=1){ s += __shfl_xor(s,off); ss += __shfl_xor(ss,off); }
  int lane = t&63, wid = t>>6;
  if (lane==0){ sh[wid] = s; sh[wid+4] = ss; }
  __syncthreads();
  float S  = sh[0]+sh[1]+sh[2]+sh[3];
  float SS = sh[4]+sh[5]+sh[6]+sh[7];
  float mu = S*(1.f/D_);
  float var = SS*(1.f/D_) - mu*mu;
  float rs = rsqrtf(var + 1e-5f);
  o[t]     = f2bf((v0-mu)*rs*gamma[t]     + beta[t]);
  o[t+256] = f2bf((v1-mu)*rs*gamma[t+256] + beta[t+256]);
}

// ---------------- W transpose+convert: W (RxC fp32) -> WT (CxR bf16) ----------------
__global__ __launch_bounds__(256) void k_wt(const float* __restrict__ W, bf16* __restrict__ WT,
    int R, int C){
  int c0 = blockIdx.x*64, r0 = blockIdx.y*64;
  __shared__ float tile[64][65];
  int t = threadIdx.x;
  for (int i=t;i<4096;i+=256){ int r=i>>6, c=i&63; tile[r][c] = W[(size_t)(r0+r)*C + c0+c]; }
  __syncthreads();
  for (int i=t;i<512;i+=256){
    int c=i>>3, rg=i&7;
    short8 o;
    #pragma unroll
    for (int j=0;j<8;j++) ((bf16*)&o)[j] = f2bf(tile[rg*8+j][c]);
    *(short8*)&WT[(size_t)(c0+c)*R + r0 + rg*8] = o;
  }
}

// ---------------- QKV GEMM (MFMA, reg-staged, padded LDS): xn @ WT^T -> q,k,v ----------------
// grid (12, 256): consecutive blocks share the A row-panel -> A stays L2-resident (one HBM pass).
__global__ __launch_bounds__(256) void k_mm_qkv2(const bf16* __restrict__ A, const bf16* __restrict__ WT,
    bf16* __restrict__ qbuf, bf16* __restrict__ kbuf, bf16* __restrict__ vbuf){
  __shared__ __align__(16) bf16 As[128][72];
  __shared__ __align__(16) bf16 Bs[128][72];
  int t = threadIdx.x;
  int w = t>>6, lane = t&63, qd = lane>>4, n = lane&15;
  int wm = w>>1, wn = w&1;
  int r0 = blockIdx.y*128, c0 = blockIdx.x*128;
  f32x4 acc[4][4];
  #pragma unroll
  for (int i=0;i<4;i++)
    #pragma unroll
    for (int j=0;j<4;j++) acc[i][j] = (f32x4){0.f,0.f,0.f,0.f};
  int srow = t>>3, skc = t&7;
  for (int k0=0; k0<512; k0+=64){
    #pragma unroll
    for (int ch=0; ch<4; ch++){
      int m = ch*32 + srow;
      *(short8*)&As[m][skc*8] = *(const short8*)&A[(size_t)(r0+m)*512 + k0 + skc*8];
      *(short8*)&Bs[m][skc*8] = *(const short8*)&WT[(size_t)(c0+m)*512 + k0 + skc*8];
    }
    __syncthreads();
    #pragma unroll
    for (int ksub=0; ksub<2; ksub++){
      short8 af[4], bfr[4];
      #pragma unroll
      for (int i=0;i<4;i++) af[i]  = *(const short8*)&As[wm*64+i*16+n][ksub*32+qd*8];
      #pragma unroll
      for (int j=0;j<4;j++) bfr[j] = *(const short8*)&Bs[wn*64+j*16+n][ksub*32+qd*8];
      #pragma unroll
      for (int i=0;i<4;i++)
        #pragma unroll
        for (int j=0;j<4;j++) acc[i][j] = mfma16(af[i], bfr[j], acc[i][j]);
    }
    __syncthreads();
  }
  int part = c0 >> 9;
  bf16* dst = (part==0)? qbuf : (part==1)? kbuf : vbuf;
  float scale = (part==0)? 0.125f : 1.f;
  #pragma unroll
  for (int i=0;i<4;i++){
    #pragma unroll
    for (int j=0;j<4;j++){
      int c = c0 + wn*64 + j*16 + n;
      int cc = c & 511, h = cc>>6, dh = cc&63;
      #pragma unroll
      for (int rg=0; rg<4; rg++){
        int r = r0 + wm*64 + i*16 + qd*4 + rg;
        int b = r >> 13, nn = r & 8191;
        dst[(((size_t)(b*H_+h))*N_ + nn)*DH_ + dh] = f2bf(acc[i][j][rg]*scale);
      }
    }
  }
}

// ---------------- v -> vT tiled transpose (64x64) ----------------
__global__ __launch_bounds__(256) void k_transp_v(const bf16* __restrict__ v, bf16* __restrict__ vT){
  int bh = blockIdx.y, n0 = blockIdx.x*64;
  __shared__ bf16 tile[64][72];
  const bf16* vb = v + (size_t)bh*N_*DH_;
  int t = threadIdx.x;
  for (int i=t; i<512; i+=256){
    int r = i>>3, cg = i&7;
    *(short8*)&tile[r][cg*8] = *(const short8*)&vb[(size_t)(n0+r)*DH_ + cg*8];
  }
  __syncthreads();
  bf16* ob = vT + (size_t)bh*DH_*N_;
  for (int i=t; i<512; i+=256){
    int dh = i>>3, ng = i&7;
    short8 o;
    #pragma unroll
    for (int j=0;j<8;j++) ((bf16*)&o)[j] = tile[ng*8+j][dh];
    *(short8*)&ob[(size_t)dh*N_ + n0 + ng*8] = o;
  }
}

// ---------------- landmark means over contiguous 32-row chunks ----------------
__global__ __launch_bounds__(64) void k_landmark(const bf16* __restrict__ q, const bf16* __restrict__ k,
    bf16* __restrict__ ql, bf16* __restrict__ kl){
  int bhm = blockIdx.x;
  int bh = bhm >> 8, m = bhm & 255;
  int dh = threadIdx.x;
  const bf16* qp = q + ((size_t)bh*N_ + (size_t)m*LCH)*DH_ + dh;
  const bf16* kp = k + ((size_t)bh*N_ + (size_t)m*LCH)*DH_ + dh;
  float sq=0.f, sk=0.f;
  #pragma unroll
  for (int j=0;j<LCH;j++){ sq += bf2f(qp[(size_t)j*DH_]); sk += bf2f(kp[(size_t)j*DH_]); }
  ql[((size_t)bh*M_ + m)*DH_ + dh] = f2bf(sq*(1.f/LCH));
  kl[((size_t)bh*M_ + m)*DH_ + dh] = f2bf(sk*(1.f/LCH));
}

// ---------------- attn2 = softmax(q_l @ k_l^T) rows (fp32 out) ----------------
__global__ __launch_bounds__(256) void k_attn2(const bf16* __restrict__ ql, const bf16* __restrict__ kl,
    float* __restrict__ A2){
  int bhm = blockIdx.x;
  int bh = bhm >> 8, m = bhm & 255;
  int t = threadIdx.x;
  __shared__ float qrow[64];
  __shared__ float sh[4];
  if (t < 64) qrow[t] = bf2f(ql[((size_t)bh*M_ + m)*DH_ + t]);
  __syncthreads();
  const bf16* krow = kl + ((size_t)bh*M_ + t)*DH_;
  float s = 0.f;
  #pragma unroll
  for (int i=0;i<64;i++) s += qrow[i]*bf2f(krow[i]);
  float mx = s;
  for (int off=32; off; off>>=1) mx = fmaxf(mx, __shfl_xor(mx, off));
  if ((t&63)==0) sh[t>>6] = mx;
  __syncthreads();
  mx = fmaxf(fmaxf(sh[0],sh[1]), fmaxf(sh[2],sh[3]));
  float e = expf(s - mx);
  float sum = e;
  for (int off=32; off; off>>=1) sum += __shfl_xor(sum, off);
  __syncthreads();
  if ((t&63)==0) sh[t>>6] = sum;
  __syncthreads();
  sum = sh[0]+sh[1]+sh[2]+sh[3];
  A2[((size_t)bh*M_ + m)*M_ + t] = e/sum;
}

// ---------------- pinv init: Z = A^T / (max_rowsum * max_colsum) ----------------
__global__ __launch_bounds__(256) void k_pinv_init(const float* __restrict__ A2, float* __restrict__ Z){
  int bh = blockIdx.x;
  int t = threadIdx.x;
  const float* Ab = A2 + (size_t)bh*M_*M_;
  float* Zb = Z + (size_t)bh*M_*M_;
  float cs=0.f, rsm=0.f;
  for (int r=0;r<M_;r++) cs += fabsf(Ab[(size_t)r*M_ + t]);
  for (int c=0;c<M_;c++) rsm += fabsf(Ab[(size_t)t*M_ + c]);
  __shared__ float sh[4];
  float v = cs;
  for (int off=32; off; off>>=1) v = fmaxf(v, __shfl_xor(v, off));
  if ((t&63)==0) sh[t>>6] = v;
  __syncthreads();
  float maxc = fmaxf(fmaxf(sh[0],sh[1]), fmaxf(sh[2],sh[3]));
  __syncthreads();
  v = rsm;
  for (int off=32; off; off>>=1) v = fmaxf(v, __shfl_xor(v, off));
  if ((t&63)==0) sh[t>>6] = v;
  __syncthreads();
  float maxr = fmaxf(fmaxf(sh[0],sh[1]), fmaxf(sh[2],sh[3]));
  float inv = 1.f/(maxr*maxc);
  for (int r=0;r<M_;r++) Zb[(size_t)r*M_ + t] = Ab[(size_t)t*M_ + r]*inv;
}

// ---------------- pinv GEMM (bf16 MFMA; optional hi/lo split precision) ----------------
// C = cScale*(cNeg? cDiag*I - A@B' : A@B'), B' = bNeg? bDiag*I-B : B
// NOTE (round 4): do NOT fuse these via cooperative grid.sync — the device-scope fences
// defeat cross-XCD cache reuse (560MB HBM refetch, 23x slower). 24 small launches win.
__global__ __launch_bounds__(256) void k_gemm_pm(float* __restrict__ C, const float* __restrict__ A,
    const float* __restrict__ Bm, float bDiag, int bNeg, float cDiag, int cNeg, float cScale,
    int split){
  int bh = blockIdx.y;
  int tm = blockIdx.x >> 2, tn = blockIdx.x & 3;
  const float* Ab = A  + (size_t)bh*65536;
  const float* Bb = Bm + (size_t)bh*65536;
  float* Cb = C + (size_t)bh*65536;
  __shared__ __align__(16) bf16 Ah[64][72];
  __shared__ __align__(16) bf16 Al[64][72];
  __shared__ __align__(16) bf16 Bh[64][72];
  __shared__ __align__(16) bf16 Bl[64][72];
  int t = threadIdx.x;
  int w = t>>6, lane = t&63, qd = lane>>4, n = lane&15;
  int wm = w>>1, wn = w&1;
  int r0 = tm*64, c0 = tn*64;
  f32x4 acc[2][2];
  #pragma unroll
  for (int i=0;i<2;i++)
    #pragma unroll
    for (int j=0;j<2;j++) acc[i][j] = (f32x4){0.f,0.f,0.f,0.f};
  int srow = t>>3, skc = t&7;
  for (int k0=0; k0<256; k0+=64){
    #pragma unroll
    for (int ch=0; ch<2; ch++){
      int m = ch*32 + srow;
      short8 vh, vl;
      const float* ap = &Ab[(size_t)(r0+m)*256 + k0 + skc*8];
      #pragma unroll
      for (int j=0;j<8;j++){
        float x = ap[j];
        bf16 h = f2bf(x);
        ((bf16*)&vh)[j] = h;
        if (split) ((bf16*)&vl)[j] = f2bf(x - bf2f(h));
      }
      *(short8*)&Ah[m][skc*8] = vh;
      if (split) *(short8*)&Al[m][skc*8] = vl;
      const float* bp = &Bb[(size_t)(k0+m)*256 + c0 + skc*8];
      int kr = k0 + m;
      #pragma unroll
      for (int j=0;j<8;j++){
        float x = bp[j];
        if (bNeg) x = (kr == (c0 + skc*8 + j) ? bDiag : 0.f) - x;
        bf16 h = f2bf(x);
        ((bf16*)&vh)[j] = h;
        if (split) ((bf16*)&vl)[j] = f2bf(x - bf2f(h));
      }
      #pragma unroll
      for (int j=0;j<8;j++){
        Bh[skc*8+j][m] = ((bf16*)&vh)[j];
        if (split) Bl[skc*8+j][m] = ((bf16*)&vl)[j];
      }
    }
    __syncthreads();
    #pragma unroll
    for (int ksub=0; ksub<2; ksub++){
      short8 afh[2], afl[2], bfh[2], bfl[2];
      #pragma unroll
      for (int i=0;i<2;i++){
        afh[i] = *(const short8*)&Ah[wm*32+i*16+n][ksub*32+qd*8];
        if (split) afl[i] = *(const short8*)&Al[wm*32+i*16+n][ksub*32+qd*8];
      }
      #pragma unroll
      for (int j=0;j<2;j++){
        bfh[j] = *(const short8*)&Bh[wn*32+j*16+n][ksub*32+qd*8];
        if (split) bfl[j] = *(const short8*)&Bl[wn*32+j*16+n][ksub*32+qd*8];
      }
      #pragma unroll
      for (int i=0;i<2;i++)
        #pragma unroll
        for (int j=0;j<2;j++){
          if (split){
            acc[i][j] = mfma16(afl[i], bfh[j], acc[i][j]);
            acc[i][j] = mfma16(afh[i], bfl[j], acc[i][j]);
          }
          acc[i][j] = mfma16(afh[i], bfh[j], acc[i][j]);
        }
    }
    __syncthreads();
  }
  #pragma unroll
  for (int i=0;i<2;i++){
    #pragma unroll
    for (int j=0;j<2;j++){
      int cidx = c0 + wn*32 + j*16 + n;
      #pragma unroll
      for (int rg=0; rg<4; rg++){
        int r = r0 + wm*32 + i*16 + qd*4 + rg;
        float r_ = acc[i][j][rg];
        if (cNeg) r_ = ((r==cidx)? cDiag : 0.f) - r_;
        Cb[(size_t)r*256 + cidx] = r_*cScale;
      }
    }
  }
}

// ---------------- batched GEMM 256x64x256: z2T = (Z @ kv3)^T ----------------
__global__ __launch_bounds__(256) void k_gemm_z2(bf16* __restrict__ z2t, const float* __restrict__ A,
    const bf16* __restrict__ Bm){
  int bh = blockIdx.y;
  int tm = blockIdx.x;
  const float* Ab = A  + (size_t)bh*65536;
  const bf16* Bb = Bm + (size_t)bh*M_*DH_;
  __shared__ float As[16][68];
  __shared__ float Bs[16][64];
  int t = threadIdx.x, tx = t&15, ty = t>>4;
  int r0 = tm*64;
  float acc[4][4] = {};
  for (int k0=0;k0<256;k0+=16){
    for (int i=t;i<1024;i+=256){
      int m=i>>4, kq=i&15;
      As[kq][m] = Ab[(size_t)(r0+m)*256 + k0+kq];
      int nn=i&63, k2=i>>6;
      Bs[k2][nn] = bf2f(Bb[(size_t)(k0+k2)*64 + nn]);
    }
    __syncthreads();
    #pragma unroll
    for (int kq=0;kq<16;kq++){
      float a0[4], b0[4];
      #pragma unroll
      for (int i=0;i<4;i++) a0[i] = As[kq][ty*4+i];
      #pragma unroll
      for (int j=0;j<4;j++) b0[j] = Bs[kq][tx*4+j];
      #pragma unroll
      for (int i=0;i<4;i++)
        #pragma unroll
        for (int j=0;j<4;j++) acc[i][j] += a0[i]*b0[j];
    }
    __syncthreads();
  }
  #pragma unroll
  for (int i=0;i<4;i++){
    int r = r0+ty*4+i;
    #pragma unroll
    for (int j=0;j<4;j++)
      z2t[(size_t)bh*16384 + (size_t)(tx*4+j)*256 + r] = f2bf(acc[i][j]);
  }
}

// ---------------- attn3 flash, flash-decoding split over columns ----------------
__global__ __launch_bounds__(256, 2) void k_flash_split(const bf16* __restrict__ Q,
    const bf16* __restrict__ K, const bf16* __restrict__ VT,
    float* __restrict__ OP, float* __restrict__ MP, float* __restrict__ LP){
  int bh = blockIdx.y;
  int sp = blockIdx.x;
  int t = threadIdx.x, w = t>>6, lane = t&63, qd = lane>>4, n = lane&15;
  int r0 = w*64;
  const size_t Qoff = ((size_t)bh*M_ + r0)*DH_;
  const size_t Koff = ((size_t)bh*N_ + (size_t)sp*CS)*DH_;
  const size_t Voff = (size_t)bh*DH_*N_ + (size_t)sp*CS;
  __shared__ __align__(16) bf16 pbuf[4][4][16][72];
  short8 aq[4][2];
  #pragma unroll
  for (int rt=0; rt<4; rt++){
    aq[rt][0] = *(const short8*)&Q[Qoff + (size_t)(rt*16+n)*DH_ + qd*8];
    aq[rt][1] = *(const short8*)&Q[Qoff + (size_t)(rt*16+n)*DH_ + 32 + qd*8];
  }
  f32x4 o[4][4];
  float mrun[4][4], lrun[4][4];
  #pragma unroll
  for (int rt=0; rt<4; rt++){
    #pragma unroll
    for (int j=0;j<4;j++){ o[rt][j] = (f32x4){0.f,0.f,0.f,0.f}; mrun[rt][j] = -1e30f; lrun[rt][j] = 0.f; }
  }
  for (int tl=0; tl<CS/64; ++tl){
    const bf16* kp = K + Koff + (size_t)(tl*64)*DH_;
    short8 kb[4][2];
    #pragma unroll
    for (int cg=0; cg<4; cg++){
      kb[cg][0] = *(const short8*)&kp[(size_t)(cg*16+n)*DH_ + qd*8];
      kb[cg][1] = *(const short8*)&kp[(size_t)(cg*16+n)*DH_ + 32 + qd*8];
    }
    #pragma unroll
    for (int rt=0; rt<4; rt++){
      f32x4 s[4];
      #pragma unroll
      for (int cg=0; cg<4; cg++){
        f32x4 z = (f32x4){0.f,0.f,0.f,0.f};
        z = mfma16(aq[rt][0], kb[cg][0], z);
        z = mfma16(aq[rt][1], kb[cg][1], z);
        s[cg] = z;
      }
      float alpha[4];
      #pragma unroll
      for (int rg=0; rg<4; rg++){
        float smax = fmaxf(fmaxf(s[0][rg],s[1][rg]), fmaxf(s[2][rg],s[3][rg]));
        smax = fmaxf(smax, __shfl_xor(smax, 1));
        smax = fmaxf(smax, __shfl_xor(smax, 2));
        smax = fmaxf(smax, __shfl_xor(smax, 4));
        smax = fmaxf(smax, __shfl_xor(smax, 8));
        float mn = fmaxf(mrun[rt][rg], smax);
        float p0 = __expf(s[0][rg]-mn), p1 = __expf(s[1][rg]-mn);
        float p2 = __expf(s[2][rg]-mn), p3 = __expf(s[3][rg]-mn);
        float ts = p0+p1+p2+p3;
        ts += __shfl_xor(ts,1); ts += __shfl_xor(ts,2);
        ts += __shfl_xor(ts,4); ts += __shfl_xor(ts,8);
        float al = __expf(mrun[rt][rg]-mn);
        lrun[rt][rg] = lrun[rt][rg]*al + ts;
        mrun[rt][rg] = mn;
        alpha[rg] = al;
        pbuf[w][rt][qd*4+rg][n]    = f2bf(p0);
        pbuf[w][rt][qd*4+rg][16+n] = f2bf(p1);
        pbuf[w][rt][qd*4+rg][32+n] = f2bf(p2);
        pbuf[w][rt][qd*4+rg][48+n] = f2bf(p3);
      }
      #pragma unroll
      for (int dg=0; dg<4; dg++)
        #pragma unroll
        for (int rg=0; rg<4; rg++) o[rt][dg][rg] *= alpha[rg];
    }
    const bf16* vp = VT + Voff + tl*64 + qd*8;
    short8 vb[4][2];
    #pragma unroll
    for (int dg=0; dg<4; dg++){
      vb[dg][0] = *(const short8*)&vp[(size_t)(dg*16+n)*N_];
      vb[dg][1] = *(const short8*)&vp[(size_t)(dg*16+n)*N_ + 32];
    }
    #pragma unroll
    for (int rt=0; rt<4; rt++){
      short8 ap0 = *(const short8*)&pbuf[w][rt][n][qd*8];
      short8 ap1 = *(const short8*)&pbuf[w][rt][n][32+qd*8];
      #pragma unroll
      for (int dg=0; dg<4; dg++){
        o[rt][dg] = mfma16(ap0, vb[dg][0], o[rt][dg]);
        o[rt][dg] = mfma16(ap1, vb[dg][1], o[rt][dg]);
      }
    }
  }
  size_t base = ((size_t)sp*(B_*H_) + bh)*M_;
  #pragma unroll
  for (int rt=0; rt<4; rt++){
    #pragma unroll
    for (int rg=0; rg<4; rg++){
      int row = r0 + rt*16 + qd*4 + rg;
      if (n==0){ MP[base+row] = mrun[rt][rg]; LP[base+row] = lrun[rt][rg]; }
      #pragma unroll
      for (int dg=0; dg<4; dg++)
        OP[(base+row)*DH_ + dg*16 + n] = o[rt][dg][rg];
    }
  }
}

// ---------------- merge NSPLIT flash partials -> kv3 ----------------
__global__ __launch_bounds__(256) void k_flash_merge(const float* __restrict__ OP,
    const float* __restrict__ MP, const float* __restrict__ LP, bf16* __restrict__ O){
  int bh = blockIdx.y;
  int r = blockIdx.x*4 + (threadIdx.x>>6);
  int dh = threadIdx.x & 63;
  float M = -1e30f, acc = 0.f, den = 0.f;
  for (int s=0; s<NSPLIT; s++){
    size_t base = ((size_t)s*(B_*H_) + bh)*M_ + r;
    float m = MP[base];
    float l = LP[base];
    float ov = OP[base*DH_ + dh];
    float Mn = fmaxf(M, m);
    float wo = __expf(M - Mn), wn = __expf(m - Mn);
    acc = acc*wo + ov*wn;
    den = den*wo + l*wn;
    M = Mn;
  }
  O[((size_t)bh*M_ + r)*DH_ + dh] = f2bf(acc/den);
}

// ---------------- attn1 flash, split-structured: 4 waves x 4 rowtiles, 64-col tiles ----------------
__global__ __launch_bounds__(256, 2) void k_flash_w3(const bf16* __restrict__ Q,
    const bf16* __restrict__ K, const bf16* __restrict__ VT, bf16* __restrict__ O){
  int bh = blockIdx.y;
  int t = threadIdx.x, w = t>>6, lane = t&63, qd = lane>>4, n = lane&15;
  int r0 = blockIdx.x*256 + w*64;
  const size_t Qoff = ((size_t)bh*N_ + r0)*DH_;
  const size_t Koff = (size_t)bh*M_*DH_;
  const size_t Voff = (size_t)bh*DH_*M_;
  __shared__ __align__(16) bf16 pbuf[4][4][16][72];
  short8 aq[4][2];
  #pragma unroll
  for (int rt=0; rt<4; rt++){
    aq[rt][0] = *(const short8*)&Q[Qoff + (size_t)(rt*16+n)*DH_ + qd*8];
    aq[rt][1] = *(const short8*)&Q[Qoff + (size_t)(rt*16+n)*DH_ + 32 + qd*8];
  }
  f32x4 o[4][4];
  float mrun[4][4], lrun[4][4];
  #pragma unroll
  for (int rt=0; rt<4; rt++){
    #pragma unroll
    for (int j=0;j<4;j++){ o[rt][j] = (f32x4){0.f,0.f,0.f,0.f}; mrun[rt][j] = -1e30f; lrun[rt][j] = 0.f; }
  }
  #pragma unroll
  for (int tl=0; tl<4; ++tl){
    const bf16* kp = K + Koff + (size_t)(tl*64)*DH_;
    short8 kb[4][2];
    #pragma unroll
    for (int cg=0; cg<4; cg++){
      kb[cg][0] = *(const short8*)&kp[(size_t)(cg*16+n)*DH_ + qd*8];
      kb[cg][1] = *(const short8*)&kp[(size_t)(cg*16+n)*DH_ + 32 + qd*8];
    }
    #pragma unroll
    for (int rt=0; rt<4; rt++){
      f32x4 s[4];
      #pragma unroll
      for (int cg=0; cg<4; cg++){
        f32x4 z = (f32x4){0.f,0.f,0.f,0.f};
        z = mfma16(aq[rt][0], kb[cg][0], z);
        z = mfma16(aq[rt][1], kb[cg][1], z);
        s[cg] = z;
      }
      float alpha[4];
      #pragma unroll
      for (int rg=0; rg<4; rg++){
        float smax = fmaxf(fmaxf(s[0][rg],s[1][rg]), fmaxf(s[2][rg],s[3][rg]));
        smax = fmaxf(smax, __shfl_xor(smax, 1));
        smax = fmaxf(smax, __shfl_xor(smax, 2));
        smax = fmaxf(smax, __shfl_xor(smax, 4));
        smax = fmaxf(smax, __shfl_xor(smax, 8));
        float mn = fmaxf(mrun[rt][rg], smax);
        float p0 = __expf(s[0][rg]-mn), p1 = __expf(s[1][rg]-mn);
        float p2 = __expf(s[2][rg]-mn), p3 = __expf(s[3][rg]-mn);
        float ts = p0+p1+p2+p3;
        ts += __shfl_xor(ts,1); ts += __shfl_xor(ts,2);
        ts += __shfl_xor(ts,4); ts += __shfl_xor(ts,8);
        float al = __expf(mrun[rt][rg]-mn);
        lrun[rt][rg] = lrun[rt][rg]*al + ts;
        mrun[rt][rg] = mn;
        alpha[rg] = al;
        pbuf[w][rt][qd*4+rg][n]    = f2bf(p0);
        pbuf[w][rt][qd*4+rg][16+n] = f2bf(p1);
        pbuf[w][rt][qd*4+rg][32+n] = f2bf(p2);
        pbuf[w][rt][qd*4+rg][48+n] = f2bf(p3);
      }
      #pragma unroll
      for (int dg=0; dg<4; dg++)
        #pragma unroll
        for (int rg=0; rg<4; rg++) o[rt][dg][rg] *= alpha[rg];
    }
    const bf16* vp = VT + Voff + tl*64 + qd*8;
    short8 vb[4][2];
    #pragma unroll
    for (int dg=0; dg<4; dg++){
      vb[dg][0] = *(const short8*)&vp[(size_t)(dg*16+n)*M_];
      vb[dg][1] = *(const short8*)&vp[(size_t)(dg*16+n)*M_ + 32];
    }
    #pragma unroll
    for (int rt=0; rt<4; rt++){
      short8 ap0 = *(const short8*)&pbuf[w][rt][n][qd*8];
      short8 ap1 = *(const short8*)&pbuf[w][rt][n][32+qd*8];
      #pragma unroll
      for (int dg=0; dg<4; dg++){
        o[rt][dg] = mfma16(ap0, vb[dg][0], o[rt][dg]);
        o[rt][dg] = mfma16(ap1, vb[dg][1], o[rt][dg]);
      }
    }
  }
  #pragma unroll
  for (int rt=0; rt<4; rt++){
    #pragma unroll
    for (int rg=0; rg<4; rg++){
      float inv = 1.f/lrun[rt][rg];
      size_t rowoff = ((size_t)bh*N_ + r0 + rt*16 + qd*4 + rg)*DH_;
      #pragma unroll
      for (int dg=0; dg<4; dg++)
        O[rowoff + dg*16 + n] = f2bf(o[rt][dg][rg]*inv);
    }
  }
}

// ---------------- depthwise conv(KER=33), LDS-tiled, vectorized RMW into outh ----------------
#define CCH 256
__global__ __launch_bounds__(256) void k_conv_add(const bf16* __restrict__ v, const float* __restrict__ w,
    bf16* __restrict__ outh){
  int bh = blockIdx.y;
  int n0 = blockIdx.x * CCH;
  int h = bh & 7;
  __shared__ bf16 vs[CCH+32][72];
  __shared__ float wk[KER_];
  int t = threadIdx.x;
  if (t < KER_) wk[t] = w[h*KER_ + t];
  const bf16* vb = v + (size_t)bh*N_*DH_;
  for (int i=t; i<(CCH+32)*8; i+=256){
    int r = i>>3, cg = i&7;
    int nn = n0 - 16 + r;
    short8 val = {0,0,0,0,0,0,0,0};
    if (nn >= 0 && nn < N_) val = *(const short8*)&vb[(size_t)nn*DH_ + cg*8];
    *(short8*)&vs[r][cg*8] = val;
  }
  __syncthreads();
  int dhg = t & 7, rowg = t >> 3;
  bf16* ob = outh + ((size_t)bh*N_ + n0)*DH_;
  #pragma unroll
  for (int rr=0; rr<8; rr++){
    int lr = rowg*8 + rr;
    float acc[8] = {0.f,0.f,0.f,0.f,0.f,0.f,0.f,0.f};
    for (int tt=0; tt<KER_; tt++){
      short8 vv = *(const short8*)&vs[lr+tt][dhg*8];
      float wt = wk[tt];
      #pragma unroll
      for (int j=0;j<8;j++) acc[j] += wt * bf2f(((bf16*)&vv)[j]);
    }
    short8 o = *(short8*)&ob[(size_t)lr*DH_ + dhg*8];
    #pragma unroll
    for (int j=0;j<8;j++) ((bf16*)&o)[j] = f2bf(bf2f(((bf16*)&o)[j]) + acc[j]);
    *(short8*)&ob[(size_t)lr*DH_ + dhg*8] = o;
  }
}

// ---------------- final GEMM (MFMA, reg-staged, padded LDS): out = x + gather(outh) @ WT2^T + b_out ----------------
// grid (4, 256): consecutive blocks share the A row-panel (same L2-locality fix as qkv).
__global__ __launch_bounds__(256) void k_mm_out2(const bf16* __restrict__ Ahd, const bf16* __restrict__ WT2,
    const float* __restrict__ bias, const float* __restrict__ xin, float* __restrict__ out){
  __shared__ __align__(16) bf16 As[128][72];
  __shared__ __align__(16) bf16 Bs[128][72];
  int t = threadIdx.x;
  int w = t>>6, lane = t&63, qd = lane>>4, n = lane&15;
  int wm = w>>1, wn = w&1;
  int r0 = blockIdx.y*128, c0 = blockIdx.x*128;
  f32x4 acc[4][4];
  #pragma unroll
  for (int i=0;i<4;i++)
    #pragma unroll
    for (int j=0;j<4;j++) acc[i][j] = (f32x4){0.f,0.f,0.f,0.f};
  int srow = t>>3, skc = t&7;
  for (int k0=0; k0<512; k0+=64){
    int h = k0 >> 6;
    #pragma unroll
    for (int ch=0; ch<4; ch++){
      int m = ch*32 + srow;
      int r = r0 + m, b = r>>13, nn = r&8191;
      *(short8*)&As[m][skc*8] = *(const short8*)&Ahd[((size_t)(b*H_+h)*N_ + nn)*DH_ + skc*8];
      *(short8*)&Bs[m][skc*8] = *(const short8*)&WT2[(size_t)(c0+m)*512 + k0 + skc*8];
    }
    __syncthreads();
    #pragma unroll
    for (int ksub=0; ksub<2; ksub++){
      short8 af[4], bfr[4];
      #pragma unroll
      for (int i=0;i<4;i++) af[i]  = *(const short8*)&As[wm*64+i*16+n][ksub*32+qd*8];
      #pragma unroll
      for (int j=0;j<4;j++) bfr[j] = *(const short8*)&Bs[wn*64+j*16+n][ksub*32+qd*8];
      #pragma unroll
      for (int i=0;i<4;i++)
        #pragma unroll
        for (int j=0;j<4;j++) acc[i][j] = mfma16(af[i], bfr[j], acc[i][j]);
    }
    __syncthreads();
  }
  #pragma unroll
  for (int i=0;i<4;i++){
    #pragma unroll
    for (int j=0;j<4;j++){
      int c = c0 + wn*64 + j*16 + n;
      #pragma unroll
      for (int rg=0; rg<4; rg++){
        int r = r0 + wm*64 + i*16 + qd*4 + rg;
        out[(size_t)r*512 + c] = acc[i][j][rg] + bias[c] + xin[(size_t)r*512 + c];
      }
    }
  }
}

extern "C" void kernel_launch(void* const* d_in, const int* in_sizes, int n_in,
                              void* d_out, int out_size, void* d_ws, size_t ws_size,
                              hipStream_t stream) {
  const float* x     = (const float*)d_in[0];
  const float* gamma = (const float*)d_in[1];
  const float* beta  = (const float*)d_in[2];
  const float* wqkv  = (const float*)d_in[3];
  const float* resk  = (const float*)d_in[4];
  const float* wout  = (const float*)d_in[5];
  const float* bout  = (const float*)d_in[6];
  float* out = (float*)d_out;

  const size_t SL = (size_t)B_*H_*N_*DH_;
  const size_t SM = (size_t)B_*H_*M_*DH_;
  const size_t SP = (size_t)B_*H_*M_*M_;

  bf16* xn  = (bf16*)d_ws;     // reused as: flash partial OP, then pinv P1..P4, then outh
  bf16* q   = xn + SL;
  bf16* k   = q + SL;
  bf16* v   = k + SL;
  bf16* vT  = v + SL;
  bf16* ql  = vT + SL;
  bf16* kl  = ql + SM;
  bf16* kv3 = kl + SM;
  bf16* z2T = kv3 + SM;
  float* A2 = (float*)(z2T + SM);
  bf16* WT  = (bf16*)(A2 + SP);       // 1536 x 512 bf16
  bf16* WT2 = WT + (size_t)1536*512;  // 512 x 512 bf16
  float* P1 = (float*)xn;             // pinv scratch aliases xn (4*SP*4B == SL*2B)
  float* P2 = P1 + SP;
  float* P3 = P2 + SP;
  float* P4 = P3 + SP;
  float* OPp = (float*)xn;
  float* MPp = (float*)z2T;
  float* LPp = MPp + (size_t)NSPLIT*B_*H_*M_;

  k_wt<<<dim3(24, 8), 256, 0, stream>>>(wqkv, WT, 512, 1536);
  k_wt<<<dim3(8, 8), 256, 0, stream>>>(wout, WT2, 512, 512);
  k_layernorm<<<B_*N_, 256, 0, stream>>>(x, gamma, beta, xn);
  k_mm_qkv2<<<dim3(12, 256), 256, 0, stream>>>(xn, WT, q, k, v);
  k_transp_v<<<dim3(128, 32), 256, 0, stream>>>(v, vT);
  k_landmark<<<B_*H_*M_, 64, 0, stream>>>(q, k, ql, kl);

  // attn3 flash (split + merge) runs BEFORE pinv so partials can use the dead xn/z2T regions
  k_flash_split<<<dim3(NSPLIT, B_*H_), 256, 0, stream>>>(ql, k, vT, OPp, MPp, LPp);
  k_flash_merge<<<dim3(M_/4, B_*H_), 256, 0, stream>>>(OPp, MPp, LPp, kv3);

  k_attn2<<<B_*H_*M_, 256, 0, stream>>>(ql, kl, A2);
  k_pinv_init<<<B_*H_, 256, 0, stream>>>(A2, P1);

  float* Zi = P1; float* Zo = P3;
  for (int it=0; it<6; ++it){
    int sp = (it < 4) ? 0 : 1;   // first 4 NS iterations plain bf16; last 2 split-precision
    k_gemm_pm<<<dim3(16,32), 256, 0, stream>>>(P2, A2, Zi, 0.f,0, 0.f,0, 1.f, sp);    // P = A2@Z
    k_gemm_pm<<<dim3(16,32), 256, 0, stream>>>(Zo, P2, P2, 7.f,1, 15.f,1, 1.f, sp);   // S = 15I - P@(7I-P)
    k_gemm_pm<<<dim3(16,32), 256, 0, stream>>>(P4, P2, Zo, 0.f,0, 13.f,1, 1.f, sp);   // U = 13I - P@S
    k_gemm_pm<<<dim3(16,32), 256, 0, stream>>>(Zo, Zi, P4, 0.f,0, 0.f,0, 0.25f, sp);  // Zn = 0.25*Z@U
    float* tt = Zi; Zi = Zo; Zo = tt;
  }

  k_gemm_z2<<<dim3(4, B_*H_), 256, 0, stream>>>(z2T, Zi, kv3);
  k_flash_w3<<<dim3(N_/256, B_*H_), 256, 0, stream>>>(q, kl, z2T, xn);
  k_conv_add<<<dim3(N_/CCH, B_*H_), 256, 0, stream>>>(v, resk, xn);
  k_mm_out2<<<dim3(4, 256), 256, 0, stream>>>(xn, WT2, bout, x, out);
}

// Round 6
// 887.741 us; speedup vs baseline: 2.5255x; 1.0024x over previous
//
#include <hip/hip_runtime.h>
#include <hip/hip_bf16.h>

#define B_ 4
#define N_ 8192
#define D_ 512
#define H_ 8
#define DH_ 64
#define M_ 256
#define LCH 32
#define KER_ 33
#define NSPLIT 16
#define CS (N_/NSPLIT)   // 512 cols per split chunk

typedef __hip_bfloat16 bf16;
typedef __attribute__((ext_vector_type(8))) short short8;
typedef __attribute__((ext_vector_type(4))) float f32x4;

__device__ __forceinline__ float bf2f(bf16 h){ return __bfloat162float(h); }
__device__ __forceinline__ bf16 f2bf(float f){ return __float2bfloat16(f); }
__device__ __forceinline__ f32x4 mfma16(short8 a, short8 b, f32x4 c){
  return __builtin_amdgcn_mfma_f32_16x16x32_bf16(a, b, c, 0, 0, 0);
}

// ---------------- LayerNorm: x (b,n,512) fp32 -> xn bf16 ----------------
__global__ __launch_bounds__(256) void k_layernorm(const float* __restrict__ x,
    const float* __restrict__ gamma, const float* __restrict__ beta,
    bf16* __restrict__ xn){
  int row = blockIdx.x;
  const float* xr = x + (size_t)row * D_;
  bf16* o = xn + (size_t)row * D_;
  int t = threadIdx.x;
  float v0 = xr[t], v1 = xr[t+256];
  float s = v0+v1, ss = v0*v0 + v1*v1;
  __shared__ float sh[8];
  for (int off=32; off; off>>=1){ s += __shfl_xor(s,off); ss += __shfl_xor(ss,off); }
  int lane = t&63, wid = t>>6;
  if (lane==0){ sh[wid] = s; sh[wid+4] = ss; }
  __syncthreads();
  float S  = sh[0]+sh[1]+sh[2]+sh[3];
  float SS = sh[4]+sh[5]+sh[6]+sh[7];
  float mu = S*(1.f/D_);
  float var = SS*(1.f/D_) - mu*mu;
  float rs = rsqrtf(var + 1e-5f);
  o[t]     = f2bf((v0-mu)*rs*gamma[t]     + beta[t]);
  o[t+256] = f2bf((v1-mu)*rs*gamma[t+256] + beta[t+256]);
}

// ---------------- W transpose+convert: W (RxC fp32) -> WT (CxR bf16) ----------------
__global__ __launch_bounds__(256) void k_wt(const float* __restrict__ W, bf16* __restrict__ WT,
    int R, int C){
  int c0 = blockIdx.x*64, r0 = blockIdx.y*64;
  __shared__ float tile[64][65];
  int t = threadIdx.x;
  for (int i=t;i<4096;i+=256){ int r=i>>6, c=i&63; tile[r][c] = W[(size_t)(r0+r)*C + c0+c]; }
  __syncthreads();
  for (int i=t;i<512;i+=256){
    int c=i>>3, rg=i&7;
    short8 o;
    #pragma unroll
    for (int j=0;j<8;j++) ((bf16*)&o)[j] = f2bf(tile[rg*8+j][c]);
    *(short8*)&WT[(size_t)(c0+c)*R + r0 + rg*8] = o;
  }
}

// ---------------- QKV GEMM (MFMA, 128x256 tile, LDS-transposed full-line epilogue) ----------------
// grid (6, 256). 2 col-subtiles/block halve B-staging per MFMA and A re-reads.
// Epilogue routes acc through LDS so q/k/v writes are full 128B lines (kills L2 write-allocate
// RMW fetches: round-5 FETCH excess ~= output size).
__global__ __launch_bounds__(256, 2) void k_mm_qkv4(const bf16* __restrict__ A, const bf16* __restrict__ WT,
    bf16* __restrict__ qbuf, bf16* __restrict__ kbuf, bf16* __restrict__ vbuf){
  __shared__ __align__(16) bf16 smem[3*128*72];
  bf16 (*As)[72]  = (bf16(*)[72])smem;
  bf16 (*Bs0)[72] = (bf16(*)[72])(smem + 128*72);
  bf16 (*Bs1)[72] = (bf16(*)[72])(smem + 2*128*72);
  bf16 (*ebuf)[136] = (bf16(*)[136])smem;   // epilogue reuse (17408 elems <= 27648)
  int t = threadIdx.x;
  int w = t>>6, lane = t&63, qd = lane>>4, n = lane&15;
  int wm = w>>1, wn = w&1;
  int r0 = blockIdx.y*128, c0 = blockIdx.x*256;
  f32x4 acc[2][4][4];
  #pragma unroll
  for (int cb=0;cb<2;cb++)
    #pragma unroll
    for (int i=0;i<4;i++)
      #pragma unroll
      for (int j=0;j<4;j++) acc[cb][i][j] = (f32x4){0.f,0.f,0.f,0.f};
  int srow = t>>3, skc = t&7;
  for (int k0=0; k0<512; k0+=64){
    #pragma unroll
    for (int ch=0; ch<4; ch++){
      int m = ch*32 + srow;
      *(short8*)&As[m][skc*8]  = *(const short8*)&A [(size_t)(r0+m)*512 + k0 + skc*8];
      *(short8*)&Bs0[m][skc*8] = *(const short8*)&WT[(size_t)(c0+m)*512 + k0 + skc*8];
      *(short8*)&Bs1[m][skc*8] = *(const short8*)&WT[(size_t)(c0+128+m)*512 + k0 + skc*8];
    }
    __syncthreads();
    #pragma unroll
    for (int ksub=0; ksub<2; ksub++){
      short8 af[4];
      #pragma unroll
      for (int i=0;i<4;i++) af[i] = *(const short8*)&As[wm*64+i*16+n][ksub*32+qd*8];
      #pragma unroll
      for (int cb=0; cb<2; cb++){
        bf16 (*Bsc)[72] = cb ? Bs1 : Bs0;
        short8 bfr[4];
        #pragma unroll
        for (int j=0;j<4;j++) bfr[j] = *(const short8*)&Bsc[wn*64+j*16+n][ksub*32+qd*8];
        #pragma unroll
        for (int i=0;i<4;i++)
          #pragma unroll
          for (int j=0;j<4;j++) acc[cb][i][j] = mfma16(af[i], bfr[j], acc[cb][i][j]);
      }
    }
    __syncthreads();
  }
  int part = c0 >> 9;   // uniform per block (256-wide tile within one 512 part)
  bf16* dst = (part==0)? qbuf : (part==1)? kbuf : vbuf;
  float scale = (part==0)? 0.125f : 1.f;
  #pragma unroll
  for (int cb=0; cb<2; cb++){
    __syncthreads();
    #pragma unroll
    for (int i=0;i<4;i++)
      #pragma unroll
      for (int j=0;j<4;j++)
        #pragma unroll
        for (int rg=0; rg<4; rg++)
          ebuf[wm*64+i*16+qd*4+rg][wn*64+j*16+n] = f2bf(acc[cb][i][j][rg]*scale);
    __syncthreads();
    #pragma unroll
    for (int rep=0; rep<8; rep++){
      int unit = rep*256 + t;
      int row = unit >> 4, ch = unit & 15;
      int col = c0 + cb*128 + ch*8;
      int cc = col & 511, h = cc>>6, dh = cc&63;
      int r = r0 + row, b = r>>13, nn = r&8191;
      *(short8*)&dst[(((size_t)(b*H_+h))*N_ + nn)*DH_ + dh] = *(const short8*)&ebuf[row][ch*8];
    }
  }
}

// ---------------- v -> vT tiled transpose (64x64) ----------------
__global__ __launch_bounds__(256) void k_transp_v(const bf16* __restrict__ v, bf16* __restrict__ vT){
  int bh = blockIdx.y, n0 = blockIdx.x*64;
  __shared__ bf16 tile[64][72];
  const bf16* vb = v + (size_t)bh*N_*DH_;
  int t = threadIdx.x;
  for (int i=t; i<512; i+=256){
    int r = i>>3, cg = i&7;
    *(short8*)&tile[r][cg*8] = *(const short8*)&vb[(size_t)(n0+r)*DH_ + cg*8];
  }
  __syncthreads();
  bf16* ob = vT + (size_t)bh*DH_*N_;
  for (int i=t; i<512; i+=256){
    int dh = i>>3, ng = i&7;
    short8 o;
    #pragma unroll
    for (int j=0;j<8;j++) ((bf16*)&o)[j] = tile[ng*8+j][dh];
    *(short8*)&ob[(size_t)dh*N_ + n0 + ng*8] = o;
  }
}

// ---------------- landmark means over contiguous 32-row chunks ----------------
__global__ __launch_bounds__(64) void k_landmark(const bf16* __restrict__ q, const bf16* __restrict__ k,
    bf16* __restrict__ ql, bf16* __restrict__ kl){
  int bhm = blockIdx.x;
  int bh = bhm >> 8, m = bhm & 255;
  int dh = threadIdx.x;
  const bf16* qp = q + ((size_t)bh*N_ + (size_t)m*LCH)*DH_ + dh;
  const bf16* kp = k + ((size_t)bh*N_ + (size_t)m*LCH)*DH_ + dh;
  float sq=0.f, sk=0.f;
  #pragma unroll
  for (int j=0;j<LCH;j++){ sq += bf2f(qp[(size_t)j*DH_]); sk += bf2f(kp[(size_t)j*DH_]); }
  ql[((size_t)bh*M_ + m)*DH_ + dh] = f2bf(sq*(1.f/LCH));
  kl[((size_t)bh*M_ + m)*DH_ + dh] = f2bf(sk*(1.f/LCH));
}

// ---------------- attn2 = softmax(q_l @ k_l^T) rows (fp32 out) ----------------
__global__ __launch_bounds__(256) void k_attn2(const bf16* __restrict__ ql, const bf16* __restrict__ kl,
    float* __restrict__ A2){
  int bhm = blockIdx.x;
  int bh = bhm >> 8, m = bhm & 255;
  int t = threadIdx.x;
  __shared__ float qrow[64];
  __shared__ float sh[4];
  if (t < 64) qrow[t] = bf2f(ql[((size_t)bh*M_ + m)*DH_ + t]);
  __syncthreads();
  const bf16* krow = kl + ((size_t)bh*M_ + t)*DH_;
  float s = 0.f;
  #pragma unroll
  for (int i=0;i<64;i++) s += qrow[i]*bf2f(krow[i]);
  float mx = s;
  for (int off=32; off; off>>=1) mx = fmaxf(mx, __shfl_xor(mx, off));
  if ((t&63)==0) sh[t>>6] = mx;
  __syncthreads();
  mx = fmaxf(fmaxf(sh[0],sh[1]), fmaxf(sh[2],sh[3]));
  float e = expf(s - mx);
  float sum = e;
  for (int off=32; off; off>>=1) sum += __shfl_xor(sum, off);
  __syncthreads();
  if ((t&63)==0) sh[t>>6] = sum;
  __syncthreads();
  sum = sh[0]+sh[1]+sh[2]+sh[3];
  A2[((size_t)bh*M_ + m)*M_ + t] = e/sum;
}

// ---------------- pinv init: Z = A^T / (max_rowsum * max_colsum) ----------------
__global__ __launch_bounds__(256) void k_pinv_init(const float* __restrict__ A2, float* __restrict__ Z){
  int bh = blockIdx.x;
  int t = threadIdx.x;
  const float* Ab = A2 + (size_t)bh*M_*M_;
  float* Zb = Z + (size_t)bh*M_*M_;
  float cs=0.f, rsm=0.f;
  for (int r=0;r<M_;r++) cs += fabsf(Ab[(size_t)r*M_ + t]);
  for (int c=0;c<M_;c++) rsm += fabsf(Ab[(size_t)t*M_ + c]);
  __shared__ float sh[4];
  float v = cs;
  for (int off=32; off; off>>=1) v = fmaxf(v, __shfl_xor(v, off));
  if ((t&63)==0) sh[t>>6] = v;
  __syncthreads();
  float maxc = fmaxf(fmaxf(sh[0],sh[1]), fmaxf(sh[2],sh[3]));
  __syncthreads();
  v = rsm;
  for (int off=32; off; off>>=1) v = fmaxf(v, __shfl_xor(v, off));
  if ((t&63)==0) sh[t>>6] = v;
  __syncthreads();
  float maxr = fmaxf(fmaxf(sh[0],sh[1]), fmaxf(sh[2],sh[3]));
  float inv = 1.f/(maxr*maxc);
  for (int r=0;r<M_;r++) Zb[(size_t)r*M_ + t] = Ab[(size_t)t*M_ + r]*inv;
}

// ---------------- pinv GEMM (bf16 MFMA; optional hi/lo split precision) ----------------
// NOTE (round 4): do NOT fuse these via cooperative grid.sync — the device-scope fences
// defeat cross-XCD cache reuse (560MB HBM refetch, 23x slower). 24 small launches win.
__global__ __launch_bounds__(256) void k_gemm_pm(float* __restrict__ C, const float* __restrict__ A,
    const float* __restrict__ Bm, float bDiag, int bNeg, float cDiag, int cNeg, float cScale,
    int split){
  int bh = blockIdx.y;
  int tm = blockIdx.x >> 2, tn = blockIdx.x & 3;
  const float* Ab = A  + (size_t)bh*65536;
  const float* Bb = Bm + (size_t)bh*65536;
  float* Cb = C + (size_t)bh*65536;
  __shared__ __align__(16) bf16 Ah[64][72];
  __shared__ __align__(16) bf16 Al[64][72];
  __shared__ __align__(16) bf16 Bh[64][72];
  __shared__ __align__(16) bf16 Bl[64][72];
  int t = threadIdx.x;
  int w = t>>6, lane = t&63, qd = lane>>4, n = lane&15;
  int wm = w>>1, wn = w&1;
  int r0 = tm*64, c0 = tn*64;
  f32x4 acc[2][2];
  #pragma unroll
  for (int i=0;i<2;i++)
    #pragma unroll
    for (int j=0;j<2;j++) acc[i][j] = (f32x4){0.f,0.f,0.f,0.f};
  int srow = t>>3, skc = t&7;
  for (int k0=0; k0<256; k0+=64){
    #pragma unroll
    for (int ch=0; ch<2; ch++){
      int m = ch*32 + srow;
      short8 vh, vl;
      const float* ap = &Ab[(size_t)(r0+m)*256 + k0 + skc*8];
      #pragma unroll
      for (int j=0;j<8;j++){
        float x = ap[j];
        bf16 h = f2bf(x);
        ((bf16*)&vh)[j] = h;
        if (split) ((bf16*)&vl)[j] = f2bf(x - bf2f(h));
      }
      *(short8*)&Ah[m][skc*8] = vh;
      if (split) *(short8*)&Al[m][skc*8] = vl;
      const float* bp = &Bb[(size_t)(k0+m)*256 + c0 + skc*8];
      int kr = k0 + m;
      #pragma unroll
      for (int j=0;j<8;j++){
        float x = bp[j];
        if (bNeg) x = (kr == (c0 + skc*8 + j) ? bDiag : 0.f) - x;
        bf16 h = f2bf(x);
        ((bf16*)&vh)[j] = h;
        if (split) ((bf16*)&vl)[j] = f2bf(x - bf2f(h));
      }
      #pragma unroll
      for (int j=0;j<8;j++){
        Bh[skc*8+j][m] = ((bf16*)&vh)[j];
        if (split) Bl[skc*8+j][m] = ((bf16*)&vl)[j];
      }
    }
    __syncthreads();
    #pragma unroll
    for (int ksub=0; ksub<2; ksub++){
      short8 afh[2], afl[2], bfh[2], bfl[2];
      #pragma unroll
      for (int i=0;i<2;i++){
        afh[i] = *(const short8*)&Ah[wm*32+i*16+n][ksub*32+qd*8];
        if (split) afl[i] = *(const short8*)&Al[wm*32+i*16+n][ksub*32+qd*8];
      }
      #pragma unroll
      for (int j=0;j<2;j++){
        bfh[j] = *(const short8*)&Bh[wn*32+j*16+n][ksub*32+qd*8];
        if (split) bfl[j] = *(const short8*)&Bl[wn*32+j*16+n][ksub*32+qd*8];
      }
      #pragma unroll
      for (int i=0;i<2;i++)
        #pragma unroll
        for (int j=0;j<2;j++){
          if (split){
            acc[i][j] = mfma16(afl[i], bfh[j], acc[i][j]);
            acc[i][j] = mfma16(afh[i], bfl[j], acc[i][j]);
          }
          acc[i][j] = mfma16(afh[i], bfh[j], acc[i][j]);
        }
    }
    __syncthreads();
  }
  #pragma unroll
  for (int i=0;i<2;i++){
    #pragma unroll
    for (int j=0;j<2;j++){
      int cidx = c0 + wn*32 + j*16 + n;
      #pragma unroll
      for (int rg=0; rg<4; rg++){
        int r = r0 + wm*32 + i*16 + qd*4 + rg;
        float r_ = acc[i][j][rg];
        if (cNeg) r_ = ((r==cidx)? cDiag : 0.f) - r_;
        Cb[(size_t)r*256 + cidx] = r_*cScale;
      }
    }
  }
}

// ---------------- batched GEMM 256x64x256: z2T = (Z @ kv3)^T ----------------
__global__ __launch_bounds__(256) void k_gemm_z2(bf16* __restrict__ z2t, const float* __restrict__ A,
    const bf16* __restrict__ Bm){
  int bh = blockIdx.y;
  int tm = blockIdx.x;
  const float* Ab = A  + (size_t)bh*65536;
  const bf16* Bb = Bm + (size_t)bh*M_*DH_;
  __shared__ float As[16][68];
  __shared__ float Bs[16][64];
  int t = threadIdx.x, tx = t&15, ty = t>>4;
  int r0 = tm*64;
  float acc[4][4] = {};
  for (int k0=0;k0<256;k0+=16){
    for (int i=t;i<1024;i+=256){
      int m=i>>4, kq=i&15;
      As[kq][m] = Ab[(size_t)(r0+m)*256 + k0+kq];
      int nn=i&63, k2=i>>6;
      Bs[k2][nn] = bf2f(Bb[(size_t)(k0+k2)*64 + nn]);
    }
    __syncthreads();
    #pragma unroll
    for (int kq=0;kq<16;kq++){
      float a0[4], b0[4];
      #pragma unroll
      for (int i=0;i<4;i++) a0[i] = As[kq][ty*4+i];
      #pragma unroll
      for (int j=0;j<4;j++) b0[j] = Bs[kq][tx*4+j];
      #pragma unroll
      for (int i=0;i<4;i++)
        #pragma unroll
        for (int j=0;j<4;j++) acc[i][j] += a0[i]*b0[j];
    }
    __syncthreads();
  }
  #pragma unroll
  for (int i=0;i<4;i++){
    int r = r0+ty*4+i;
    #pragma unroll
    for (int j=0;j<4;j++)
      z2t[(size_t)bh*16384 + (size_t)(tx*4+j)*256 + r] = f2bf(acc[i][j]);
  }
}

// ---------------- attn3 flash, flash-decoding split over columns ----------------
__global__ __launch_bounds__(256, 2) void k_flash_split(const bf16* __restrict__ Q,
    const bf16* __restrict__ K, const bf16* __restrict__ VT,
    float* __restrict__ OP, float* __restrict__ MP, float* __restrict__ LP){
  int bh = blockIdx.y;
  int sp = blockIdx.x;
  int t = threadIdx.x, w = t>>6, lane = t&63, qd = lane>>4, n = lane&15;
  int r0 = w*64;
  const size_t Qoff = ((size_t)bh*M_ + r0)*DH_;
  const size_t Koff = ((size_t)bh*N_ + (size_t)sp*CS)*DH_;
  const size_t Voff = (size_t)bh*DH_*N_ + (size_t)sp*CS;
  __shared__ __align__(16) bf16 pbuf[4][4][16][72];
  short8 aq[4][2];
  #pragma unroll
  for (int rt=0; rt<4; rt++){
    aq[rt][0] = *(const short8*)&Q[Qoff + (size_t)(rt*16+n)*DH_ + qd*8];
    aq[rt][1] = *(const short8*)&Q[Qoff + (size_t)(rt*16+n)*DH_ + 32 + qd*8];
  }
  f32x4 o[4][4];
  float mrun[4][4], lrun[4][4];
  #pragma unroll
  for (int rt=0; rt<4; rt++){
    #pragma unroll
    for (int j=0;j<4;j++){ o[rt][j] = (f32x4){0.f,0.f,0.f,0.f}; mrun[rt][j] = -1e30f; lrun[rt][j] = 0.f; }
  }
  for (int tl=0; tl<CS/64; ++tl){
    const bf16* kp = K + Koff + (size_t)(tl*64)*DH_;
    short8 kb[4][2];
    #pragma unroll
    for (int cg=0; cg<4; cg++){
      kb[cg][0] = *(const short8*)&kp[(size_t)(cg*16+n)*DH_ + qd*8];
      kb[cg][1] = *(const short8*)&kp[(size_t)(cg*16+n)*DH_ + 32 + qd*8];
    }
    #pragma unroll
    for (int rt=0; rt<4; rt++){
      f32x4 s[4];
      #pragma unroll
      for (int cg=0; cg<4; cg++){
        f32x4 z = (f32x4){0.f,0.f,0.f,0.f};
        z = mfma16(aq[rt][0], kb[cg][0], z);
        z = mfma16(aq[rt][1], kb[cg][1], z);
        s[cg] = z;
      }
      float alpha[4];
      #pragma unroll
      for (int rg=0; rg<4; rg++){
        float smax = fmaxf(fmaxf(s[0][rg],s[1][rg]), fmaxf(s[2][rg],s[3][rg]));
        smax = fmaxf(smax, __shfl_xor(smax, 1));
        smax = fmaxf(smax, __shfl_xor(smax, 2));
        smax = fmaxf(smax, __shfl_xor(smax, 4));
        smax = fmaxf(smax, __shfl_xor(smax, 8));
        float mn = fmaxf(mrun[rt][rg], smax);
        float p0 = __expf(s[0][rg]-mn), p1 = __expf(s[1][rg]-mn);
        float p2 = __expf(s[2][rg]-mn), p3 = __expf(s[3][rg]-mn);
        float ts = p0+p1+p2+p3;
        ts += __shfl_xor(ts,1); ts += __shfl_xor(ts,2);
        ts += __shfl_xor(ts,4); ts += __shfl_xor(ts,8);
        float al = __expf(mrun[rt][rg]-mn);
        lrun[rt][rg] = lrun[rt][rg]*al + ts;
        mrun[rt][rg] = mn;
        alpha[rg] = al;
        pbuf[w][rt][qd*4+rg][n]    = f2bf(p0);
        pbuf[w][rt][qd*4+rg][16+n] = f2bf(p1);
        pbuf[w][rt][qd*4+rg][32+n] = f2bf(p2);
        pbuf[w][rt][qd*4+rg][48+n] = f2bf(p3);
      }
      #pragma unroll
      for (int dg=0; dg<4; dg++)
        #pragma unroll
        for (int rg=0; rg<4; rg++) o[rt][dg][rg] *= alpha[rg];
    }
    const bf16* vp = VT + Voff + tl*64 + qd*8;
    short8 vb[4][2];
    #pragma unroll
    for (int dg=0; dg<4; dg++){
      vb[dg][0] = *(const short8*)&vp[(size_t)(dg*16+n)*N_];
      vb[dg][1] = *(const short8*)&vp[(size_t)(dg*16+n)*N_ + 32];
    }
    #pragma unroll
    for (int rt=0; rt<4; rt++){
      short8 ap0 = *(const short8*)&pbuf[w][rt][n][qd*8];
      short8 ap1 = *(const short8*)&pbuf[w][rt][n][32+qd*8];
      #pragma unroll
      for (int dg=0; dg<4; dg++){
        o[rt][dg] = mfma16(ap0, vb[dg][0], o[rt][dg]);
        o[rt][dg] = mfma16(ap1, vb[dg][1], o[rt][dg]);
      }
    }
  }
  size_t base = ((size_t)sp*(B_*H_) + bh)*M_;
  #pragma unroll
  for (int rt=0; rt<4; rt++){
    #pragma unroll
    for (int rg=0; rg<4; rg++){
      int row = r0 + rt*16 + qd*4 + rg;
      if (n==0){ MP[base+row] = mrun[rt][rg]; LP[base+row] = lrun[rt][rg]; }
      #pragma unroll
      for (int dg=0; dg<4; dg++)
        OP[(base+row)*DH_ + dg*16 + n] = o[rt][dg][rg];
    }
  }
}

// ---------------- merge NSPLIT flash partials -> kv3 ----------------
__global__ __launch_bounds__(256) void k_flash_merge(const float* __restrict__ OP,
    const float* __restrict__ MP, const float* __restrict__ LP, bf16* __restrict__ O){
  int bh = blockIdx.y;
  int r = blockIdx.x*4 + (threadIdx.x>>6);
  int dh = threadIdx.x & 63;
  float M = -1e30f, acc = 0.f, den = 0.f;
  for (int s=0; s<NSPLIT; s++){
    size_t base = ((size_t)s*(B_*H_) + bh)*M_ + r;
    float m = MP[base];
    float l = LP[base];
    float ov = OP[base*DH_ + dh];
    float Mn = fmaxf(M, m);
    float wo = __expf(M - Mn), wn = __expf(m - Mn);
    acc = acc*wo + ov*wn;
    den = den*wo + l*wn;
    M = Mn;
  }
  O[((size_t)bh*M_ + r)*DH_ + dh] = f2bf(acc/den);
}

// ---------------- attn1 flash, split-structured: 4 waves x 4 rowtiles, 64-col tiles ----------------
__global__ __launch_bounds__(256, 2) void k_flash_w3(const bf16* __restrict__ Q,
    const bf16* __restrict__ K, const bf16* __restrict__ VT, bf16* __restrict__ O){
  int bh = blockIdx.y;
  int t = threadIdx.x, w = t>>6, lane = t&63, qd = lane>>4, n = lane&15;
  int r0 = blockIdx.x*256 + w*64;
  const size_t Qoff = ((size_t)bh*N_ + r0)*DH_;
  const size_t Koff = (size_t)bh*M_*DH_;
  const size_t Voff = (size_t)bh*DH_*M_;
  __shared__ __align__(16) bf16 pbuf[4][4][16][72];
  short8 aq[4][2];
  #pragma unroll
  for (int rt=0; rt<4; rt++){
    aq[rt][0] = *(const short8*)&Q[Qoff + (size_t)(rt*16+n)*DH_ + qd*8];
    aq[rt][1] = *(const short8*)&Q[Qoff + (size_t)(rt*16+n)*DH_ + 32 + qd*8];
  }
  f32x4 o[4][4];
  float mrun[4][4], lrun[4][4];
  #pragma unroll
  for (int rt=0; rt<4; rt++){
    #pragma unroll
    for (int j=0;j<4;j++){ o[rt][j] = (f32x4){0.f,0.f,0.f,0.f}; mrun[rt][j] = -1e30f; lrun[rt][j] = 0.f; }
  }
  #pragma unroll
  for (int tl=0; tl<4; ++tl){
    const bf16* kp = K + Koff + (size_t)(tl*64)*DH_;
    short8 kb[4][2];
    #pragma unroll
    for (int cg=0; cg<4; cg++){
      kb[cg][0] = *(const short8*)&kp[(size_t)(cg*16+n)*DH_ + qd*8];
      kb[cg][1] = *(const short8*)&kp[(size_t)(cg*16+n)*DH_ + 32 + qd*8];
    }
    #pragma unroll
    for (int rt=0; rt<4; rt++){
      f32x4 s[4];
      #pragma unroll
      for (int cg=0; cg<4; cg++){
        f32x4 z = (f32x4){0.f,0.f,0.f,0.f};
        z = mfma16(aq[rt][0], kb[cg][0], z);
        z = mfma16(aq[rt][1], kb[cg][1], z);
        s[cg] = z;
      }
      float alpha[4];
      #pragma unroll
      for (int rg=0; rg<4; rg++){
        float smax = fmaxf(fmaxf(s[0][rg],s[1][rg]), fmaxf(s[2][rg],s[3][rg]));
        smax = fmaxf(smax, __shfl_xor(smax, 1));
        smax = fmaxf(smax, __shfl_xor(smax, 2));
        smax = fmaxf(smax, __shfl_xor(smax, 4));
        smax = fmaxf(smax, __shfl_xor(smax, 8));
        float mn = fmaxf(mrun[rt][rg], smax);
        float p0 = __expf(s[0][rg]-mn), p1 = __expf(s[1][rg]-mn);
        float p2 = __expf(s[2][rg]-mn), p3 = __expf(s[3][rg]-mn);
        float ts = p0+p1+p2+p3;
        ts += __shfl_xor(ts,1); ts += __shfl_xor(ts,2);
        ts += __shfl_xor(ts,4); ts += __shfl_xor(ts,8);
        float al = __expf(mrun[rt][rg]-mn);
        lrun[rt][rg] = lrun[rt][rg]*al + ts;
        mrun[rt][rg] = mn;
        alpha[rg] = al;
        pbuf[w][rt][qd*4+rg][n]    = f2bf(p0);
        pbuf[w][rt][qd*4+rg][16+n] = f2bf(p1);
        pbuf[w][rt][qd*4+rg][32+n] = f2bf(p2);
        pbuf[w][rt][qd*4+rg][48+n] = f2bf(p3);
      }
      #pragma unroll
      for (int dg=0; dg<4; dg++)
        #pragma unroll
        for (int rg=0; rg<4; rg++) o[rt][dg][rg] *= alpha[rg];
    }
    const bf16* vp = VT + Voff + tl*64 + qd*8;
    short8 vb[4][2];
    #pragma unroll
    for (int dg=0; dg<4; dg++){
      vb[dg][0] = *(const short8*)&vp[(size_t)(dg*16+n)*M_];
      vb[dg][1] = *(const short8*)&vp[(size_t)(dg*16+n)*M_ + 32];
    }
    #pragma unroll
    for (int rt=0; rt<4; rt++){
      short8 ap0 = *(const short8*)&pbuf[w][rt][n][qd*8];
      short8 ap1 = *(const short8*)&pbuf[w][rt][n][32+qd*8];
      #pragma unroll
      for (int dg=0; dg<4; dg++){
        o[rt][dg] = mfma16(ap0, vb[dg][0], o[rt][dg]);
        o[rt][dg] = mfma16(ap1, vb[dg][1], o[rt][dg]);
      }
    }
  }
  #pragma unroll
  for (int rt=0; rt<4; rt++){
    #pragma unroll
    for (int rg=0; rg<4; rg++){
      float inv = 1.f/lrun[rt][rg];
      size_t rowoff = ((size_t)bh*N_ + r0 + rt*16 + qd*4 + rg)*DH_;
      #pragma unroll
      for (int dg=0; dg<4; dg++)
        O[rowoff + dg*16 + n] = f2bf(o[rt][dg][rg]*inv);
    }
  }
}

// ---------------- depthwise conv(KER=33), LDS-tiled, vectorized RMW into outh ----------------
#define CCH 256
__global__ __launch_bounds__(256) void k_conv_add(const bf16* __restrict__ v, const float* __restrict__ w,
    bf16* __restrict__ outh){
  int bh = blockIdx.y;
  int n0 = blockIdx.x * CCH;
  int h = bh & 7;
  __shared__ bf16 vs[CCH+32][72];
  __shared__ float wk[KER_];
  int t = threadIdx.x;
  if (t < KER_) wk[t] = w[h*KER_ + t];
  const bf16* vb = v + (size_t)bh*N_*DH_;
  for (int i=t; i<(CCH+32)*8; i+=256){
    int r = i>>3, cg = i&7;
    int nn = n0 - 16 + r;
    short8 val = {0,0,0,0,0,0,0,0};
    if (nn >= 0 && nn < N_) val = *(const short8*)&vb[(size_t)nn*DH_ + cg*8];
    *(short8*)&vs[r][cg*8] = val;
  }
  __syncthreads();
  int dhg = t & 7, rowg = t >> 3;
  bf16* ob = outh + ((size_t)bh*N_ + n0)*DH_;
  #pragma unroll
  for (int rr=0; rr<8; rr++){
    int lr = rowg*8 + rr;
    float acc[8] = {0.f,0.f,0.f,0.f,0.f,0.f,0.f,0.f};
    for (int tt=0; tt<KER_; tt++){
      short8 vv = *(const short8*)&vs[lr+tt][dhg*8];
      float wt = wk[tt];
      #pragma unroll
      for (int j=0;j<8;j++) acc[j] += wt * bf2f(((bf16*)&vv)[j]);
    }
    short8 o = *(short8*)&ob[(size_t)lr*DH_ + dhg*8];
    #pragma unroll
    for (int j=0;j<8;j++) ((bf16*)&o)[j] = f2bf(bf2f(((bf16*)&o)[j]) + acc[j]);
    *(short8*)&ob[(size_t)lr*DH_ + dhg*8] = o;
  }
}

// ---------------- final GEMM (MFMA, reg-staged, padded LDS): out = x + gather(outh) @ WT2^T + b_out ----------------
// grid (4, 256); store loop j-innermost so the 4 stores covering adjacent 64B segments issue
// back-to-back (write-combine, reduces L2 write-allocate RMW fetch).
__global__ __launch_bounds__(256) void k_mm_out2(const bf16* __restrict__ Ahd, const bf16* __restrict__ WT2,
    const float* __restrict__ bias, const float* __restrict__ xin, float* __restrict__ out){
  __shared__ __align__(16) bf16 As[128][72];
  __shared__ __align__(16) bf16 Bs[128][72];
  int t = threadIdx.x;
  int w = t>>6, lane = t&63, qd = lane>>4, n = lane&15;
  int wm = w>>1, wn = w&1;
  int r0 = blockIdx.y*128, c0 = blockIdx.x*128;
  f32x4 acc[4][4];
  #pragma unroll
  for (int i=0;i<4;i++)
    #pragma unroll
    for (int j=0;j<4;j++) acc[i][j] = (f32x4){0.f,0.f,0.f,0.f};
  int srow = t>>3, skc = t&7;
  for (int k0=0; k0<512; k0+=64){
    int h = k0 >> 6;
    #pragma unroll
    for (int ch=0; ch<4; ch++){
      int m = ch*32 + srow;
      int r = r0 + m, b = r>>13, nn = r&8191;
      *(short8*)&As[m][skc*8] = *(const short8*)&Ahd[((size_t)(b*H_+h)*N_ + nn)*DH_ + skc*8];
      *(short8*)&Bs[m][skc*8] = *(const short8*)&WT2[(size_t)(c0+m)*512 + k0 + skc*8];
    }
    __syncthreads();
    #pragma unroll
    for (int ksub=0; ksub<2; ksub++){
      short8 af[4], bfr[4];
      #pragma unroll
      for (int i=0;i<4;i++) af[i]  = *(const short8*)&As[wm*64+i*16+n][ksub*32+qd*8];
      #pragma unroll
      for (int j=0;j<4;j++) bfr[j] = *(const short8*)&Bs[wn*64+j*16+n][ksub*32+qd*8];
      #pragma unroll
      for (int i=0;i<4;i++)
        #pragma unroll
        for (int j=0;j<4;j++) acc[i][j] = mfma16(af[i], bfr[j], acc[i][j]);
    }
    __syncthreads();
  }
  #pragma unroll
  for (int i=0;i<4;i++){
    #pragma unroll
    for (int rg=0; rg<4; rg++){
      int r = r0 + wm*64 + i*16 + qd*4 + rg;
      size_t base = (size_t)r*512;
      #pragma unroll
      for (int j=0;j<4;j++){
        int c = c0 + wn*64 + j*16 + n;
        out[base + c] = acc[i][j][rg] + bias[c] + xin[base + c];
      }
    }
  }
}

extern "C" void kernel_launch(void* const* d_in, const int* in_sizes, int n_in,
                              void* d_out, int out_size, void* d_ws, size_t ws_size,
                              hipStream_t stream) {
  const float* x     = (const float*)d_in[0];
  const float* gamma = (const float*)d_in[1];
  const float* beta  = (const float*)d_in[2];
  const float* wqkv  = (const float*)d_in[3];
  const float* resk  = (const float*)d_in[4];
  const float* wout  = (const float*)d_in[5];
  const float* bout  = (const float*)d_in[6];
  float* out = (float*)d_out;

  const size_t SL = (size_t)B_*H_*N_*DH_;
  const size_t SM = (size_t)B_*H_*M_*DH_;
  const size_t SP = (size_t)B_*H_*M_*M_;

  bf16* xn  = (bf16*)d_ws;     // reused as: flash partial OP, then pinv P1..P4, then outh
  bf16* q   = xn + SL;
  bf16* k   = q + SL;
  bf16* v   = k + SL;
  bf16* vT  = v + SL;
  bf16* ql  = vT + SL;
  bf16* kl  = ql + SM;
  bf16* kv3 = kl + SM;
  bf16* z2T = kv3 + SM;
  float* A2 = (float*)(z2T + SM);
  bf16* WT  = (bf16*)(A2 + SP);       // 1536 x 512 bf16
  bf16* WT2 = WT + (size_t)1536*512;  // 512 x 512 bf16
  float* P1 = (float*)xn;             // pinv scratch aliases xn (4*SP*4B == SL*2B)
  float* P2 = P1 + SP;
  float* P3 = P2 + SP;
  float* P4 = P3 + SP;
  float* OPp = (float*)xn;
  float* MPp = (float*)z2T;
  float* LPp = MPp + (size_t)NSPLIT*B_*H_*M_;

  k_wt<<<dim3(24, 8), 256, 0, stream>>>(wqkv, WT, 512, 1536);
  k_wt<<<dim3(8, 8), 256, 0, stream>>>(wout, WT2, 512, 512);
  k_layernorm<<<B_*N_, 256, 0, stream>>>(x, gamma, beta, xn);
  k_mm_qkv4<<<dim3(6, 256), 256, 0, stream>>>(xn, WT, q, k, v);
  k_transp_v<<<dim3(128, 32), 256, 0, stream>>>(v, vT);
  k_landmark<<<B_*H_*M_, 64, 0, stream>>>(q, k, ql, kl);

  // attn3 flash (split + merge) runs BEFORE pinv so partials can use the dead xn/z2T regions
  k_flash_split<<<dim3(NSPLIT, B_*H_), 256, 0, stream>>>(ql, k, vT, OPp, MPp, LPp);
  k_flash_merge<<<dim3(M_/4, B_*H_), 256, 0, stream>>>(OPp, MPp, LPp, kv3);

  k_attn2<<<B_*H_*M_, 256, 0, stream>>>(ql, kl, A2);
  k_pinv_init<<<B_*H_, 256, 0, stream>>>(A2, P1);

  float* Zi = P1; float* Zo = P3;
  for (int it=0; it<6; ++it){
    int sp = (it < 4) ? 0 : 1;   // first 4 NS iterations plain bf16; last 2 split-precision
    k_gemm_pm<<<dim3(16,32), 256, 0, stream>>>(P2, A2, Zi, 0.f,0, 0.f,0, 1.f, sp);    // P = A2@Z
    k_gemm_pm<<<dim3(16,32), 256, 0, stream>>>(Zo, P2, P2, 7.f,1, 15.f,1, 1.f, sp);   // S = 15I - P@(7I-P)
    k_gemm_pm<<<dim3(16,32), 256, 0, stream>>>(P4, P2, Zo, 0.f,0, 13.f,1, 1.f, sp);   // U = 13I - P@S
    k_gemm_pm<<<dim3(16,32), 256, 0, stream>>>(Zo, Zi, P4, 0.f,0, 0.f,0, 0.25f, sp);  // Zn = 0.25*Z@U
    float* tt = Zi; Zi = Zo; Zo = tt;
  }

  k_gemm_z2<<<dim3(4, B_*H_), 256, 0, stream>>>(z2T, Zi, kv3);
  k_flash_w3<<<dim3(N_/256, B_*H_), 256, 0, stream>>>(q, kl, z2T, xn);
  k_conv_add<<<dim3(N_/CCH, B_*H_), 256, 0, stream>>>(v, resk, xn);
  k_mm_out2<<<dim3(4, 256), 256, 0, stream>>>(xn, WT2, bout, x, out);
}

// Round 7
// 776.985 us; speedup vs baseline: 2.8855x; 1.1425x over previous
//
#include <hip/hip_runtime.h>
#include <hip/hip_bf16.h>

#define B_ 4
#define N_ 8192
#define D_ 512
#define H_ 8
#define DH_ 64
#define M_ 256
#define LCH 32
#define KER_ 33
#define NSPLIT 16
#define CS (N_/NSPLIT)   // 512 cols per split chunk

typedef __hip_bfloat16 bf16;
typedef __attribute__((ext_vector_type(8))) short short8;
typedef __attribute__((ext_vector_type(4))) float f32x4;

__device__ __forceinline__ float bf2f(bf16 h){ return __bfloat162float(h); }
__device__ __forceinline__ bf16 f2bf(float f){ return __float2bfloat16(f); }
__device__ __forceinline__ f32x4 mfma16(short8 a, short8 b, f32x4 c){
  return __builtin_amdgcn_mfma_f32_16x16x32_bf16(a, b, c, 0, 0, 0);
}

// ---------------- LayerNorm: x (b,n,512) fp32 -> xn bf16 ----------------
__global__ __launch_bounds__(256) void k_layernorm(const float* __restrict__ x,
    const float* __restrict__ gamma, const float* __restrict__ beta,
    bf16* __restrict__ xn){
  int row = blockIdx.x;
  const float* xr = x + (size_t)row * D_;
  bf16* o = xn + (size_t)row * D_;
  int t = threadIdx.x;
  float v0 = xr[t], v1 = xr[t+256];
  float s = v0+v1, ss = v0*v0 + v1*v1;
  __shared__ float sh[8];
  for (int off=32; off; off>>=1){ s += __shfl_xor(s,off); ss += __shfl_xor(ss,off); }
  int lane = t&63, wid = t>>6;
  if (lane==0){ sh[wid] = s; sh[wid+4] = ss; }
  __syncthreads();
  float S  = sh[0]+sh[1]+sh[2]+sh[3];
  float SS = sh[4]+sh[5]+sh[6]+sh[7];
  float mu = S*(1.f/D_);
  float var = SS*(1.f/D_) - mu*mu;
  float rs = rsqrtf(var + 1e-5f);
  o[t]     = f2bf((v0-mu)*rs*gamma[t]     + beta[t]);
  o[t+256] = f2bf((v1-mu)*rs*gamma[t+256] + beta[t+256]);
}

// ---------------- W transpose+convert: W (RxC fp32) -> WT (CxR bf16) ----------------
__global__ __launch_bounds__(256) void k_wt(const float* __restrict__ W, bf16* __restrict__ WT,
    int R, int C){
  int c0 = blockIdx.x*64, r0 = blockIdx.y*64;
  __shared__ float tile[64][65];
  int t = threadIdx.x;
  for (int i=t;i<4096;i+=256){ int r=i>>6, c=i&63; tile[r][c] = W[(size_t)(r0+r)*C + c0+c]; }
  __syncthreads();
  for (int i=t;i<512;i+=256){
    int c=i>>3, rg=i&7;
    short8 o;
    #pragma unroll
    for (int j=0;j<8;j++) ((bf16*)&o)[j] = f2bf(tile[rg*8+j][c]);
    *(short8*)&WT[(size_t)(c0+c)*R + r0 + rg*8] = o;
  }
}

// ---------------- QKV GEMM (MFMA, 128x256 tile, LDS-transposed full-line epilogue) ----------------
// Also fuses the landmark means: part-0/1 blocks hold complete 32-row chunks of q/k in ebuf,
// so ql/kl are computed here (no atomics) and the 8192-block k_landmark launch is deleted.
__global__ __launch_bounds__(256, 2) void k_mm_qkv4(const bf16* __restrict__ A, const bf16* __restrict__ WT,
    bf16* __restrict__ qbuf, bf16* __restrict__ kbuf, bf16* __restrict__ vbuf,
    bf16* __restrict__ qlb, bf16* __restrict__ klb){
  __shared__ __align__(16) bf16 smem[3*128*72];
  bf16 (*As)[72]  = (bf16(*)[72])smem;
  bf16 (*Bs0)[72] = (bf16(*)[72])(smem + 128*72);
  bf16 (*Bs1)[72] = (bf16(*)[72])(smem + 2*128*72);
  bf16 (*ebuf)[136] = (bf16(*)[136])smem;   // epilogue reuse
  int t = threadIdx.x;
  int w = t>>6, lane = t&63, qd = lane>>4, n = lane&15;
  int wm = w>>1, wn = w&1;
  int r0 = blockIdx.y*128, c0 = blockIdx.x*256;
  f32x4 acc[2][4][4];
  #pragma unroll
  for (int cb=0;cb<2;cb++)
    #pragma unroll
    for (int i=0;i<4;i++)
      #pragma unroll
      for (int j=0;j<4;j++) acc[cb][i][j] = (f32x4){0.f,0.f,0.f,0.f};
  int srow = t>>3, skc = t&7;
  for (int k0=0; k0<512; k0+=64){
    #pragma unroll
    for (int ch=0; ch<4; ch++){
      int m = ch*32 + srow;
      *(short8*)&As[m][skc*8]  = *(const short8*)&A [(size_t)(r0+m)*512 + k0 + skc*8];
      *(short8*)&Bs0[m][skc*8] = *(const short8*)&WT[(size_t)(c0+m)*512 + k0 + skc*8];
      *(short8*)&Bs1[m][skc*8] = *(const short8*)&WT[(size_t)(c0+128+m)*512 + k0 + skc*8];
    }
    __syncthreads();
    #pragma unroll
    for (int ksub=0; ksub<2; ksub++){
      short8 af[4];
      #pragma unroll
      for (int i=0;i<4;i++) af[i] = *(const short8*)&As[wm*64+i*16+n][ksub*32+qd*8];
      #pragma unroll
      for (int cb=0; cb<2; cb++){
        bf16 (*Bsc)[72] = cb ? Bs1 : Bs0;
        short8 bfr[4];
        #pragma unroll
        for (int j=0;j<4;j++) bfr[j] = *(const short8*)&Bsc[wn*64+j*16+n][ksub*32+qd*8];
        #pragma unroll
        for (int i=0;i<4;i++)
          #pragma unroll
          for (int j=0;j<4;j++) acc[cb][i][j] = mfma16(af[i], bfr[j], acc[cb][i][j]);
      }
    }
    __syncthreads();
  }
  int part = c0 >> 9;   // uniform per block
  bf16* dst = (part==0)? qbuf : (part==1)? kbuf : vbuf;
  float scale = (part==0)? 0.125f : 1.f;
  #pragma unroll
  for (int cb=0; cb<2; cb++){
    __syncthreads();
    #pragma unroll
    for (int i=0;i<4;i++)
      #pragma unroll
      for (int j=0;j<4;j++)
        #pragma unroll
        for (int rg=0; rg<4; rg++)
          ebuf[wm*64+i*16+qd*4+rg][wn*64+j*16+n] = f2bf(acc[cb][i][j][rg]*scale);
    __syncthreads();
    #pragma unroll
    for (int rep=0; rep<8; rep++){
      int unit = rep*256 + t;
      int row = unit >> 4, ch = unit & 15;
      int col = c0 + cb*128 + ch*8;
      int cc = col & 511, h = cc>>6, dh = cc&63;
      int r = r0 + row, b = r>>13, nn = r&8191;
      *(short8*)&dst[(((size_t)(b*H_+h))*N_ + nn)*DH_ + dh] = *(const short8*)&ebuf[row][ch*8];
    }
    if (part < 2){
      bf16* lt = (part==0) ? qlb : klb;
      #pragma unroll
      for (int rep=0; rep<2; rep++){
        int oi = rep*256 + t;          // 0..511: chunk(4) x col(128)
        int chunk = oi >> 7, col = oi & 127;
        float sum = 0.f;
        #pragma unroll
        for (int rr=0; rr<32; rr++) sum += bf2f(ebuf[chunk*32+rr][col]);
        int r = r0 + chunk*32;
        int b = r >> 13, m = (r & 8191) >> 5;
        int cc = (c0 + cb*128 + col) & 511;
        int h = cc >> 6, dh = cc & 63;
        lt[(((size_t)(b*H_+h))*M_ + m)*DH_ + dh] = f2bf(sum * (1.f/LCH));
      }
    }
  }
}

// ---------------- v -> vT tiled transpose (64x64) ----------------
__global__ __launch_bounds__(256) void k_transp_v(const bf16* __restrict__ v, bf16* __restrict__ vT){
  int bh = blockIdx.y, n0 = blockIdx.x*64;
  __shared__ bf16 tile[64][72];
  const bf16* vb = v + (size_t)bh*N_*DH_;
  int t = threadIdx.x;
  for (int i=t; i<512; i+=256){
    int r = i>>3, cg = i&7;
    *(short8*)&tile[r][cg*8] = *(const short8*)&vb[(size_t)(n0+r)*DH_ + cg*8];
  }
  __syncthreads();
  bf16* ob = vT + (size_t)bh*DH_*N_;
  for (int i=t; i<512; i+=256){
    int dh = i>>3, ng = i&7;
    short8 o;
    #pragma unroll
    for (int j=0;j<8;j++) ((bf16*)&o)[j] = tile[ng*8+j][dh];
    *(short8*)&ob[(size_t)dh*N_ + n0 + ng*8] = o;
  }
}

// ---------------- attn2 = softmax(q_l @ k_l^T) rows (fp32 + bf16 out) ----------------
__global__ __launch_bounds__(256) void k_attn2(const bf16* __restrict__ ql, const bf16* __restrict__ kl,
    float* __restrict__ A2, bf16* __restrict__ A2b){
  int bhm = blockIdx.x;
  int bh = bhm >> 8, m = bhm & 255;
  int t = threadIdx.x;
  __shared__ float qrow[64];
  __shared__ float sh[4];
  if (t < 64) qrow[t] = bf2f(ql[((size_t)bh*M_ + m)*DH_ + t]);
  __syncthreads();
  const bf16* krow = kl + ((size_t)bh*M_ + t)*DH_;
  float s = 0.f;
  #pragma unroll
  for (int i=0;i<64;i++) s += qrow[i]*bf2f(krow[i]);
  float mx = s;
  for (int off=32; off; off>>=1) mx = fmaxf(mx, __shfl_xor(mx, off));
  if ((t&63)==0) sh[t>>6] = mx;
  __syncthreads();
  mx = fmaxf(fmaxf(sh[0],sh[1]), fmaxf(sh[2],sh[3]));
  float e = expf(s - mx);
  float sum = e;
  for (int off=32; off; off>>=1) sum += __shfl_xor(sum, off);
  __syncthreads();
  if ((t&63)==0) sh[t>>6] = sum;
  __syncthreads();
  sum = sh[0]+sh[1]+sh[2]+sh[3];
  float r = e/sum;
  A2[((size_t)bh*M_ + m)*M_ + t] = r;
  A2b[((size_t)bh*M_ + m)*M_ + t] = f2bf(r);
}

// ---------------- pinv init: Z = A^T / (max_rowsum * max_colsum), bf16 out ----------------
__global__ __launch_bounds__(256) void k_pinv_init(const float* __restrict__ A2, bf16* __restrict__ Z){
  int bh = blockIdx.x;
  int t = threadIdx.x;
  const float* Ab = A2 + (size_t)bh*M_*M_;
  bf16* Zb = Z + (size_t)bh*M_*M_;
  float cs=0.f, rsm=0.f;
  for (int r=0;r<M_;r++) cs += fabsf(Ab[(size_t)r*M_ + t]);
  for (int c=0;c<M_;c++) rsm += fabsf(Ab[(size_t)t*M_ + c]);
  __shared__ float sh[4];
  float v = cs;
  for (int off=32; off; off>>=1) v = fmaxf(v, __shfl_xor(v, off));
  if ((t&63)==0) sh[t>>6] = v;
  __syncthreads();
  float maxc = fmaxf(fmaxf(sh[0],sh[1]), fmaxf(sh[2],sh[3]));
  __syncthreads();
  v = rsm;
  for (int off=32; off; off>>=1) v = fmaxf(v, __shfl_xor(v, off));
  if ((t&63)==0) sh[t>>6] = v;
  __syncthreads();
  float maxr = fmaxf(fmaxf(sh[0],sh[1]), fmaxf(sh[2],sh[3]));
  float inv = 1.f/(maxr*maxc);
  for (int r=0;r<M_;r++) Zb[(size_t)r*M_ + t] = f2bf(Ab[(size_t)t*M_ + r]*inv);
}

// ---------------- pinv GEMM, pure bf16 (plain NS iterations 0-3) ----------------
// In plain mode A/B were already rounded to bf16 for MFMA; storing C as bf16 is ~equivalent
// and halves traffic + deletes staging converts. C = cScale*(cNeg? cDiag*I - A@B' : A@B').
__global__ __launch_bounds__(256) void k_gemm_pmb(bf16* __restrict__ C, const bf16* __restrict__ A,
    const bf16* __restrict__ Bm, float bDiag, int bNeg, float cDiag, int cNeg, float cScale){
  int bh = blockIdx.y;
  int tm = blockIdx.x >> 2, tn = blockIdx.x & 3;
  const bf16* Ab = A  + (size_t)bh*65536;
  const bf16* Bb = Bm + (size_t)bh*65536;
  bf16* Cb = C + (size_t)bh*65536;
  __shared__ __align__(16) bf16 Ah[64][72];
  __shared__ __align__(16) bf16 Bh[64][72];
  int t = threadIdx.x;
  int w = t>>6, lane = t&63, qd = lane>>4, n = lane&15;
  int wm = w>>1, wn = w&1;
  int r0 = tm*64, c0 = tn*64;
  f32x4 acc[2][2];
  #pragma unroll
  for (int i=0;i<2;i++)
    #pragma unroll
    for (int j=0;j<2;j++) acc[i][j] = (f32x4){0.f,0.f,0.f,0.f};
  int srow = t>>3, skc = t&7;
  for (int k0=0; k0<256; k0+=64){
    #pragma unroll
    for (int ch=0; ch<2; ch++){
      int m = ch*32 + srow;
      *(short8*)&Ah[m][skc*8] = *(const short8*)&Ab[(size_t)(r0+m)*256 + k0 + skc*8];
      short8 vb = *(const short8*)&Bb[(size_t)(k0+m)*256 + c0 + skc*8];
      int kr = k0 + m;
      if (bNeg){
        #pragma unroll
        for (int j=0;j<8;j++){
          float x = (kr == (c0 + skc*8 + j) ? bDiag : 0.f) - bf2f(((bf16*)&vb)[j]);
          Bh[skc*8+j][m] = f2bf(x);
        }
      } else {
        #pragma unroll
        for (int j=0;j<8;j++) Bh[skc*8+j][m] = ((bf16*)&vb)[j];
      }
    }
    __syncthreads();
    #pragma unroll
    for (int ksub=0; ksub<2; ksub++){
      short8 afh[2], bfh[2];
      #pragma unroll
      for (int i=0;i<2;i++) afh[i] = *(const short8*)&Ah[wm*32+i*16+n][ksub*32+qd*8];
      #pragma unroll
      for (int j=0;j<2;j++) bfh[j] = *(const short8*)&Bh[wn*32+j*16+n][ksub*32+qd*8];
      #pragma unroll
      for (int i=0;i<2;i++)
        #pragma unroll
        for (int j=0;j<2;j++) acc[i][j] = mfma16(afh[i], bfh[j], acc[i][j]);
    }
    __syncthreads();
  }
  #pragma unroll
  for (int i=0;i<2;i++){
    #pragma unroll
    for (int j=0;j<2;j++){
      int cidx = c0 + wn*32 + j*16 + n;
      #pragma unroll
      for (int rg=0; rg<4; rg++){
        int r = r0 + wm*32 + i*16 + qd*4 + rg;
        float r_ = acc[i][j][rg];
        if (cNeg) r_ = ((r==cidx)? cDiag : 0.f) - r_;
        Cb[(size_t)r*256 + cidx] = f2bf(r_*cScale);
      }
    }
  }
}

// ---------------- pinv GEMM fp32 (split precision; aBf/bBf: operand is bf16, lo=0) ----------------
// NOTE (round 4): do NOT fuse via cooperative grid.sync — device-scope fences defeat
// cross-XCD cache reuse (560MB HBM refetch, 23x slower). Small launches win.
__global__ __launch_bounds__(256) void k_gemm_pm(float* __restrict__ C, const void* __restrict__ Av,
    const void* __restrict__ Bv, float bDiag, int bNeg, float cDiag, int cNeg, float cScale,
    int aBf, int bBf){
  int bh = blockIdx.y;
  int tm = blockIdx.x >> 2, tn = blockIdx.x & 3;
  const float* Af = (const float*)Av; const bf16* A16 = (const bf16*)Av;
  const float* Bf = (const float*)Bv; const bf16* B16 = (const bf16*)Bv;
  float* Cb = C + (size_t)bh*65536;
  __shared__ __align__(16) bf16 Ah[64][72];
  __shared__ __align__(16) bf16 Al[64][72];
  __shared__ __align__(16) bf16 Bh[64][72];
  __shared__ __align__(16) bf16 Bl[64][72];
  int t = threadIdx.x;
  int w = t>>6, lane = t&63, qd = lane>>4, n = lane&15;
  int wm = w>>1, wn = w&1;
  int r0 = tm*64, c0 = tn*64;
  f32x4 acc[2][2];
  #pragma unroll
  for (int i=0;i<2;i++)
    #pragma unroll
    for (int j=0;j<2;j++) acc[i][j] = (f32x4){0.f,0.f,0.f,0.f};
  int srow = t>>3, skc = t&7;
  for (int k0=0; k0<256; k0+=64){
    #pragma unroll
    for (int ch=0; ch<2; ch++){
      int m = ch*32 + srow;
      if (aBf){
        *(short8*)&Ah[m][skc*8] = *(const short8*)&A16[(size_t)bh*65536 + (size_t)(r0+m)*256 + k0 + skc*8];
      } else {
        short8 vh, vl;
        const float* ap = &Af[(size_t)bh*65536 + (size_t)(r0+m)*256 + k0 + skc*8];
        #pragma unroll
        for (int j=0;j<8;j++){
          float x = ap[j];
          bf16 h = f2bf(x);
          ((bf16*)&vh)[j] = h;
          ((bf16*)&vl)[j] = f2bf(x - bf2f(h));
        }
        *(short8*)&Ah[m][skc*8] = vh;
        *(short8*)&Al[m][skc*8] = vl;
      }
      int kr = k0 + m;
      if (bBf){
        short8 vb = *(const short8*)&B16[(size_t)bh*65536 + (size_t)(k0+m)*256 + c0 + skc*8];
        #pragma unroll
        for (int j=0;j<8;j++) Bh[skc*8+j][m] = ((bf16*)&vb)[j];  // bBf only used with bNeg==0
      } else {
        const float* bp = &Bf[(size_t)bh*65536 + (size_t)(k0+m)*256 + c0 + skc*8];
        #pragma unroll
        for (int j=0;j<8;j++){
          float x = bp[j];
          if (bNeg) x = (kr == (c0 + skc*8 + j) ? bDiag : 0.f) - x;
          bf16 h = f2bf(x);
          Bh[skc*8+j][m] = h;
          Bl[skc*8+j][m] = f2bf(x - bf2f(h));
        }
      }
    }
    __syncthreads();
    #pragma unroll
    for (int ksub=0; ksub<2; ksub++){
      short8 afh[2], afl[2], bfh[2], bfl[2];
      #pragma unroll
      for (int i=0;i<2;i++){
        afh[i] = *(const short8*)&Ah[wm*32+i*16+n][ksub*32+qd*8];
        if (!aBf) afl[i] = *(const short8*)&Al[wm*32+i*16+n][ksub*32+qd*8];
      }
      #pragma unroll
      for (int j=0;j<2;j++){
        bfh[j] = *(const short8*)&Bh[wn*32+j*16+n][ksub*32+qd*8];
        if (!bBf) bfl[j] = *(const short8*)&Bl[wn*32+j*16+n][ksub*32+qd*8];
      }
      #pragma unroll
      for (int i=0;i<2;i++)
        #pragma unroll
        for (int j=0;j<2;j++){
          if (!aBf) acc[i][j] = mfma16(afl[i], bfh[j], acc[i][j]);
          if (!bBf) acc[i][j] = mfma16(afh[i], bfl[j], acc[i][j]);
          acc[i][j] = mfma16(afh[i], bfh[j], acc[i][j]);
        }
    }
    __syncthreads();
  }
  #pragma unroll
  for (int i=0;i<2;i++){
    #pragma unroll
    for (int j=0;j<2;j++){
      int cidx = c0 + wn*32 + j*16 + n;
      #pragma unroll
      for (int rg=0; rg<4; rg++){
        int r = r0 + wm*32 + i*16 + qd*4 + rg;
        float r_ = acc[i][j][rg];
        if (cNeg) r_ = ((r==cidx)? cDiag : 0.f) - r_;
        Cb[(size_t)r*256 + cidx] = r_*cScale;
      }
    }
  }
}

// ---------------- batched GEMM 256x64x256: z2T = (Z @ kv3)^T ----------------
__global__ __launch_bounds__(256) void k_gemm_z2(bf16* __restrict__ z2t, const float* __restrict__ A,
    const bf16* __restrict__ Bm){
  int bh = blockIdx.y;
  int tm = blockIdx.x;
  const float* Ab = A  + (size_t)bh*65536;
  const bf16* Bb = Bm + (size_t)bh*M_*DH_;
  __shared__ float As[16][68];
  __shared__ float Bs[16][64];
  int t = threadIdx.x, tx = t&15, ty = t>>4;
  int r0 = tm*64;
  float acc[4][4] = {};
  for (int k0=0;k0<256;k0+=16){
    for (int i=t;i<1024;i+=256){
      int m=i>>4, kq=i&15;
      As[kq][m] = Ab[(size_t)(r0+m)*256 + k0+kq];
      int nn=i&63, k2=i>>6;
      Bs[k2][nn] = bf2f(Bb[(size_t)(k0+k2)*64 + nn]);
    }
    __syncthreads();
    #pragma unroll
    for (int kq=0;kq<16;kq++){
      float a0[4], b0[4];
      #pragma unroll
      for (int i=0;i<4;i++) a0[i] = As[kq][ty*4+i];
      #pragma unroll
      for (int j=0;j<4;j++) b0[j] = Bs[kq][tx*4+j];
      #pragma unroll
      for (int i=0;i<4;i++)
        #pragma unroll
        for (int j=0;j<4;j++) acc[i][j] += a0[i]*b0[j];
    }
    __syncthreads();
  }
  #pragma unroll
  for (int i=0;i<4;i++){
    int r = r0+ty*4+i;
    #pragma unroll
    for (int j=0;j<4;j++)
      z2t[(size_t)bh*16384 + (size_t)(tx*4+j)*256 + r] = f2bf(acc[i][j]);
  }
}

// ---------------- attn3 flash, no-max softmax (|s| <= ~2: exp safe, identical after norm) ----------------
__global__ __launch_bounds__(256, 2) void k_flash_split(const bf16* __restrict__ Q,
    const bf16* __restrict__ K, const bf16* __restrict__ VT,
    float* __restrict__ OP, float* __restrict__ LP){
  int bh = blockIdx.y;
  int sp = blockIdx.x;
  int t = threadIdx.x, w = t>>6, lane = t&63, qd = lane>>4, n = lane&15;
  int r0 = w*64;
  const size_t Qoff = ((size_t)bh*M_ + r0)*DH_;
  const size_t Koff = ((size_t)bh*N_ + (size_t)sp*CS)*DH_;
  const size_t Voff = (size_t)bh*DH_*N_ + (size_t)sp*CS;
  __shared__ __align__(16) bf16 pbuf[4][4][16][72];
  short8 aq[4][2];
  #pragma unroll
  for (int rt=0; rt<4; rt++){
    aq[rt][0] = *(const short8*)&Q[Qoff + (size_t)(rt*16+n)*DH_ + qd*8];
    aq[rt][1] = *(const short8*)&Q[Qoff + (size_t)(rt*16+n)*DH_ + 32 + qd*8];
  }
  f32x4 o[4][4];
  float lrun[4][4];
  #pragma unroll
  for (int rt=0; rt<4; rt++){
    #pragma unroll
    for (int j=0;j<4;j++){ o[rt][j] = (f32x4){0.f,0.f,0.f,0.f}; lrun[rt][j] = 0.f; }
  }
  for (int tl=0; tl<CS/64; ++tl){
    const bf16* kp = K + Koff + (size_t)(tl*64)*DH_;
    short8 kb[4][2];
    #pragma unroll
    for (int cg=0; cg<4; cg++){
      kb[cg][0] = *(const short8*)&kp[(size_t)(cg*16+n)*DH_ + qd*8];
      kb[cg][1] = *(const short8*)&kp[(size_t)(cg*16+n)*DH_ + 32 + qd*8];
    }
    #pragma unroll
    for (int rt=0; rt<4; rt++){
      f32x4 s[4];
      #pragma unroll
      for (int cg=0; cg<4; cg++){
        f32x4 z = (f32x4){0.f,0.f,0.f,0.f};
        z = mfma16(aq[rt][0], kb[cg][0], z);
        z = mfma16(aq[rt][1], kb[cg][1], z);
        s[cg] = z;
      }
      #pragma unroll
      for (int rg=0; rg<4; rg++){
        float p0 = __expf(s[0][rg]), p1 = __expf(s[1][rg]);
        float p2 = __expf(s[2][rg]), p3 = __expf(s[3][rg]);
        float ts = p0+p1+p2+p3;
        ts += __shfl_xor(ts,1); ts += __shfl_xor(ts,2);
        ts += __shfl_xor(ts,4); ts += __shfl_xor(ts,8);
        lrun[rt][rg] += ts;
        pbuf[w][rt][qd*4+rg][n]    = f2bf(p0);
        pbuf[w][rt][qd*4+rg][16+n] = f2bf(p1);
        pbuf[w][rt][qd*4+rg][32+n] = f2bf(p2);
        pbuf[w][rt][qd*4+rg][48+n] = f2bf(p3);
      }
    }
    const bf16* vp = VT + Voff + tl*64 + qd*8;
    short8 vb[4][2];
    #pragma unroll
    for (int dg=0; dg<4; dg++){
      vb[dg][0] = *(const short8*)&vp[(size_t)(dg*16+n)*N_];
      vb[dg][1] = *(const short8*)&vp[(size_t)(dg*16+n)*N_ + 32];
    }
    #pragma unroll
    for (int rt=0; rt<4; rt++){
      short8 ap0 = *(const short8*)&pbuf[w][rt][n][qd*8];
      short8 ap1 = *(const short8*)&pbuf[w][rt][n][32+qd*8];
      #pragma unroll
      for (int dg=0; dg<4; dg++){
        o[rt][dg] = mfma16(ap0, vb[dg][0], o[rt][dg]);
        o[rt][dg] = mfma16(ap1, vb[dg][1], o[rt][dg]);
      }
    }
  }
  size_t base = ((size_t)sp*(B_*H_) + bh)*M_;
  #pragma unroll
  for (int rt=0; rt<4; rt++){
    #pragma unroll
    for (int rg=0; rg<4; rg++){
      int row = r0 + rt*16 + qd*4 + rg;
      if (n==0) LP[base+row] = lrun[rt][rg];
      #pragma unroll
      for (int dg=0; dg<4; dg++)
        OP[(base+row)*DH_ + dg*16 + n] = o[rt][dg][rg];
    }
  }
}

// ---------------- merge NSPLIT flash partials -> kv3 (plain sums, no m) ----------------
__global__ __launch_bounds__(256) void k_flash_merge(const float* __restrict__ OP,
    const float* __restrict__ LP, bf16* __restrict__ O){
  int bh = blockIdx.y;
  int r = blockIdx.x*4 + (threadIdx.x>>6);
  int dh = threadIdx.x & 63;
  float acc = 0.f, den = 0.f;
  for (int s=0; s<NSPLIT; s++){
    size_t base = ((size_t)s*(B_*H_) + bh)*M_ + r;
    den += LP[base];
    acc += OP[base*DH_ + dh];
  }
  O[((size_t)bh*M_ + r)*DH_ + dh] = f2bf(acc/den);
}

// ---------------- attn1 flash, no-max softmax, 4 waves x 4 rowtiles ----------------
__global__ __launch_bounds__(256, 2) void k_flash_w3(const bf16* __restrict__ Q,
    const bf16* __restrict__ K, const bf16* __restrict__ VT, bf16* __restrict__ O){
  int bh = blockIdx.y;
  int t = threadIdx.x, w = t>>6, lane = t&63, qd = lane>>4, n = lane&15;
  int r0 = blockIdx.x*256 + w*64;
  const size_t Qoff = ((size_t)bh*N_ + r0)*DH_;
  const size_t Koff = (size_t)bh*M_*DH_;
  const size_t Voff = (size_t)bh*DH_*M_;
  __shared__ __align__(16) bf16 pbuf[4][4][16][72];
  short8 aq[4][2];
  #pragma unroll
  for (int rt=0; rt<4; rt++){
    aq[rt][0] = *(const short8*)&Q[Qoff + (size_t)(rt*16+n)*DH_ + qd*8];
    aq[rt][1] = *(const short8*)&Q[Qoff + (size_t)(rt*16+n)*DH_ + 32 + qd*8];
  }
  f32x4 o[4][4];
  float lrun[4][4];
  #pragma unroll
  for (int rt=0; rt<4; rt++){
    #pragma unroll
    for (int j=0;j<4;j++){ o[rt][j] = (f32x4){0.f,0.f,0.f,0.f}; lrun[rt][j] = 0.f; }
  }
  #pragma unroll
  for (int tl=0; tl<4; ++tl){
    const bf16* kp = K + Koff + (size_t)(tl*64)*DH_;
    short8 kb[4][2];
    #pragma unroll
    for (int cg=0; cg<4; cg++){
      kb[cg][0] = *(const short8*)&kp[(size_t)(cg*16+n)*DH_ + qd*8];
      kb[cg][1] = *(const short8*)&kp[(size_t)(cg*16+n)*DH_ + 32 + qd*8];
    }
    #pragma unroll
    for (int rt=0; rt<4; rt++){
      f32x4 s[4];
      #pragma unroll
      for (int cg=0; cg<4; cg++){
        f32x4 z = (f32x4){0.f,0.f,0.f,0.f};
        z = mfma16(aq[rt][0], kb[cg][0], z);
        z = mfma16(aq[rt][1], kb[cg][1], z);
        s[cg] = z;
      }
      #pragma unroll
      for (int rg=0; rg<4; rg++){
        float p0 = __expf(s[0][rg]), p1 = __expf(s[1][rg]);
        float p2 = __expf(s[2][rg]), p3 = __expf(s[3][rg]);
        float ts = p0+p1+p2+p3;
        ts += __shfl_xor(ts,1); ts += __shfl_xor(ts,2);
        ts += __shfl_xor(ts,4); ts += __shfl_xor(ts,8);
        lrun[rt][rg] += ts;
        pbuf[w][rt][qd*4+rg][n]    = f2bf(p0);
        pbuf[w][rt][qd*4+rg][16+n] = f2bf(p1);
        pbuf[w][rt][qd*4+rg][32+n] = f2bf(p2);
        pbuf[w][rt][qd*4+rg][48+n] = f2bf(p3);
      }
    }
    const bf16* vp = VT + Voff + tl*64 + qd*8;
    short8 vb[4][2];
    #pragma unroll
    for (int dg=0; dg<4; dg++){
      vb[dg][0] = *(const short8*)&vp[(size_t)(dg*16+n)*M_];
      vb[dg][1] = *(const short8*)&vp[(size_t)(dg*16+n)*M_ + 32];
    }
    #pragma unroll
    for (int rt=0; rt<4; rt++){
      short8 ap0 = *(const short8*)&pbuf[w][rt][n][qd*8];
      short8 ap1 = *(const short8*)&pbuf[w][rt][n][32+qd*8];
      #pragma unroll
      for (int dg=0; dg<4; dg++){
        o[rt][dg] = mfma16(ap0, vb[dg][0], o[rt][dg]);
        o[rt][dg] = mfma16(ap1, vb[dg][1], o[rt][dg]);
      }
    }
  }
  #pragma unroll
  for (int rt=0; rt<4; rt++){
    #pragma unroll
    for (int rg=0; rg<4; rg++){
      float inv = 1.f/lrun[rt][rg];
      size_t rowoff = ((size_t)bh*N_ + r0 + rt*16 + qd*4 + rg)*DH_;
      #pragma unroll
      for (int dg=0; dg<4; dg++)
        O[rowoff + dg*16 + n] = f2bf(o[rt][dg][rg]*inv);
    }
  }
}

// ---------------- depthwise conv(KER=33), LDS-tiled, vectorized RMW into outh ----------------
#define CCH 256
__global__ __launch_bounds__(256) void k_conv_add(const bf16* __restrict__ v, const float* __restrict__ w,
    bf16* __restrict__ outh){
  int bh = blockIdx.y;
  int n0 = blockIdx.x * CCH;
  int h = bh & 7;
  __shared__ bf16 vs[CCH+32][72];
  __shared__ float wk[KER_];
  int t = threadIdx.x;
  if (t < KER_) wk[t] = w[h*KER_ + t];
  const bf16* vb = v + (size_t)bh*N_*DH_;
  for (int i=t; i<(CCH+32)*8; i+=256){
    int r = i>>3, cg = i&7;
    int nn = n0 - 16 + r;
    short8 val = {0,0,0,0,0,0,0,0};
    if (nn >= 0 && nn < N_) val = *(const short8*)&vb[(size_t)nn*DH_ + cg*8];
    *(short8*)&vs[r][cg*8] = val;
  }
  __syncthreads();
  int dhg = t & 7, rowg = t >> 3;
  bf16* ob = outh + ((size_t)bh*N_ + n0)*DH_;
  #pragma unroll
  for (int rr=0; rr<8; rr++){
    int lr = rowg*8 + rr;
    float acc[8] = {0.f,0.f,0.f,0.f,0.f,0.f,0.f,0.f};
    for (int tt=0; tt<KER_; tt++){
      short8 vv = *(const short8*)&vs[lr+tt][dhg*8];
      float wt = wk[tt];
      #pragma unroll
      for (int j=0;j<8;j++) acc[j] += wt * bf2f(((bf16*)&vv)[j]);
    }
    short8 o = *(short8*)&ob[(size_t)lr*DH_ + dhg*8];
    #pragma unroll
    for (int j=0;j<8;j++) ((bf16*)&o)[j] = f2bf(bf2f(((bf16*)&o)[j]) + acc[j]);
    *(short8*)&ob[(size_t)lr*DH_ + dhg*8] = o;
  }
}

// ---------------- final GEMM: out = x + gather(outh) @ WT2^T + b_out ----------------
__global__ __launch_bounds__(256) void k_mm_out2(const bf16* __restrict__ Ahd, const bf16* __restrict__ WT2,
    const float* __restrict__ bias, const float* __restrict__ xin, float* __restrict__ out){
  __shared__ __align__(16) bf16 As[128][72];
  __shared__ __align__(16) bf16 Bs[128][72];
  int t = threadIdx.x;
  int w = t>>6, lane = t&63, qd = lane>>4, n = lane&15;
  int wm = w>>1, wn = w&1;
  int r0 = blockIdx.y*128, c0 = blockIdx.x*128;
  f32x4 acc[4][4];
  #pragma unroll
  for (int i=0;i<4;i++)
    #pragma unroll
    for (int j=0;j<4;j++) acc[i][j] = (f32x4){0.f,0.f,0.f,0.f};
  int srow = t>>3, skc = t&7;
  for (int k0=0; k0<512; k0+=64){
    int h = k0 >> 6;
    #pragma unroll
    for (int ch=0; ch<4; ch++){
      int m = ch*32 + srow;
      int r = r0 + m, b = r>>13, nn = r&8191;
      *(short8*)&As[m][skc*8] = *(const short8*)&Ahd[((size_t)(b*H_+h)*N_ + nn)*DH_ + skc*8];
      *(short8*)&Bs[m][skc*8] = *(const short8*)&WT2[(size_t)(c0+m)*512 + k0 + skc*8];
    }
    __syncthreads();
    #pragma unroll
    for (int ksub=0; ksub<2; ksub++){
      short8 af[4], bfr[4];
      #pragma unroll
      for (int i=0;i<4;i++) af[i]  = *(const short8*)&As[wm*64+i*16+n][ksub*32+qd*8];
      #pragma unroll
      for (int j=0;j<4;j++) bfr[j] = *(const short8*)&Bs[wn*64+j*16+n][ksub*32+qd*8];
      #pragma unroll
      for (int i=0;i<4;i++)
        #pragma unroll
        for (int j=0;j<4;j++) acc[i][j] = mfma16(af[i], bfr[j], acc[i][j]);
    }
    __syncthreads();
  }
  #pragma unroll
  for (int i=0;i<4;i++){
    #pragma unroll
    for (int rg=0; rg<4; rg++){
      int r = r0 + wm*64 + i*16 + qd*4 + rg;
      size_t base = (size_t)r*512;
      #pragma unroll
      for (int j=0;j<4;j++){
        int c = c0 + wn*64 + j*16 + n;
        out[base + c] = acc[i][j][rg] + bias[c] + xin[base + c];
      }
    }
  }
}

extern "C" void kernel_launch(void* const* d_in, const int* in_sizes, int n_in,
                              void* d_out, int out_size, void* d_ws, size_t ws_size,
                              hipStream_t stream) {
  const float* x     = (const float*)d_in[0];
  const float* gamma = (const float*)d_in[1];
  const float* beta  = (const float*)d_in[2];
  const float* wqkv  = (const float*)d_in[3];
  const float* resk  = (const float*)d_in[4];
  const float* wout  = (const float*)d_in[5];
  const float* bout  = (const float*)d_in[6];
  float* out = (float*)d_out;

  const size_t SL = (size_t)B_*H_*N_*DH_;
  const size_t SM = (size_t)B_*H_*M_*DH_;
  const size_t SP = (size_t)B_*H_*M_*M_;

  bf16* xn  = (bf16*)d_ws;     // reused as: flash partial OP, then pinv P1..P4, then outh
  bf16* q   = xn + SL;
  bf16* k   = q + SL;          // k region dead after flash_split -> holds bf16 pinv scratch
  bf16* v   = k + SL;
  bf16* vT  = v + SL;
  bf16* ql  = vT + SL;
  bf16* kl  = ql + SM;
  bf16* kv3 = kl + SM;
  bf16* z2T = kv3 + SM;
  float* A2 = (float*)(z2T + SM);
  bf16* WT  = (bf16*)(A2 + SP);       // 1536 x 512 bf16
  bf16* WT2 = WT + (size_t)1536*512;  // 512 x 512 bf16
  float* P1 = (float*)xn;             // pinv fp32 scratch aliases xn (4*SP*4B == SL*2B)
  float* P2 = P1 + SP;
  float* P3 = P2 + SP;
  float* P4 = P3 + SP;
  float* OPp = (float*)xn;            // flash partials alias xn (dead before pinv)
  float* LPp = (float*)z2T;           // and z2T (dead until gemm_z2)
  // bf16 pinv scratch in dead k region (6*SP*2B = 25.2MB <= 33.5MB)
  bf16* A2b = k;
  bf16* Zb0 = A2b + SP;
  bf16* Zb1 = Zb0 + SP;
  bf16* Pb  = Zb1 + SP;
  bf16* Tb  = Pb + SP;
  bf16* Ub  = Tb + SP;

  k_wt<<<dim3(24, 8), 256, 0, stream>>>(wqkv, WT, 512, 1536);
  k_wt<<<dim3(8, 8), 256, 0, stream>>>(wout, WT2, 512, 512);
  k_layernorm<<<B_*N_, 256, 0, stream>>>(x, gamma, beta, xn);
  k_mm_qkv4<<<dim3(6, 256), 256, 0, stream>>>(xn, WT, q, k, v, ql, kl);
  k_transp_v<<<dim3(128, 32), 256, 0, stream>>>(v, vT);

  // attn3 flash (split + merge) BEFORE pinv so partials use the dead xn/z2T regions
  k_flash_split<<<dim3(NSPLIT, B_*H_), 256, 0, stream>>>(ql, k, vT, OPp, LPp);
  k_flash_merge<<<dim3(M_/4, B_*H_), 256, 0, stream>>>(OPp, LPp, kv3);

  k_attn2<<<B_*H_*M_, 256, 0, stream>>>(ql, kl, A2, A2b);
  k_pinv_init<<<B_*H_, 256, 0, stream>>>(A2, Zb0);

  // NS iterations 0-3: pure bf16 (ops already bf16-rounded in plain mode; storage matches)
  bf16* Zbi = Zb0; bf16* Zbo = Zb1;
  for (int it=0; it<4; ++it){
    k_gemm_pmb<<<dim3(16,32), 256, 0, stream>>>(Pb,  A2b, Zbi, 0.f,0, 0.f,0, 1.f);   // P = A2@Z
    k_gemm_pmb<<<dim3(16,32), 256, 0, stream>>>(Tb,  Pb,  Pb,  7.f,1, 15.f,1, 1.f);  // S = 15I-P@(7I-P)
    k_gemm_pmb<<<dim3(16,32), 256, 0, stream>>>(Ub,  Pb,  Tb,  0.f,0, 13.f,1, 1.f);  // U = 13I-P@S
    k_gemm_pmb<<<dim3(16,32), 256, 0, stream>>>(Zbo, Zbi, Ub,  0.f,0, 0.f,0, 0.25f); // Zn = .25*Z@U
    bf16* tt = Zbi; Zbi = Zbo; Zbo = tt;
  }
  // NS iterations 4-5: split precision fp32 (bf16 operands where exact: lo=0)
  k_gemm_pm<<<dim3(16,32), 256, 0, stream>>>(P2, A2, Zbi, 0.f,0, 0.f,0, 1.f,  0,1); // P
  k_gemm_pm<<<dim3(16,32), 256, 0, stream>>>(P3, P2, P2,  7.f,1, 15.f,1, 1.f, 0,0); // S
  k_gemm_pm<<<dim3(16,32), 256, 0, stream>>>(P4, P2, P3,  0.f,0, 13.f,1, 1.f, 0,0); // U
  k_gemm_pm<<<dim3(16,32), 256, 0, stream>>>(P1, Zbi, P4, 0.f,0, 0.f,0, 0.25f,1,0); // Zn->P1
  k_gemm_pm<<<dim3(16,32), 256, 0, stream>>>(P2, A2, P1,  0.f,0, 0.f,0, 1.f,  0,0); // P
  k_gemm_pm<<<dim3(16,32), 256, 0, stream>>>(P3, P2, P2,  7.f,1, 15.f,1, 1.f, 0,0); // S
  k_gemm_pm<<<dim3(16,32), 256, 0, stream>>>(P4, P2, P3,  0.f,0, 13.f,1, 1.f, 0,0); // U
  k_gemm_pm<<<dim3(16,32), 256, 0, stream>>>(P2, P1, P4,  0.f,0, 0.f,0, 0.25f,0,0); // Zn->P2

  k_gemm_z2<<<dim3(4, B_*H_), 256, 0, stream>>>(z2T, P2, kv3);
  k_flash_w3<<<dim3(N_/256, B_*H_), 256, 0, stream>>>(q, kl, z2T, xn);
  k_conv_add<<<dim3(N_/CCH, B_*H_), 256, 0, stream>>>(v, resk, xn);
  k_mm_out2<<<dim3(4, 256), 256, 0, stream>>>(xn, WT2, bout, x, out);
}

// Round 8
// 747.838 us; speedup vs baseline: 2.9980x; 1.0390x over previous
//
#include <hip/hip_runtime.h>
#include <hip/hip_bf16.h>

#define B_ 4
#define N_ 8192
#define D_ 512
#define H_ 8
#define DH_ 64
#define M_ 256
#define LCH 32
#define KER_ 33
#define NSPLIT 16
#define CS (N_/NSPLIT)   // 512 cols per split chunk

typedef __hip_bfloat16 bf16;
typedef __attribute__((ext_vector_type(8))) short short8;
typedef __attribute__((ext_vector_type(4))) float f32x4;

__device__ __forceinline__ float bf2f(bf16 h){ return __bfloat162float(h); }
__device__ __forceinline__ bf16 f2bf(float f){ return __float2bfloat16(f); }
__device__ __forceinline__ f32x4 mfma16(short8 a, short8 b, f32x4 c){
  return __builtin_amdgcn_mfma_f32_16x16x32_bf16(a, b, c, 0, 0, 0);
}

// ---------------- LayerNorm: x (b,n,512) fp32 -> xn bf16 ----------------
__global__ __launch_bounds__(256) void k_layernorm(const float* __restrict__ x,
    const float* __restrict__ gamma, const float* __restrict__ beta,
    bf16* __restrict__ xn){
  int row = blockIdx.x;
  const float* xr = x + (size_t)row * D_;
  bf16* o = xn + (size_t)row * D_;
  int t = threadIdx.x;
  float v0 = xr[t], v1 = xr[t+256];
  float s = v0+v1, ss = v0*v0 + v1*v1;
  __shared__ float sh[8];
  for (int off=32; off; off>>=1){ s += __shfl_xor(s,off); ss += __shfl_xor(ss,off); }
  int lane = t&63, wid = t>>6;
  if (lane==0){ sh[wid] = s; sh[wid+4] = ss; }
  __syncthreads();
  float S  = sh[0]+sh[1]+sh[2]+sh[3];
  float SS = sh[4]+sh[5]+sh[6]+sh[7];
  float mu = S*(1.f/D_);
  float var = SS*(1.f/D_) - mu*mu;
  float rs = rsqrtf(var + 1e-5f);
  o[t]     = f2bf((v0-mu)*rs*gamma[t]     + beta[t]);
  o[t+256] = f2bf((v1-mu)*rs*gamma[t+256] + beta[t+256]);
}

// ---------------- W transpose+convert: W (RxC fp32) -> WT (CxR bf16) ----------------
__global__ __launch_bounds__(256) void k_wt(const float* __restrict__ W, bf16* __restrict__ WT,
    int R, int C){
  int c0 = blockIdx.x*64, r0 = blockIdx.y*64;
  __shared__ float tile[64][65];
  int t = threadIdx.x;
  for (int i=t;i<4096;i+=256){ int r=i>>6, c=i&63; tile[r][c] = W[(size_t)(r0+r)*C + c0+c]; }
  __syncthreads();
  for (int i=t;i<512;i+=256){
    int c=i>>3, rg=i&7;
    short8 o;
    #pragma unroll
    for (int j=0;j<8;j++) ((bf16*)&o)[j] = f2bf(tile[rg*8+j][c]);
    *(short8*)&WT[(size_t)(c0+c)*R + r0 + rg*8] = o;
  }
}

// ---------------- QKV GEMM (MFMA, 128x256 tile, LDS-transposed full-line epilogue) ----------------
// 1D grid 1536 with XCD-chunked swizzle: each XCD owns 32 complete A row-panels (x6 col-tiles
// consecutive) -> A fetched once chip-wide instead of ~3x (round-7 FETCH 107MB vs 35 ideal).
// Fuses landmark means (part 0/1) AND the v->vT transpose (part 2, from ebuf, full-line writes)
// so both k_landmark and k_transp_v launches are deleted.
__global__ __launch_bounds__(256, 2) void k_mm_qkv4(const bf16* __restrict__ A, const bf16* __restrict__ WT,
    bf16* __restrict__ qbuf, bf16* __restrict__ kbuf, bf16* __restrict__ vbuf,
    bf16* __restrict__ vT, bf16* __restrict__ qlb, bf16* __restrict__ klb){
  __shared__ __align__(16) bf16 smem[3*128*72];
  bf16 (*As)[72]  = (bf16(*)[72])smem;
  bf16 (*Bs0)[72] = (bf16(*)[72])(smem + 128*72);
  bf16 (*Bs1)[72] = (bf16(*)[72])(smem + 2*128*72);
  bf16 (*ebuf)[136] = (bf16(*)[136])smem;   // epilogue reuse
  int t = threadIdx.x;
  int w = t>>6, lane = t&63, qd = lane>>4, n = lane&15;
  int wm = w>>1, wn = w&1;
  int bid = blockIdx.x;                 // 0..1535
  int xcd = bid & 7, pos = bid >> 3;
  int tid = xcd*192 + pos;              // contiguous tile range per XCD
  int cx = tid % 6, ry = tid / 6;       // 6 col-tiles of one row-panel consecutive
  int r0 = ry*128, c0 = cx*256;
  f32x4 acc[2][4][4];
  #pragma unroll
  for (int cb=0;cb<2;cb++)
    #pragma unroll
    for (int i=0;i<4;i++)
      #pragma unroll
      for (int j=0;j<4;j++) acc[cb][i][j] = (f32x4){0.f,0.f,0.f,0.f};
  int srow = t>>3, skc = t&7;
  for (int k0=0; k0<512; k0+=64){
    #pragma unroll
    for (int ch=0; ch<4; ch++){
      int m = ch*32 + srow;
      *(short8*)&As[m][skc*8]  = *(const short8*)&A [(size_t)(r0+m)*512 + k0 + skc*8];
      *(short8*)&Bs0[m][skc*8] = *(const short8*)&WT[(size_t)(c0+m)*512 + k0 + skc*8];
      *(short8*)&Bs1[m][skc*8] = *(const short8*)&WT[(size_t)(c0+128+m)*512 + k0 + skc*8];
    }
    __syncthreads();
    #pragma unroll
    for (int ksub=0; ksub<2; ksub++){
      short8 af[4];
      #pragma unroll
      for (int i=0;i<4;i++) af[i] = *(const short8*)&As[wm*64+i*16+n][ksub*32+qd*8];
      #pragma unroll
      for (int cb=0; cb<2; cb++){
        bf16 (*Bsc)[72] = cb ? Bs1 : Bs0;
        short8 bfr[4];
        #pragma unroll
        for (int j=0;j<4;j++) bfr[j] = *(const short8*)&Bsc[wn*64+j*16+n][ksub*32+qd*8];
        #pragma unroll
        for (int i=0;i<4;i++)
          #pragma unroll
          for (int j=0;j<4;j++) acc[cb][i][j] = mfma16(af[i], bfr[j], acc[cb][i][j]);
      }
    }
    __syncthreads();
  }
  int part = c0 >> 9;   // uniform per block
  bf16* dst = (part==0)? qbuf : (part==1)? kbuf : vbuf;
  float scale = (part==0)? 0.125f : 1.f;
  int b = r0 >> 13, nn = r0 & 8191;
  #pragma unroll
  for (int cb=0; cb<2; cb++){
    __syncthreads();
    #pragma unroll
    for (int i=0;i<4;i++)
      #pragma unroll
      for (int j=0;j<4;j++)
        #pragma unroll
        for (int rg=0; rg<4; rg++)
          ebuf[wm*64+i*16+qd*4+rg][wn*64+j*16+n] = f2bf(acc[cb][i][j][rg]*scale);
    __syncthreads();
    #pragma unroll
    for (int rep=0; rep<8; rep++){
      int unit = rep*256 + t;
      int row = unit >> 4, ch = unit & 15;
      int col = c0 + cb*128 + ch*8;
      int cc = col & 511, h = cc>>6, dh = cc&63;
      *(short8*)&dst[(((size_t)(b*H_+h))*N_ + nn + row)*DH_ + dh] = *(const short8*)&ebuf[row][ch*8];
    }
    if (part < 2){
      bf16* lt = (part==0) ? qlb : klb;
      #pragma unroll
      for (int rep=0; rep<2; rep++){
        int oi = rep*256 + t;          // 0..511: chunk(4) x col(128)
        int chunk = oi >> 7, col = oi & 127;
        float sum = 0.f;
        #pragma unroll
        for (int rr=0; rr<32; rr++) sum += bf2f(ebuf[chunk*32+rr][col]);
        int m = (nn >> 5) + chunk;
        int cc = (c0 + cb*128 + col) & 511;
        int h = cc >> 6, dh = cc & 63;
        lt[(((size_t)(b*H_+h))*M_ + m)*DH_ + dh] = f2bf(sum * (1.f/LCH));
      }
    } else {
      // vT = v^T written straight from ebuf: 128 consecutive n per dh-row = 2 full 128B lines.
      #pragma unroll
      for (int rep=0; rep<8; rep++){
        int unit = rep*256 + t;        // col(128) x rg(16)
        int col = unit >> 4, rg = unit & 15;
        int cc = (c0 + cb*128 + col) & 511;
        int h = cc >> 6, dh = cc & 63;
        short8 o;
        #pragma unroll
        for (int j=0;j<8;j++) ((bf16*)&o)[j] = ebuf[rg*8+j][col];
        *(short8*)&vT[(((size_t)(b*H_+h))*DH_ + dh)*N_ + nn + rg*8] = o;
      }
    }
  }
}

// ---------------- attn2 = softmax(q_l @ k_l^T) rows (fp32 + bf16 out) ----------------
__global__ __launch_bounds__(256) void k_attn2(const bf16* __restrict__ ql, const bf16* __restrict__ kl,
    float* __restrict__ A2, bf16* __restrict__ A2b){
  int bhm = blockIdx.x;
  int bh = bhm >> 8, m = bhm & 255;
  int t = threadIdx.x;
  __shared__ float qrow[64];
  __shared__ float sh[4];
  if (t < 64) qrow[t] = bf2f(ql[((size_t)bh*M_ + m)*DH_ + t]);
  __syncthreads();
  const bf16* krow = kl + ((size_t)bh*M_ + t)*DH_;
  float s = 0.f;
  #pragma unroll
  for (int i=0;i<64;i++) s += qrow[i]*bf2f(krow[i]);
  float mx = s;
  for (int off=32; off; off>>=1) mx = fmaxf(mx, __shfl_xor(mx, off));
  if ((t&63)==0) sh[t>>6] = mx;
  __syncthreads();
  mx = fmaxf(fmaxf(sh[0],sh[1]), fmaxf(sh[2],sh[3]));
  float e = expf(s - mx);
  float sum = e;
  for (int off=32; off; off>>=1) sum += __shfl_xor(sum, off);
  __syncthreads();
  if ((t&63)==0) sh[t>>6] = sum;
  __syncthreads();
  sum = sh[0]+sh[1]+sh[2]+sh[3];
  float r = e/sum;
  A2[((size_t)bh*M_ + m)*M_ + t] = r;
  A2b[((size_t)bh*M_ + m)*M_ + t] = f2bf(r);
}

// ---------------- pinv init: Z = A^T / (max_rowsum * max_colsum), bf16 out ----------------
__global__ __launch_bounds__(256) void k_pinv_init(const float* __restrict__ A2, bf16* __restrict__ Z){
  int bh = blockIdx.x;
  int t = threadIdx.x;
  const float* Ab = A2 + (size_t)bh*M_*M_;
  bf16* Zb = Z + (size_t)bh*M_*M_;
  float cs=0.f, rsm=0.f;
  for (int r=0;r<M_;r++) cs += fabsf(Ab[(size_t)r*M_ + t]);
  for (int c=0;c<M_;c++) rsm += fabsf(Ab[(size_t)t*M_ + c]);
  __shared__ float sh[4];
  float v = cs;
  for (int off=32; off; off>>=1) v = fmaxf(v, __shfl_xor(v, off));
  if ((t&63)==0) sh[t>>6] = v;
  __syncthreads();
  float maxc = fmaxf(fmaxf(sh[0],sh[1]), fmaxf(sh[2],sh[3]));
  __syncthreads();
  v = rsm;
  for (int off=32; off; off>>=1) v = fmaxf(v, __shfl_xor(v, off));
  if ((t&63)==0) sh[t>>6] = v;
  __syncthreads();
  float maxr = fmaxf(fmaxf(sh[0],sh[1]), fmaxf(sh[2],sh[3]));
  float inv = 1.f/(maxr*maxc);
  for (int r=0;r<M_;r++) Zb[(size_t)r*M_ + t] = f2bf(Ab[(size_t)t*M_ + r]*inv);
}

// ---------------- pinv GEMM, pure bf16 (plain NS iterations) ----------------
__global__ __launch_bounds__(256) void k_gemm_pmb(bf16* __restrict__ C, const bf16* __restrict__ A,
    const bf16* __restrict__ Bm, float bDiag, int bNeg, float cDiag, int cNeg, float cScale){
  int bh = blockIdx.y;
  int tm = blockIdx.x >> 2, tn = blockIdx.x & 3;
  const bf16* Ab = A  + (size_t)bh*65536;
  const bf16* Bb = Bm + (size_t)bh*65536;
  bf16* Cb = C + (size_t)bh*65536;
  __shared__ __align__(16) bf16 Ah[64][72];
  __shared__ __align__(16) bf16 Bh[64][72];
  int t = threadIdx.x;
  int w = t>>6, lane = t&63, qd = lane>>4, n = lane&15;
  int wm = w>>1, wn = w&1;
  int r0 = tm*64, c0 = tn*64;
  f32x4 acc[2][2];
  #pragma unroll
  for (int i=0;i<2;i++)
    #pragma unroll
    for (int j=0;j<2;j++) acc[i][j] = (f32x4){0.f,0.f,0.f,0.f};
  int srow = t>>3, skc = t&7;
  for (int k0=0; k0<256; k0+=64){
    #pragma unroll
    for (int ch=0; ch<2; ch++){
      int m = ch*32 + srow;
      *(short8*)&Ah[m][skc*8] = *(const short8*)&Ab[(size_t)(r0+m)*256 + k0 + skc*8];
      short8 vb = *(const short8*)&Bb[(size_t)(k0+m)*256 + c0 + skc*8];
      int kr = k0 + m;
      if (bNeg){
        #pragma unroll
        for (int j=0;j<8;j++){
          float x = (kr == (c0 + skc*8 + j) ? bDiag : 0.f) - bf2f(((bf16*)&vb)[j]);
          Bh[skc*8+j][m] = f2bf(x);
        }
      } else {
        #pragma unroll
        for (int j=0;j<8;j++) Bh[skc*8+j][m] = ((bf16*)&vb)[j];
      }
    }
    __syncthreads();
    #pragma unroll
    for (int ksub=0; ksub<2; ksub++){
      short8 afh[2], bfh[2];
      #pragma unroll
      for (int i=0;i<2;i++) afh[i] = *(const short8*)&Ah[wm*32+i*16+n][ksub*32+qd*8];
      #pragma unroll
      for (int j=0;j<2;j++) bfh[j] = *(const short8*)&Bh[wn*32+j*16+n][ksub*32+qd*8];
      #pragma unroll
      for (int i=0;i<2;i++)
        #pragma unroll
        for (int j=0;j<2;j++) acc[i][j] = mfma16(afh[i], bfh[j], acc[i][j]);
    }
    __syncthreads();
  }
  #pragma unroll
  for (int i=0;i<2;i++){
    #pragma unroll
    for (int j=0;j<2;j++){
      int cidx = c0 + wn*32 + j*16 + n;
      #pragma unroll
      for (int rg=0; rg<4; rg++){
        int r = r0 + wm*32 + i*16 + qd*4 + rg;
        float r_ = acc[i][j][rg];
        if (cNeg) r_ = ((r==cidx)? cDiag : 0.f) - r_;
        Cb[(size_t)r*256 + cidx] = f2bf(r_*cScale);
      }
    }
  }
}

// ---------------- pinv GEMM fp32 (split precision; aBf/bBf: operand is bf16, lo=0) ----------------
// NOTE (round 4): do NOT fuse via cooperative grid.sync — device-scope fences defeat
// cross-XCD cache reuse (560MB HBM refetch, 23x slower). Small launches win.
__global__ __launch_bounds__(256) void k_gemm_pm(float* __restrict__ C, const void* __restrict__ Av,
    const void* __restrict__ Bv, float bDiag, int bNeg, float cDiag, int cNeg, float cScale,
    int aBf, int bBf){
  int bh = blockIdx.y;
  int tm = blockIdx.x >> 2, tn = blockIdx.x & 3;
  const float* Af = (const float*)Av; const bf16* A16 = (const bf16*)Av;
  const float* Bf = (const float*)Bv; const bf16* B16 = (const bf16*)Bv;
  float* Cb = C + (size_t)bh*65536;
  __shared__ __align__(16) bf16 Ah[64][72];
  __shared__ __align__(16) bf16 Al[64][72];
  __shared__ __align__(16) bf16 Bh[64][72];
  __shared__ __align__(16) bf16 Bl[64][72];
  int t = threadIdx.x;
  int w = t>>6, lane = t&63, qd = lane>>4, n = lane&15;
  int wm = w>>1, wn = w&1;
  int r0 = tm*64, c0 = tn*64;
  f32x4 acc[2][2];
  #pragma unroll
  for (int i=0;i<2;i++)
    #pragma unroll
    for (int j=0;j<2;j++) acc[i][j] = (f32x4){0.f,0.f,0.f,0.f};
  int srow = t>>3, skc = t&7;
  for (int k0=0; k0<256; k0+=64){
    #pragma unroll
    for (int ch=0; ch<2; ch++){
      int m = ch*32 + srow;
      if (aBf){
        *(short8*)&Ah[m][skc*8] = *(const short8*)&A16[(size_t)bh*65536 + (size_t)(r0+m)*256 + k0 + skc*8];
      } else {
        short8 vh, vl;
        const float* ap = &Af[(size_t)bh*65536 + (size_t)(r0+m)*256 + k0 + skc*8];
        #pragma unroll
        for (int j=0;j<8;j++){
          float x = ap[j];
          bf16 h = f2bf(x);
          ((bf16*)&vh)[j] = h;
          ((bf16*)&vl)[j] = f2bf(x - bf2f(h));
        }
        *(short8*)&Ah[m][skc*8] = vh;
        *(short8*)&Al[m][skc*8] = vl;
      }
      int kr = k0 + m;
      if (bBf){
        short8 vb = *(const short8*)&B16[(size_t)bh*65536 + (size_t)(k0+m)*256 + c0 + skc*8];
        #pragma unroll
        for (int j=0;j<8;j++) Bh[skc*8+j][m] = ((bf16*)&vb)[j];  // bBf only used with bNeg==0
      } else {
        const float* bp = &Bf[(size_t)bh*65536 + (size_t)(k0+m)*256 + c0 + skc*8];
        #pragma unroll
        for (int j=0;j<8;j++){
          float x = bp[j];
          if (bNeg) x = (kr == (c0 + skc*8 + j) ? bDiag : 0.f) - x;
          bf16 h = f2bf(x);
          Bh[skc*8+j][m] = h;
          Bl[skc*8+j][m] = f2bf(x - bf2f(h));
        }
      }
    }
    __syncthreads();
    #pragma unroll
    for (int ksub=0; ksub<2; ksub++){
      short8 afh[2], afl[2], bfh[2], bfl[2];
      #pragma unroll
      for (int i=0;i<2;i++){
        afh[i] = *(const short8*)&Ah[wm*32+i*16+n][ksub*32+qd*8];
        if (!aBf) afl[i] = *(const short8*)&Al[wm*32+i*16+n][ksub*32+qd*8];
      }
      #pragma unroll
      for (int j=0;j<2;j++){
        bfh[j] = *(const short8*)&Bh[wn*32+j*16+n][ksub*32+qd*8];
        if (!bBf) bfl[j] = *(const short8*)&Bl[wn*32+j*16+n][ksub*32+qd*8];
      }
      #pragma unroll
      for (int i=0;i<2;i++)
        #pragma unroll
        for (int j=0;j<2;j++){
          if (!aBf) acc[i][j] = mfma16(afl[i], bfh[j], acc[i][j]);
          if (!bBf) acc[i][j] = mfma16(afh[i], bfl[j], acc[i][j]);
          acc[i][j] = mfma16(afh[i], bfh[j], acc[i][j]);
        }
    }
    __syncthreads();
  }
  #pragma unroll
  for (int i=0;i<2;i++){
    #pragma unroll
    for (int j=0;j<2;j++){
      int cidx = c0 + wn*32 + j*16 + n;
      #pragma unroll
      for (int rg=0; rg<4; rg++){
        int r = r0 + wm*32 + i*16 + qd*4 + rg;
        float r_ = acc[i][j][rg];
        if (cNeg) r_ = ((r==cidx)? cDiag : 0.f) - r_;
        Cb[(size_t)r*256 + cidx] = r_*cScale;
      }
    }
  }
}

// ---------------- batched GEMM 256x64x256: z2T = (Z @ kv3)^T ----------------
__global__ __launch_bounds__(256) void k_gemm_z2(bf16* __restrict__ z2t, const float* __restrict__ A,
    const bf16* __restrict__ Bm){
  int bh = blockIdx.y;
  int tm = blockIdx.x;
  const float* Ab = A  + (size_t)bh*65536;
  const bf16* Bb = Bm + (size_t)bh*M_*DH_;
  __shared__ float As[16][68];
  __shared__ float Bs[16][64];
  int t = threadIdx.x, tx = t&15, ty = t>>4;
  int r0 = tm*64;
  float acc[4][4] = {};
  for (int k0=0;k0<256;k0+=16){
    for (int i=t;i<1024;i+=256){
      int m=i>>4, kq=i&15;
      As[kq][m] = Ab[(size_t)(r0+m)*256 + k0+kq];
      int nn=i&63, k2=i>>6;
      Bs[k2][nn] = bf2f(Bb[(size_t)(k0+k2)*64 + nn]);
    }
    __syncthreads();
    #pragma unroll
    for (int kq=0;kq<16;kq++){
      float a0[4], b0[4];
      #pragma unroll
      for (int i=0;i<4;i++) a0[i] = As[kq][ty*4+i];
      #pragma unroll
      for (int j=0;j<4;j++) b0[j] = Bs[kq][tx*4+j];
      #pragma unroll
      for (int i=0;i<4;i++)
        #pragma unroll
        for (int j=0;j<4;j++) acc[i][j] += a0[i]*b0[j];
    }
    __syncthreads();
  }
  #pragma unroll
  for (int i=0;i<4;i++){
    int r = r0+ty*4+i;
    #pragma unroll
    for (int j=0;j<4;j++)
      z2t[(size_t)bh*16384 + (size_t)(tx*4+j)*256 + r] = f2bf(acc[i][j]);
  }
}

// ---------------- attn3 flash, no-max softmax (|s| <= ~2: exp safe, identical after norm) ----------------
__global__ __launch_bounds__(256, 2) void k_flash_split(const bf16* __restrict__ Q,
    const bf16* __restrict__ K, const bf16* __restrict__ VT,
    float* __restrict__ OP, float* __restrict__ LP){
  int bh = blockIdx.y;
  int sp = blockIdx.x;
  int t = threadIdx.x, w = t>>6, lane = t&63, qd = lane>>4, n = lane&15;
  int r0 = w*64;
  const size_t Qoff = ((size_t)bh*M_ + r0)*DH_;
  const size_t Koff = ((size_t)bh*N_ + (size_t)sp*CS)*DH_;
  const size_t Voff = (size_t)bh*DH_*N_ + (size_t)sp*CS;
  __shared__ __align__(16) bf16 pbuf[4][4][16][72];
  short8 aq[4][2];
  #pragma unroll
  for (int rt=0; rt<4; rt++){
    aq[rt][0] = *(const short8*)&Q[Qoff + (size_t)(rt*16+n)*DH_ + qd*8];
    aq[rt][1] = *(const short8*)&Q[Qoff + (size_t)(rt*16+n)*DH_ + 32 + qd*8];
  }
  f32x4 o[4][4];
  float lrun[4][4];
  #pragma unroll
  for (int rt=0; rt<4; rt++){
    #pragma unroll
    for (int j=0;j<4;j++){ o[rt][j] = (f32x4){0.f,0.f,0.f,0.f}; lrun[rt][j] = 0.f; }
  }
  for (int tl=0; tl<CS/64; ++tl){
    const bf16* kp = K + Koff + (size_t)(tl*64)*DH_;
    short8 kb[4][2];
    #pragma unroll
    for (int cg=0; cg<4; cg++){
      kb[cg][0] = *(const short8*)&kp[(size_t)(cg*16+n)*DH_ + qd*8];
      kb[cg][1] = *(const short8*)&kp[(size_t)(cg*16+n)*DH_ + 32 + qd*8];
    }
    #pragma unroll
    for (int rt=0; rt<4; rt++){
      f32x4 s[4];
      #pragma unroll
      for (int cg=0; cg<4; cg++){
        f32x4 z = (f32x4){0.f,0.f,0.f,0.f};
        z = mfma16(aq[rt][0], kb[cg][0], z);
        z = mfma16(aq[rt][1], kb[cg][1], z);
        s[cg] = z;
      }
      #pragma unroll
      for (int rg=0; rg<4; rg++){
        float p0 = __expf(s[0][rg]), p1 = __expf(s[1][rg]);
        float p2 = __expf(s[2][rg]), p3 = __expf(s[3][rg]);
        float ts = p0+p1+p2+p3;
        ts += __shfl_xor(ts,1); ts += __shfl_xor(ts,2);
        ts += __shfl_xor(ts,4); ts += __shfl_xor(ts,8);
        lrun[rt][rg] += ts;
        pbuf[w][rt][qd*4+rg][n]    = f2bf(p0);
        pbuf[w][rt][qd*4+rg][16+n] = f2bf(p1);
        pbuf[w][rt][qd*4+rg][32+n] = f2bf(p2);
        pbuf[w][rt][qd*4+rg][48+n] = f2bf(p3);
      }
    }
    const bf16* vp = VT + Voff + tl*64 + qd*8;
    short8 vb[4][2];
    #pragma unroll
    for (int dg=0; dg<4; dg++){
      vb[dg][0] = *(const short8*)&vp[(size_t)(dg*16+n)*N_];
      vb[dg][1] = *(const short8*)&vp[(size_t)(dg*16+n)*N_ + 32];
    }
    #pragma unroll
    for (int rt=0; rt<4; rt++){
      short8 ap0 = *(const short8*)&pbuf[w][rt][n][qd*8];
      short8 ap1 = *(const short8*)&pbuf[w][rt][n][32+qd*8];
      #pragma unroll
      for (int dg=0; dg<4; dg++){
        o[rt][dg] = mfma16(ap0, vb[dg][0], o[rt][dg]);
        o[rt][dg] = mfma16(ap1, vb[dg][1], o[rt][dg]);
      }
    }
  }
  size_t base = ((size_t)sp*(B_*H_) + bh)*M_;
  #pragma unroll
  for (int rt=0; rt<4; rt++){
    #pragma unroll
    for (int rg=0; rg<4; rg++){
      int row = r0 + rt*16 + qd*4 + rg;
      if (n==0) LP[base+row] = lrun[rt][rg];
      #pragma unroll
      for (int dg=0; dg<4; dg++)
        OP[(base+row)*DH_ + dg*16 + n] = o[rt][dg][rg];
    }
  }
}

// ---------------- merge NSPLIT flash partials -> kv3 (plain sums, no m) ----------------
__global__ __launch_bounds__(256) void k_flash_merge(const float* __restrict__ OP,
    const float* __restrict__ LP, bf16* __restrict__ O){
  int bh = blockIdx.y;
  int r = blockIdx.x*4 + (threadIdx.x>>6);
  int dh = threadIdx.x & 63;
  float acc = 0.f, den = 0.f;
  for (int s=0; s<NSPLIT; s++){
    size_t base = ((size_t)s*(B_*H_) + bh)*M_ + r;
    den += LP[base];
    acc += OP[base*DH_ + dh];
  }
  O[((size_t)bh*M_ + r)*DH_ + dh] = f2bf(acc/den);
}

// ---------------- attn1 flash, no-max softmax, 4 waves x 4 rowtiles ----------------
__global__ __launch_bounds__(256, 2) void k_flash_w3(const bf16* __restrict__ Q,
    const bf16* __restrict__ K, const bf16* __restrict__ VT, bf16* __restrict__ O){
  int bh = blockIdx.y;
  int t = threadIdx.x, w = t>>6, lane = t&63, qd = lane>>4, n = lane&15;
  int r0 = blockIdx.x*256 + w*64;
  const size_t Qoff = ((size_t)bh*N_ + r0)*DH_;
  const size_t Koff = (size_t)bh*M_*DH_;
  const size_t Voff = (size_t)bh*DH_*M_;
  __shared__ __align__(16) bf16 pbuf[4][4][16][72];
  short8 aq[4][2];
  #pragma unroll
  for (int rt=0; rt<4; rt++){
    aq[rt][0] = *(const short8*)&Q[Qoff + (size_t)(rt*16+n)*DH_ + qd*8];
    aq[rt][1] = *(const short8*)&Q[Qoff + (size_t)(rt*16+n)*DH_ + 32 + qd*8];
  }
  f32x4 o[4][4];
  float lrun[4][4];
  #pragma unroll
  for (int rt=0; rt<4; rt++){
    #pragma unroll
    for (int j=0;j<4;j++){ o[rt][j] = (f32x4){0.f,0.f,0.f,0.f}; lrun[rt][j] = 0.f; }
  }
  #pragma unroll
  for (int tl=0; tl<4; ++tl){
    const bf16* kp = K + Koff + (size_t)(tl*64)*DH_;
    short8 kb[4][2];
    #pragma unroll
    for (int cg=0; cg<4; cg++){
      kb[cg][0] = *(const short8*)&kp[(size_t)(cg*16+n)*DH_ + qd*8];
      kb[cg][1] = *(const short8*)&kp[(size_t)(cg*16+n)*DH_ + 32 + qd*8];
    }
    #pragma unroll
    for (int rt=0; rt<4; rt++){
      f32x4 s[4];
      #pragma unroll
      for (int cg=0; cg<4; cg++){
        f32x4 z = (f32x4){0.f,0.f,0.f,0.f};
        z = mfma16(aq[rt][0], kb[cg][0], z);
        z = mfma16(aq[rt][1], kb[cg][1], z);
        s[cg] = z;
      }
      #pragma unroll
      for (int rg=0; rg<4; rg++){
        float p0 = __expf(s[0][rg]), p1 = __expf(s[1][rg]);
        float p2 = __expf(s[2][rg]), p3 = __expf(s[3][rg]);
        float ts = p0+p1+p2+p3;
        ts += __shfl_xor(ts,1); ts += __shfl_xor(ts,2);
        ts += __shfl_xor(ts,4); ts += __shfl_xor(ts,8);
        lrun[rt][rg] += ts;
        pbuf[w][rt][qd*4+rg][n]    = f2bf(p0);
        pbuf[w][rt][qd*4+rg][16+n] = f2bf(p1);
        pbuf[w][rt][qd*4+rg][32+n] = f2bf(p2);
        pbuf[w][rt][qd*4+rg][48+n] = f2bf(p3);
      }
    }
    const bf16* vp = VT + Voff + tl*64 + qd*8;
    short8 vb[4][2];
    #pragma unroll
    for (int dg=0; dg<4; dg++){
      vb[dg][0] = *(const short8*)&vp[(size_t)(dg*16+n)*M_];
      vb[dg][1] = *(const short8*)&vp[(size_t)(dg*16+n)*M_ + 32];
    }
    #pragma unroll
    for (int rt=0; rt<4; rt++){
      short8 ap0 = *(const short8*)&pbuf[w][rt][n][qd*8];
      short8 ap1 = *(const short8*)&pbuf[w][rt][n][32+qd*8];
      #pragma unroll
      for (int dg=0; dg<4; dg++){
        o[rt][dg] = mfma16(ap0, vb[dg][0], o[rt][dg]);
        o[rt][dg] = mfma16(ap1, vb[dg][1], o[rt][dg]);
      }
    }
  }
  #pragma unroll
  for (int rt=0; rt<4; rt++){
    #pragma unroll
    for (int rg=0; rg<4; rg++){
      float inv = 1.f/lrun[rt][rg];
      size_t rowoff = ((size_t)bh*N_ + r0 + rt*16 + qd*4 + rg)*DH_;
      #pragma unroll
      for (int dg=0; dg<4; dg++)
        O[rowoff + dg*16 + n] = f2bf(o[rt][dg][rg]*inv);
    }
  }
}

// ---------------- depthwise conv(KER=33), LDS-tiled, vectorized RMW into outh ----------------
#define CCH 256
__global__ __launch_bounds__(256) void k_conv_add(const bf16* __restrict__ v, const float* __restrict__ w,
    bf16* __restrict__ outh){
  int bh = blockIdx.y;
  int n0 = blockIdx.x * CCH;
  int h = bh & 7;
  __shared__ bf16 vs[CCH+32][72];
  __shared__ float wk[KER_];
  int t = threadIdx.x;
  if (t < KER_) wk[t] = w[h*KER_ + t];
  const bf16* vb = v + (size_t)bh*N_*DH_;
  for (int i=t; i<(CCH+32)*8; i+=256){
    int r = i>>3, cg = i&7;
    int nn = n0 - 16 + r;
    short8 val = {0,0,0,0,0,0,0,0};
    if (nn >= 0 && nn < N_) val = *(const short8*)&vb[(size_t)nn*DH_ + cg*8];
    *(short8*)&vs[r][cg*8] = val;
  }
  __syncthreads();
  int dhg = t & 7, rowg = t >> 3;
  bf16* ob = outh + ((size_t)bh*N_ + n0)*DH_;
  #pragma unroll
  for (int rr=0; rr<8; rr++){
    int lr = rowg*8 + rr;
    float acc[8] = {0.f,0.f,0.f,0.f,0.f,0.f,0.f,0.f};
    for (int tt=0; tt<KER_; tt++){
      short8 vv = *(const short8*)&vs[lr+tt][dhg*8];
      float wt = wk[tt];
      #pragma unroll
      for (int j=0;j<8;j++) acc[j] += wt * bf2f(((bf16*)&vv)[j]);
    }
    short8 o = *(short8*)&ob[(size_t)lr*DH_ + dhg*8];
    #pragma unroll
    for (int j=0;j<8;j++) ((bf16*)&o)[j] = f2bf(bf2f(((bf16*)&o)[j]) + acc[j]);
    *(short8*)&ob[(size_t)lr*DH_ + dhg*8] = o;
  }
}

// ---------------- final GEMM: out = x + gather(outh) @ WT2^T + b_out ----------------
// 1D grid 1024 with XCD-chunked swizzle (same A-panel locality fix as qkv4).
__global__ __launch_bounds__(256) void k_mm_out2(const bf16* __restrict__ Ahd, const bf16* __restrict__ WT2,
    const float* __restrict__ bias, const float* __restrict__ xin, float* __restrict__ out){
  __shared__ __align__(16) bf16 As[128][72];
  __shared__ __align__(16) bf16 Bs[128][72];
  int t = threadIdx.x;
  int w = t>>6, lane = t&63, qd = lane>>4, n = lane&15;
  int wm = w>>1, wn = w&1;
  int bid = blockIdx.x;                // 0..1023
  int xcd = bid & 7, pos = bid >> 3;
  int tid = xcd*128 + pos;
  int cx = tid & 3, ry = tid >> 2;
  int r0 = ry*128, c0 = cx*128;
  f32x4 acc[4][4];
  #pragma unroll
  for (int i=0;i<4;i++)
    #pragma unroll
    for (int j=0;j<4;j++) acc[i][j] = (f32x4){0.f,0.f,0.f,0.f};
  int srow = t>>3, skc = t&7;
  for (int k0=0; k0<512; k0+=64){
    int h = k0 >> 6;
    #pragma unroll
    for (int ch=0; ch<4; ch++){
      int m = ch*32 + srow;
      int r = r0 + m, b = r>>13, nn = r&8191;
      *(short8*)&As[m][skc*8] = *(const short8*)&Ahd[((size_t)(b*H_+h)*N_ + nn)*DH_ + skc*8];
      *(short8*)&Bs[m][skc*8] = *(const short8*)&WT2[(size_t)(c0+m)*512 + k0 + skc*8];
    }
    __syncthreads();
    #pragma unroll
    for (int ksub=0; ksub<2; ksub++){
      short8 af[4], bfr[4];
      #pragma unroll
      for (int i=0;i<4;i++) af[i]  = *(const short8*)&As[wm*64+i*16+n][ksub*32+qd*8];
      #pragma unroll
      for (int j=0;j<4;j++) bfr[j] = *(const short8*)&Bs[wn*64+j*16+n][ksub*32+qd*8];
      #pragma unroll
      for (int i=0;i<4;i++)
        #pragma unroll
        for (int j=0;j<4;j++) acc[i][j] = mfma16(af[i], bfr[j], acc[i][j]);
    }
    __syncthreads();
  }
  #pragma unroll
  for (int i=0;i<4;i++){
    #pragma unroll
    for (int rg=0; rg<4; rg++){
      int r = r0 + wm*64 + i*16 + qd*4 + rg;
      size_t base = (size_t)r*512;
      #pragma unroll
      for (int j=0;j<4;j++){
        int c = c0 + wn*64 + j*16 + n;
        out[base + c] = acc[i][j][rg] + bias[c] + xin[base + c];
      }
    }
  }
}

extern "C" void kernel_launch(void* const* d_in, const int* in_sizes, int n_in,
                              void* d_out, int out_size, void* d_ws, size_t ws_size,
                              hipStream_t stream) {
  const float* x     = (const float*)d_in[0];
  const float* gamma = (const float*)d_in[1];
  const float* beta  = (const float*)d_in[2];
  const float* wqkv  = (const float*)d_in[3];
  const float* resk  = (const float*)d_in[4];
  const float* wout  = (const float*)d_in[5];
  const float* bout  = (const float*)d_in[6];
  float* out = (float*)d_out;

  const size_t SL = (size_t)B_*H_*N_*DH_;
  const size_t SM = (size_t)B_*H_*M_*DH_;
  const size_t SP = (size_t)B_*H_*M_*M_;

  bf16* xn  = (bf16*)d_ws;     // reused as: flash partial OP, then pinv P1..P4, then outh
  bf16* q   = xn + SL;
  bf16* k   = q + SL;          // k region dead after flash_split -> holds bf16 pinv scratch
  bf16* v   = k + SL;
  bf16* vT  = v + SL;
  bf16* ql  = vT + SL;
  bf16* kl  = ql + SM;
  bf16* kv3 = kl + SM;
  bf16* z2T = kv3 + SM;
  float* A2 = (float*)(z2T + SM);
  bf16* WT  = (bf16*)(A2 + SP);       // 1536 x 512 bf16
  bf16* WT2 = WT + (size_t)1536*512;  // 512 x 512 bf16
  float* P1 = (float*)xn;             // pinv fp32 scratch aliases xn (4*SP*4B == SL*2B)
  float* P2 = P1 + SP;
  float* P3 = P2 + SP;
  float* P4 = P3 + SP;
  float* OPp = (float*)xn;            // flash partials alias xn (dead before pinv)
  float* LPp = (float*)z2T;           // and z2T (dead until gemm_z2)
  // bf16 pinv scratch in dead k region (6*SP*2B = 25.2MB <= 33.5MB)
  bf16* A2b = k;
  bf16* Zb0 = A2b + SP;
  bf16* Zb1 = Zb0 + SP;
  bf16* Pb  = Zb1 + SP;
  bf16* Tb  = Pb + SP;
  bf16* Ub  = Tb + SP;

  k_wt<<<dim3(24, 8), 256, 0, stream>>>(wqkv, WT, 512, 1536);
  k_wt<<<dim3(8, 8), 256, 0, stream>>>(wout, WT2, 512, 512);
  k_layernorm<<<B_*N_, 256, 0, stream>>>(x, gamma, beta, xn);
  k_mm_qkv4<<<1536, 256, 0, stream>>>(xn, WT, q, k, v, vT, ql, kl);

  // attn3 flash (split + merge) BEFORE pinv so partials use the dead xn/z2T regions
  k_flash_split<<<dim3(NSPLIT, B_*H_), 256, 0, stream>>>(ql, k, vT, OPp, LPp);
  k_flash_merge<<<dim3(M_/4, B_*H_), 256, 0, stream>>>(OPp, LPp, kv3);

  k_attn2<<<B_*H_*M_, 256, 0, stream>>>(ql, kl, A2, A2b);
  k_pinv_init<<<B_*H_, 256, 0, stream>>>(A2, Zb0);

  // NS iterations 0-4: pure bf16 (ops already bf16-rounded in plain mode; storage matches)
  bf16* Zbi = Zb0; bf16* Zbo = Zb1;
  for (int it=0; it<5; ++it){
    k_gemm_pmb<<<dim3(16,32), 256, 0, stream>>>(Pb,  A2b, Zbi, 0.f,0, 0.f,0, 1.f);   // P = A2@Z
    k_gemm_pmb<<<dim3(16,32), 256, 0, stream>>>(Tb,  Pb,  Pb,  7.f,1, 15.f,1, 1.f);  // S = 15I-P@(7I-P)
    k_gemm_pmb<<<dim3(16,32), 256, 0, stream>>>(Ub,  Pb,  Tb,  0.f,0, 13.f,1, 1.f);  // U = 13I-P@S
    k_gemm_pmb<<<dim3(16,32), 256, 0, stream>>>(Zbo, Zbi, Ub,  0.f,0, 0.f,0, 0.25f); // Zn = .25*Z@U
    bf16* tt = Zbi; Zbi = Zbo; Zbo = tt;
  }
  // NS iteration 5: split precision fp32 (bf16 operands where exact: lo=0)
  k_gemm_pm<<<dim3(16,32), 256, 0, stream>>>(P2, A2, Zbi, 0.f,0, 0.f,0, 1.f,  0,1); // P
  k_gemm_pm<<<dim3(16,32), 256, 0, stream>>>(P3, P2, P2,  7.f,1, 15.f,1, 1.f, 0,0); // S
  k_gemm_pm<<<dim3(16,32), 256, 0, stream>>>(P4, P2, P3,  0.f,0, 13.f,1, 1.f, 0,0); // U
  k_gemm_pm<<<dim3(16,32), 256, 0, stream>>>(P1, Zbi, P4, 0.f,0, 0.f,0, 0.25f,1,0); // Zn->P1

  k_gemm_z2<<<dim3(4, B_*H_), 256, 0, stream>>>(z2T, P1, kv3);
  k_flash_w3<<<dim3(N_/256, B_*H_), 256, 0, stream>>>(q, kl, z2T, xn);
  k_conv_add<<<dim3(N_/CCH, B_*H_), 256, 0, stream>>>(v, resk, xn);
  k_mm_out2<<<1024, 256, 0, stream>>>(xn, WT2, bout, x, out);
}